// Round 8
// baseline (386.449 us; speedup 1.0000x reference)
//
#include <hip/hip_runtime.h>
#include <hip/hip_bf16.h>

// Problem constants: B=4, L=2048, d_model=d_value=512, H=8, E=64, d4=2048.
// External inputs/output fp32. Internal compute: bf16 MFMA.
//
// R6: coalesced+swizzled staging in all GEMMs (verified, -52 us).
// R7/R8: attn BARRIER-FREE: K/V fragments loaded global->VGPR per wave
// (L1/L2-resident; 16x64B segments per instr), single-buffer register
// prefetch (K for r+1 issued after QK of r, V after PV). LDS only holds
// the per-wave P transpose -> no __syncthreads at all. R6 counters showed
// attn at 4200 cyc/round with no pipe saturated: 4x-redundant LDS K/V
// reads + 2 barriers/round were the structural tax.
// (R7 bench was an infra failure - "container failed twice", same signature
// as R4 which passed on identical resubmit. v10 audit clean: bounds,
// 16B alignment, no barriers, ~180 VGPR. Identical resubmit.)

typedef __attribute__((ext_vector_type(8))) short sh8;    // 8 bf16 (A/B frag)
typedef __attribute__((ext_vector_type(4))) float f32x4;  // C/D frag

#define QSCALE 0.18033688011110543f   // 0.125 * log2(e): folded into Q projection

__device__ __forceinline__ void storeOut(float* p, float v) { *p = v; }
__device__ __forceinline__ void storeOut(__hip_bfloat16* p, float v) { *p = __float2bfloat16(v); }

// async global->LDS, 16 B per lane, wave-uniform LDS base (m97 pattern)
__device__ __forceinline__ void gl_lds16(const void* g, void* l) {
    __builtin_amdgcn_global_load_lds((const __attribute__((address_space(1))) void*)g,
                                     (__attribute__((address_space(3))) void*)l, 16, 0, 0);
}

// pack two fp32 into one dword of two bf16 (RNE)
__device__ __forceinline__ unsigned pk_bf16(float a, float b) {
    __hip_bfloat162 h = __float22bfloat162_rn(make_float2(a, b));
    return *(unsigned*)&h;
}
// 8 fp32 -> sh8 bf16 fragment
__device__ __forceinline__ sh8 pk8(float4 a, float4 b) {
    int4 iv = make_int4(pk_bf16(a.x, a.y), pk_bf16(a.z, a.w),
                        pk_bf16(b.x, b.y), pk_bf16(b.z, b.w));
    return *(sh8*)&iv;
}

// ---------------------------------------------------------------------------
// Weights fp32 -> bf16 into one contiguous ws region.
// Order: Wq,Wk,Wv,Wo,Wl,Wc1,Wc2 (3407872 elements).
// ---------------------------------------------------------------------------
struct WArg { const float* w[7]; unsigned short* wd; };
__global__ __launch_bounds__(256) void conv_w(WArg p)
{
    const int i = (blockIdx.x * 256 + threadIdx.x) * 4;
    if (i >= 3407872) return;
    const float* s; int off;
    if      (i < 262144)  { s = p.w[0]; off = i; }
    else if (i < 524288)  { s = p.w[1]; off = i - 262144; }
    else if (i < 786432)  { s = p.w[2]; off = i - 524288; }
    else if (i < 1048576) { s = p.w[3]; off = i - 786432; }
    else if (i < 1310720) { s = p.w[4]; off = i - 1048576; }
    else if (i < 2359296) { s = p.w[5]; off = i - 1310720; }
    else                  { s = p.w[6]; off = i - 2359296; }
    const float4 v = *(const float4*)(s + off);
    *(uint2*)(p.wd + i) = make_uint2(pk_bf16(v.x, v.y), pk_bf16(v.z, v.w));
}

// ---------------------------------------------------------------------------
// Batched QKV GEMM (grid.z = 0,1,2). A fp32 staged coalesced (16 lanes/row,
// chunk-XOR over 16); W bf16 (8 lanes/row, XOR over 8). BK=64.
// z=0: scaled by QSCALE -> Qb. z=1 -> Kb. z=2: written TRANSPOSED into
// Vt[B*H,64,L].
// ---------------------------------------------------------------------------
struct QkvArg {
    const float *A0, *A1, *A2;
    const float *b0, *b1, *b2;
    unsigned short *C0, *C1;      // Qb, Kb [B,L,H,64]
    unsigned short *Vt;           // [B*H,64,L]
};
__global__ __launch_bounds__(256) void gemm_qkv(QkvArg ar, const unsigned short* __restrict__ Wall,
                                                int M, int N, int K)
{
    const int z = blockIdx.z;
    const float* A = z == 0 ? ar.A0 : (z == 1 ? ar.A1 : ar.A2);
    const unsigned short* W = Wall + (size_t)z * 262144;
    const float* bias = z == 0 ? ar.b0 : (z == 1 ? ar.b1 : ar.b2);

    __shared__ float AsF[8192];            // 32 KB: [row:128][chunk:16][4 fp32] swz
    __shared__ unsigned short BsL[8192];   // 16 KB: [row:128][chunk:8][8 bf16] swz
    const int t    = threadIdx.x;
    const int wave = t >> 6, lane = t & 63;
    const int quad = lane >> 4, col = lane & 15;
    const int wm   = wave >> 1, wn = wave & 1;
    const int m0   = blockIdx.y * 128, n0 = blockIdx.x * 128;

    f32x4 acc[4][4];
    #pragma unroll
    for (int mt = 0; mt < 4; mt++)
        #pragma unroll
        for (int nt = 0; nt < 4; nt++)
            acc[mt][nt] = (f32x4){0.f, 0.f, 0.f, 0.f};

    for (int k0 = 0; k0 < K; k0 += 64) {
        #pragma unroll
        for (int seg = 0; seg < 8; seg++) {        // A fp32: 4 rows/instr, 256 B/row
            const int r0  = (seg * 4 + wave) * 4;  // wave-uniform
            const int row = r0 + (lane >> 4);
            const int ck  = (lane & 15) ^ (row & 15);
            gl_lds16(A + (size_t)(m0 + row) * K + k0 + ck * 4, &AsF[r0 * 64]);
        }
        #pragma unroll
        for (int seg = 0; seg < 4; seg++) {        // W bf16: 8 rows/instr, 128 B/row
            const int r0  = (seg * 4 + wave) * 8;
            const int row = r0 + (lane >> 3);
            const int ck  = (lane & 7) ^ (row & 7);
            gl_lds16(W + (size_t)(n0 + row) * K + k0 + ck * 8, &BsL[r0 * 64]);
        }
        __syncthreads();
        #pragma unroll
        for (int kc = 0; kc < 2; kc++) {
            sh8 af[4], bf[4];
            #pragma unroll
            for (int mt = 0; mt < 4; mt++) {
                const int mr  = wm * 64 + mt * 16 + col;
                const int q0  = kc * 8 + quad * 2;
                const int m16 = mr & 15;
                float4 f0 = *(const float4*)&AsF[mr * 64 + ((q0 ^ m16) << 2)];
                float4 f1 = *(const float4*)&AsF[mr * 64 + (((q0 + 1) ^ m16) << 2)];
                af[mt] = pk8(f0, f1);
            }
            #pragma unroll
            for (int nt = 0; nt < 4; nt++) {
                const int nr = wn * 64 + nt * 16 + col;
                bf[nt] = *(const sh8*)&BsL[nr * 64 + (((kc * 4 + quad) ^ (nr & 7)) << 3)];
            }
            #pragma unroll
            for (int mt = 0; mt < 4; mt++)
                #pragma unroll
                for (int nt = 0; nt < 4; nt++)
                    acc[mt][nt] = __builtin_amdgcn_mfma_f32_16x16x32_bf16(af[mt], bf[nt], acc[mt][nt], 0, 0, 0);
        }
        __syncthreads();
    }

    if (z < 2) {
        unsigned short* C = z == 0 ? ar.C0 : ar.C1;
        const float scale = z == 0 ? QSCALE : 1.0f;
        #pragma unroll
        for (int nt = 0; nt < 4; nt++) {
            const int cn = n0 + wn * 64 + nt * 16 + col;
            const float bj = bias[cn];
            #pragma unroll
            for (int mt = 0; mt < 4; mt++) {
                const int rm = m0 + wm * 64 + mt * 16 + quad * 4;
                #pragma unroll
                for (int reg = 0; reg < 4; reg++)
                    C[(size_t)(rm + reg) * N + cn] =
                        (unsigned short)__bfloat16_as_ushort(__float2bfloat16((acc[mt][nt][reg] + bj) * scale));
            }
        }
    } else {
        // V: write transposed [B*H, 64, L]; 4 consecutive s rows pack to 8 B.
        const int b = m0 >> 11;                    // L = 2048
        #pragma unroll
        for (int nt = 0; nt < 4; nt++) {
            const int cn = n0 + wn * 64 + nt * 16 + col;
            const int h = cn >> 6, e = cn & 63;
            const float bj = bias[cn];
            #pragma unroll
            for (int mt = 0; mt < 4; mt++) {
                const int s0r = (m0 + wm * 64 + mt * 16 + quad * 4) & 2047;
                float cv[4];
                #pragma unroll
                for (int reg = 0; reg < 4; reg++) cv[reg] = acc[mt][nt][reg] + bj;
                *(uint2*)(ar.Vt + ((size_t)(b * 8 + h) * 64 + e) * 2048 + s0r) =
                    make_uint2(pk_bf16(cv[0], cv[1]), pk_bf16(cv[2], cv[3]));
            }
        }
    }
}

// ---------------------------------------------------------------------------
// MFMA GEMM 128x128, BK=64 (FFN1): coalesced+swizzled staging (R6).
// ---------------------------------------------------------------------------
template <typename TOUT, bool RELU>
__global__ __launch_bounds__(256) void gemm_mfma(const unsigned short* __restrict__ A,
                                                 const unsigned short* __restrict__ W,
                                                 const float* __restrict__ bias,
                                                 TOUT* __restrict__ C,
                                                 int M, int N, int K)
{
    __shared__ unsigned short AsL[8192];   // [row:128][chunk:8][8 bf16] swz
    __shared__ unsigned short BsL[8192];
    const int t    = threadIdx.x;
    const int wave = t >> 6, lane = t & 63;
    const int quad = lane >> 4, col = lane & 15;
    const int wm   = wave >> 1, wn = wave & 1;
    const int m0   = blockIdx.y * 128, n0 = blockIdx.x * 128;

    f32x4 acc[4][4];
    #pragma unroll
    for (int mt = 0; mt < 4; mt++)
        #pragma unroll
        for (int nt = 0; nt < 4; nt++)
            acc[mt][nt] = (f32x4){0.f, 0.f, 0.f, 0.f};

    for (int k0 = 0; k0 < K; k0 += 64) {
        #pragma unroll
        for (int seg = 0; seg < 4; seg++) {
            const int r0  = (seg * 4 + wave) * 8;  // wave-uniform
            const int row = r0 + (lane >> 3);
            const int ck  = (lane & 7) ^ (row & 7);
            gl_lds16(A + (size_t)(m0 + row) * K + k0 + ck * 8, &AsL[r0 * 64]);
            gl_lds16(W + (size_t)(n0 + row) * K + k0 + ck * 8, &BsL[r0 * 64]);
        }
        __syncthreads();
        #pragma unroll
        for (int kc = 0; kc < 2; kc++) {
            sh8 af[4], bf[4];
            #pragma unroll
            for (int mt = 0; mt < 4; mt++) {
                const int ar = wm * 64 + mt * 16 + col;
                af[mt] = *(const sh8*)&AsL[ar * 64 + (((kc * 4 + quad) ^ (ar & 7)) << 3)];
            }
            #pragma unroll
            for (int nt = 0; nt < 4; nt++) {
                const int nr = wn * 64 + nt * 16 + col;
                bf[nt] = *(const sh8*)&BsL[nr * 64 + (((kc * 4 + quad) ^ (nr & 7)) << 3)];
            }
            #pragma unroll
            for (int mt = 0; mt < 4; mt++)
                #pragma unroll
                for (int nt = 0; nt < 4; nt++)
                    acc[mt][nt] = __builtin_amdgcn_mfma_f32_16x16x32_bf16(af[mt], bf[nt], acc[mt][nt], 0, 0, 0);
        }
        __syncthreads();
    }
    #pragma unroll
    for (int nt = 0; nt < 4; nt++) {
        const int cn = n0 + wn * 64 + nt * 16 + col;
        const float bj = bias[cn];
        #pragma unroll
        for (int mt = 0; mt < 4; mt++) {
            const int rm = m0 + wm * 64 + mt * 16 + quad * 4;
            #pragma unroll
            for (int reg = 0; reg < 4; reg++) {
                float cv = acc[mt][nt][reg] + bj;
                if (RELU) cv = fmaxf(cv, 0.f);
                storeOut(&C[(size_t)(rm + reg) * N + cn], cv);
            }
        }
    }
}

// ---------------------------------------------------------------------------
// MFMA GEMM 64x128 tile, BK=64: coalesced+swizzled staging (R6).
// ---------------------------------------------------------------------------
template <typename TOUT, bool RELU>
__global__ __launch_bounds__(256) void gemm_mfma64(const unsigned short* __restrict__ A,
                                                   const unsigned short* __restrict__ W,
                                                   const float* __restrict__ bias,
                                                   TOUT* __restrict__ C,
                                                   int M, int N, int K)
{
    __shared__ unsigned short AsL[4096];   // [row:64][chunk:8][8 bf16] swz
    __shared__ unsigned short BsL[8192];
    const int t    = threadIdx.x;
    const int wave = t >> 6, lane = t & 63;
    const int quad = lane >> 4, col = lane & 15;
    const int wm   = wave >> 1, wn = wave & 1;
    const int m0   = blockIdx.y * 64, n0 = blockIdx.x * 128;

    f32x4 acc[2][4];
    #pragma unroll
    for (int mt = 0; mt < 2; mt++)
        #pragma unroll
        for (int nt = 0; nt < 4; nt++)
            acc[mt][nt] = (f32x4){0.f, 0.f, 0.f, 0.f};

    for (int k0 = 0; k0 < K; k0 += 64) {
        #pragma unroll
        for (int seg = 0; seg < 2; seg++) {
            const int r0  = (seg * 4 + wave) * 8;  // wave-uniform, 0..56
            const int row = r0 + (lane >> 3);
            const int ck  = (lane & 7) ^ (row & 7);
            gl_lds16(A + (size_t)(m0 + row) * K + k0 + ck * 8, &AsL[r0 * 64]);
        }
        #pragma unroll
        for (int seg = 0; seg < 4; seg++) {
            const int r0  = (seg * 4 + wave) * 8;
            const int row = r0 + (lane >> 3);
            const int ck  = (lane & 7) ^ (row & 7);
            gl_lds16(W + (size_t)(n0 + row) * K + k0 + ck * 8, &BsL[r0 * 64]);
        }
        __syncthreads();
        #pragma unroll
        for (int kc = 0; kc < 2; kc++) {
            sh8 af[2], bf[4];
            #pragma unroll
            for (int mt = 0; mt < 2; mt++) {
                const int ar = wm * 32 + mt * 16 + col;
                af[mt] = *(const sh8*)&AsL[ar * 64 + (((kc * 4 + quad) ^ (ar & 7)) << 3)];
            }
            #pragma unroll
            for (int nt = 0; nt < 4; nt++) {
                const int nr = wn * 64 + nt * 16 + col;
                bf[nt] = *(const sh8*)&BsL[nr * 64 + (((kc * 4 + quad) ^ (nr & 7)) << 3)];
            }
            #pragma unroll
            for (int mt = 0; mt < 2; mt++)
                #pragma unroll
                for (int nt = 0; nt < 4; nt++)
                    acc[mt][nt] = __builtin_amdgcn_mfma_f32_16x16x32_bf16(af[mt], bf[nt], acc[mt][nt], 0, 0, 0);
        }
        __syncthreads();
    }
    #pragma unroll
    for (int nt = 0; nt < 4; nt++) {
        const int cn = n0 + wn * 64 + nt * 16 + col;
        const float bj = bias[cn];
        #pragma unroll
        for (int mt = 0; mt < 2; mt++) {
            const int rm = m0 + wm * 32 + mt * 16 + quad * 4;
            #pragma unroll
            for (int reg = 0; reg < 4; reg++) {
                float cv = acc[mt][nt][reg] + bj;
                if (RELU) cv = fmaxf(cv, 0.f);
                storeOut(&C[(size_t)(rm + reg) * N + cn], cv);
            }
        }
    }
}

// ---------------------------------------------------------------------------
// MFMA flash attention v10 (causal, reverse-paired tiles, BARRIER-FREE).
// Each wave is autonomous: K/V MFMA fragments loaded global->VGPR directly
// (addresses = 16 x 64B row segments per instr; K/V are L1/L2-resident so
// the 4x cross-wave redundancy is absorbed by L1). Single-buffer register
// prefetch: K frags for r+1 issued right after QK of r consumes them
// (cover = softmax+PV); V frags for r+1 issued after PV of r (cover =
// next QK+softmax). Compiler tracks register deps -> exact waitcnts, and
// there is NO __syncthreads in the kernel. LDS holds only the per-wave
// P transpose (PsA/PsB, 18 KB).
// Block = 4 waves, q-tiles (i, 31-i), S = 32-i rounds, fixed-max softmax.
// Qb/Kb: [B,L,H,64] bf16; Vt: [B*H,64,L] bf16; O: [B,L,H,64] bf16.
// ---------------------------------------------------------------------------
__global__ __launch_bounds__(256, 2) void attn_mfma(const unsigned short* __restrict__ Qb,
                                                    const unsigned short* __restrict__ Kb,
                                                    const unsigned short* __restrict__ Vt,
                                                    __hip_bfloat16* __restrict__ O,
                                                    int L)
{
    __shared__ unsigned short PsA[4][16][72];    // per wave [qrow:16][key:64+pad] 9 KB
    __shared__ unsigned short PsB[4][16][72];

    const int i    = blockIdx.x;                 // 0..15
    const int bh   = blockIdx.y;
    const int b    = bh >> 3, h = bh & 7;        // H = 8
    const int t    = threadIdx.x;
    const int w    = t >> 6, lane = t & 63;
    const int quad = lane >> 4, col = lane & 15;

    const int qtA = i, qtB = 31 - i;             // light / heavy tile
    const int qrowA = qtA * 64 + w * 16 + col;
    const int qrowB = qtB * 64 + w * 16 + col;
    const int S = 32 - i;                        // rounds (tile B needs all)

    // Q B-frags (QSCALE pre-applied in projection)
    sh8 qfA[2], qfB[2];
    {
        const size_t qa = ((size_t)(b * L + qrowA) * 8 + h) * 64;
        qfA[0] = *(const sh8*)(Qb + qa + quad * 8);
        qfA[1] = *(const sh8*)(Qb + qa + 32 + quad * 8);
        const size_t qb2 = ((size_t)(b * L + qrowB) * 8 + h) * 64;
        qfB[0] = *(const sh8*)(Qb + qb2 + quad * 8);
        qfB[1] = *(const sh8*)(Qb + qb2 + 32 + quad * 8);
    }

    // per-lane fragment base pointers
    // K frag [ntk][half]: K[k0+ntk*16+col][e = (quad + 4*half)*8 + j]
    const unsigned short* kbase = Kb + ((size_t)(b * L + col)) * 512 + h * 64 + quad * 8;
    // V frag [kchunk][nt]: V^T[e = nt*16+col][key = k0 + kchunk*32 + quad*8 + j]
    const unsigned short* vbase = Vt + ((size_t)(bh * 64 + col)) * 2048 + quad * 8;

    sh8 kf[8];   // [ntk*2 + half]
    sh8 vf[8];   // [kchunk*4 + nt]

    // ---- prologue: load K/V fragments for round 0
    #pragma unroll
    for (int ntk = 0; ntk < 4; ntk++) {
        kf[ntk * 2]     = *(const sh8*)(kbase + (size_t)(ntk * 16) * 512);
        kf[ntk * 2 + 1] = *(const sh8*)(kbase + (size_t)(ntk * 16) * 512 + 32);
    }
    #pragma unroll
    for (int kc = 0; kc < 2; kc++)
        #pragma unroll
        for (int nt = 0; nt < 4; nt++)
            vf[kc * 4 + nt] = *(const sh8*)(vbase + (size_t)(nt * 16) * 2048 + kc * 32);

    f32x4 OA[4], OB[4];
    #pragma unroll
    for (int nt = 0; nt < 4; nt++) { OA[nt] = (f32x4){0.f,0.f,0.f,0.f}; OB[nt] = (f32x4){0.f,0.f,0.f,0.f}; }
    float lA = 0.f, lB = 0.f;

    for (int r = 0; r < S; r++) {
        const int k0 = r * 64;
        const bool actA  = (r <= i);
        const bool maskA = (r == i);
        const bool maskB = (r == S - 1);

        // ---- S^T for both tiles from register K-frags
        f32x4 stA[4], stB[4];
        const f32x4 zz = {0.f, 0.f, 0.f, 0.f};
        #pragma unroll
        for (int ntk = 0; ntk < 4; ntk++) {
            f32x4 aB = __builtin_amdgcn_mfma_f32_16x16x32_bf16(kf[ntk * 2], qfB[0], zz, 0, 0, 0);
            stB[ntk] = __builtin_amdgcn_mfma_f32_16x16x32_bf16(kf[ntk * 2 + 1], qfB[1], aB, 0, 0, 0);
            if (actA) {
                f32x4 aA = __builtin_amdgcn_mfma_f32_16x16x32_bf16(kf[ntk * 2], qfA[0], zz, 0, 0, 0);
                stA[ntk] = __builtin_amdgcn_mfma_f32_16x16x32_bf16(kf[ntk * 2 + 1], qfA[1], aA, 0, 0, 0);
            }
        }

        // ---- prefetch K for r+1 (kf free after QK; cover = softmax+PV)
        if (r + 1 < S) {
            const unsigned short* kb2 = kbase + (size_t)(r + 1) * 64 * 512;
            #pragma unroll
            for (int ntk = 0; ntk < 4; ntk++) {
                kf[ntk * 2]     = *(const sh8*)(kb2 + (size_t)(ntk * 16) * 512);
                kf[ntk * 2 + 1] = *(const sh8*)(kb2 + (size_t)(ntk * 16) * 512 + 32);
            }
        }

        // ---- fixed-max softmax: exp2, per-lane l accumulate, pack to LDS
        {
            if (maskB) {
                #pragma unroll
                for (int ntk = 0; ntk < 4; ntk++)
                    #pragma unroll
                    for (int reg = 0; reg < 4; reg++)
                        if (k0 + ntk * 16 + quad * 4 + reg > qrowB) stB[ntk][reg] = -1e30f;
            }
            #pragma unroll
            for (int ntk = 0; ntk < 4; ntk++) {
                #pragma unroll
                for (int reg = 0; reg < 4; reg++)
                    stB[ntk][reg] = exp2f(stB[ntk][reg]);
                lB += (stB[ntk][0] + stB[ntk][1]) + (stB[ntk][2] + stB[ntk][3]);
                *(uint2*)&PsB[w][col][ntk * 16 + quad * 4] =
                    make_uint2(pk_bf16(stB[ntk][0], stB[ntk][1]), pk_bf16(stB[ntk][2], stB[ntk][3]));
            }
        }
        if (actA) {
            if (maskA) {
                #pragma unroll
                for (int ntk = 0; ntk < 4; ntk++)
                    #pragma unroll
                    for (int reg = 0; reg < 4; reg++)
                        if (k0 + ntk * 16 + quad * 4 + reg > qrowA) stA[ntk][reg] = -1e30f;
            }
            #pragma unroll
            for (int ntk = 0; ntk < 4; ntk++) {
                #pragma unroll
                for (int reg = 0; reg < 4; reg++)
                    stA[ntk][reg] = exp2f(stA[ntk][reg]);
                lA += (stA[ntk][0] + stA[ntk][1]) + (stA[ntk][2] + stA[ntk][3]);
                *(uint2*)&PsA[w][col][ntk * 16 + quad * 4] =
                    make_uint2(pk_bf16(stA[ntk][0], stA[ntk][1]), pk_bf16(stA[ntk][2], stA[ntk][3]));
            }
        }

        // ---- O += P @ V from register V-frags (read P via per-wave LDS)
        #pragma unroll
        for (int kchunk = 0; kchunk < 2; kchunk++) {
            sh8 pfB = *(const sh8*)&PsB[w][col][kchunk * 32 + quad * 8];
            sh8 pfA;
            if (actA) pfA = *(const sh8*)&PsA[w][col][kchunk * 32 + quad * 8];
            #pragma unroll
            for (int nt = 0; nt < 4; nt++) {
                OB[nt] = __builtin_amdgcn_mfma_f32_16x16x32_bf16(pfB, vf[kchunk * 4 + nt], OB[nt], 0, 0, 0);
                if (actA) OA[nt] = __builtin_amdgcn_mfma_f32_16x16x32_bf16(pfA, vf[kchunk * 4 + nt], OA[nt], 0, 0, 0);
            }
        }

        // ---- prefetch V for r+1 (vf free after PV; cover = next QK+softmax)
        if (r + 1 < S) {
            const unsigned short* vb2 = vbase + (r + 1) * 64;
            #pragma unroll
            for (int kc = 0; kc < 2; kc++)
                #pragma unroll
                for (int nt = 0; nt < 4; nt++)
                    vf[kc * 4 + nt] = *(const sh8*)(vb2 + (size_t)(nt * 16) * 2048 + kc * 32);
        }
    }

    // ---- epilogue: reduce l across quads (2 shuffles, once), store O
    lA += __shfl_xor(lA, 16); lA += __shfl_xor(lA, 32);
    lB += __shfl_xor(lB, 16); lB += __shfl_xor(lB, 32);
    {
        const float li = 1.f / lA;
        float lr[4];
        #pragma unroll
        for (int reg = 0; reg < 4; reg++) lr[reg] = __shfl(li, quad * 4 + reg);
        #pragma unroll
        for (int reg = 0; reg < 4; reg++) {
            const int qr = qtA * 64 + w * 16 + quad * 4 + reg;
            #pragma unroll
            for (int nt = 0; nt < 4; nt++)
                O[((size_t)(b * L + qr) * 8 + h) * 64 + nt * 16 + col] =
                    __float2bfloat16(OA[nt][reg] * lr[reg]);
        }
    }
    {
        const float li = 1.f / lB;
        float lr[4];
        #pragma unroll
        for (int reg = 0; reg < 4; reg++) lr[reg] = __shfl(li, quad * 4 + reg);
        #pragma unroll
        for (int reg = 0; reg < 4; reg++) {
            const int qr = qtB * 64 + w * 16 + quad * 4 + reg;
            #pragma unroll
            for (int nt = 0; nt < 4; nt++)
                O[((size_t)(b * L + qr) * 8 + h) * 64 + nt * 16 + col] =
                    __float2bfloat16(OB[nt][reg] * lr[reg]);
        }
    }
}

// ---------------------------------------------------------------------------
// LayerNorm over last dim (512). x = f1 [+ f2] [+ rb]. Dual output.
// ---------------------------------------------------------------------------
__global__ __launch_bounds__(256) void layernorm_k(const float* __restrict__ f1,
                                                   const float* __restrict__ f2,
                                                   const float* __restrict__ rb,
                                                   const float* __restrict__ g,
                                                   const float* __restrict__ bb,
                                                   float* __restrict__ out32,
                                                   __hip_bfloat16* __restrict__ out16)
{
    const int row = blockIdx.x;
    const int t   = threadIdx.x;
    const size_t base = (size_t)row * 512;
    const int i0 = t * 2;

    float a0 = f1[base + i0], a1 = f1[base + i0 + 1];
    if (f2) { a0 += f2[base + i0]; a1 += f2[base + i0 + 1]; }
    if (rb) { a0 += rb[base + i0]; a1 += rb[base + i0 + 1]; }

    float s = a0 + a1, ss = a0 * a0 + a1 * a1;
    #pragma unroll
    for (int off = 32; off > 0; off >>= 1) {
        s  += __shfl_xor(s, off);
        ss += __shfl_xor(ss, off);
    }
    __shared__ float red[16];
    const int lane = t & 63, wid = t >> 6;
    if (lane == 0) { red[wid] = s; red[8 + wid] = ss; }
    __syncthreads();
    if (t == 0) {
        const float S  = red[0] + red[1] + red[2] + red[3];
        const float SS = red[8] + red[9] + red[10] + red[11];
        const float mu = S * (1.f / 512.f);
        const float var = SS * (1.f / 512.f) - mu * mu;
        red[0] = mu;
        red[1] = rsqrtf(fmaxf(var, 0.f) + 1e-5f);
    }
    __syncthreads();
    const float mu = red[0], rstd = red[1];
    const float y0 = (a0 - mu) * rstd * g[i0]     + bb[i0];
    const float y1 = (a1 - mu) * rstd * g[i0 + 1] + bb[i0 + 1];
    if (out32) { out32[base + i0] = y0; out32[base + i0 + 1] = y1; }
    if (out16) { out16[base + i0] = __float2bfloat16(y0); out16[base + i0 + 1] = __float2bfloat16(y1); }
}

// ---------------------------------------------------------------------------
extern "C" void kernel_launch(void* const* d_in, const int* in_sizes, int n_in,
                              void* d_out, int out_size, void* d_ws, size_t ws_size,
                              hipStream_t stream)
{
    const float* q   = (const float*)d_in[0];
    const float* k   = (const float*)d_in[1];
    const float* v   = (const float*)d_in[2];
    const float* Wq  = (const float*)d_in[3];
    const float* bq  = (const float*)d_in[4];
    const float* Wk  = (const float*)d_in[5];
    const float* bk  = (const float*)d_in[6];
    const float* Wv  = (const float*)d_in[7];
    const float* bv  = (const float*)d_in[8];
    const float* Wo  = (const float*)d_in[9];
    const float* bo  = (const float*)d_in[10];
    const float* Wc1 = (const float*)d_in[11];
    const float* bc1 = (const float*)d_in[12];
    const float* Wc2 = (const float*)d_in[13];
    const float* bc2 = (const float*)d_in[14];
    const float* g1  = (const float*)d_in[15];
    const float* b1  = (const float*)d_in[16];
    const float* g2  = (const float*)d_in[17];
    const float* b2  = (const float*)d_in[18];
    const float* Wl  = (const float*)d_in[19];
    const float* bl  = (const float*)d_in[20];
    float* out = (float*)d_out;

    const int B = 4, L = 2048, H = 8;
    const int M = B * L;                        // 8192

    // Workspace map (bytes; peak 82.3 MB, liveness verified R9):
    char* base = (char*)d_ws;
    unsigned short* Wall = (unsigned short*)(base + 0);          // 6.8 MB, live all
    unsigned short* Wob  = (unsigned short*)(base + 1572864);
    unsigned short* Wlb  = (unsigned short*)(base + 2097152);
    unsigned short* Wc1b = (unsigned short*)(base + 2621440);
    unsigned short* Wc2b = (unsigned short*)(base + 4718592);
    unsigned short* Qb   = (unsigned short*)(base + 6815744);    // -> dead after attn
    unsigned short* Kb   = (unsigned short*)(base + 15204352);   // -> dead after attn
    unsigned short* Vt   = (unsigned short*)(base + 23592960);   // -> dead after attn
    unsigned short* A1   = (unsigned short*)(base + 31981568);   // -> dead after Wo
    float*          A2   = (float*)(base + 40370176);            // -> dead after LN1
    float*          X1   = (float*)(base + 57147392);            // live to LN2
    unsigned short* X1b  = (unsigned short*)(base + 73924608);   // -> dead after FFN1
    unsigned short* X2b  = (unsigned short*)(base + 73924608);   // reuse
    unsigned short* H1   = (unsigned short*)(base + 6815744);    // 33.5 MB over Qb..A1
    float*          Y2   = (float*)(base + 40370176);            // reuse A2

    const dim3 blk(256);

    // 1: weights fp32 -> bf16
    WArg wa;
    wa.w[0] = Wq; wa.w[1] = Wk; wa.w[2] = Wv; wa.w[3] = Wo; wa.w[4] = Wl;
    wa.w[5] = Wc1; wa.w[6] = Wc2; wa.wd = Wall;
    conv_w<<<dim3(3328), blk, 0, stream>>>(wa);

    // 2: batched QKV projections (fp32 A direct; z=2 writes Vt transposed)
    QkvArg qa;
    qa.A0 = q;  qa.A1 = k;  qa.A2 = v;
    qa.b0 = bq; qa.b1 = bk; qa.b2 = bv;
    qa.C0 = Qb; qa.C1 = Kb; qa.Vt = Vt;
    gemm_qkv<<<dim3(4, 64, 3), blk, 0, stream>>>(qa, Wall, M, 512, 512);

    // 3: flash attention v10 (barrier-free, K/V in registers) -> bf16
    attn_mfma<<<dim3(16, B * H), blk, 0, stream>>>(Qb, Kb, Vt, (__hip_bfloat16*)A1, L);

    // 4: att @ Wo^T + bo -> fp32
    gemm_mfma64<float, false><<<dim3(4, 128), blk, 0, stream>>>(A1, Wob, bo, A2, M, 512, 512);

    // 5: x = LN(v + attO) -> fp32 X1 + bf16 X1b
    layernorm_k<<<dim3(M), blk, 0, stream>>>(A2, nullptr, v, g1, b1, X1, (__hip_bfloat16*)X1b);

    // 6: h1 = relu(x @ Wc1^T + bc1) -> bf16 [M,2048]
    gemm_mfma<__hip_bfloat16, true><<<dim3(16, 64), blk, 0, stream>>>(X1b, Wc1b, bc1, (__hip_bfloat16*)H1, M, 2048, 512);

    // 7: y2 = h1 @ Wc2^T + bc2 -> fp32
    gemm_mfma64<float, false><<<dim3(4, 128), blk, 0, stream>>>(H1, Wc2b, bc2, Y2, M, 512, 2048);

    // 8: x2 = LN(x + y2) -> bf16
    layernorm_k<<<dim3(M), blk, 0, stream>>>(X1, Y2, nullptr, g2, b2, nullptr, (__hip_bfloat16*)X2b);

    // 9: out = x2 @ Wl^T + bl -> fp32 d_out
    gemm_mfma64<float, false><<<dim3(4, 128), blk, 0, stream>>>(X2b, Wlb, bl, out, M, 512, 512);
}

// Round 9
// 330.829 us; speedup vs baseline: 1.1681x; 1.1681x over previous
//
#include <hip/hip_runtime.h>
#include <hip/hip_bf16.h>

// Problem constants: B=4, L=2048, d_model=d_value=512, H=8, E=64, d4=2048.
// External inputs/output fp32. Internal compute: bf16 MFMA.
//
// R8 lesson (v10 regression 56->120 us): per-lane MFMA-fragment loads from
// global are strided gathers (lanes 1-4 KB apart = 64 tx/instr) even when
// L1-resident - transaction count, not bytes, is the cost. K/V must go
// through coalesced staging (v9). Reverted.
// R9 (v11): v9 staging + split-KV x2 (R1's verified partials+combine;
// fixed-max softmax makes partials additive) + LDS diet 50->25 KB
// (single-buffered K/V, ONE Ps buffer used serially B-then-A) so 4 blocks/CU
// fit. Grid (32,32): co-resident blocks share x -> identical round counts;
// worst-CU makespan drops 32 -> 16 rounds.

typedef __attribute__((ext_vector_type(8))) short sh8;    // 8 bf16 (A/B frag)
typedef __attribute__((ext_vector_type(4))) float f32x4;  // C/D frag

#define QSCALE 0.18033688011110543f   // 0.125 * log2(e): folded into Q projection

__device__ __forceinline__ void storeOut(float* p, float v) { *p = v; }
__device__ __forceinline__ void storeOut(__hip_bfloat16* p, float v) { *p = __float2bfloat16(v); }

// async global->LDS, 16 B per lane, wave-uniform LDS base (m97 pattern)
__device__ __forceinline__ void gl_lds16(const void* g, void* l) {
    __builtin_amdgcn_global_load_lds((const __attribute__((address_space(1))) void*)g,
                                     (__attribute__((address_space(3))) void*)l, 16, 0, 0);
}

// pack two fp32 into one dword of two bf16 (RNE)
__device__ __forceinline__ unsigned pk_bf16(float a, float b) {
    __hip_bfloat162 h = __float22bfloat162_rn(make_float2(a, b));
    return *(unsigned*)&h;
}
// 8 fp32 -> sh8 bf16 fragment
__device__ __forceinline__ sh8 pk8(float4 a, float4 b) {
    int4 iv = make_int4(pk_bf16(a.x, a.y), pk_bf16(a.z, a.w),
                        pk_bf16(b.x, b.y), pk_bf16(b.z, b.w));
    return *(sh8*)&iv;
}

// ---------------------------------------------------------------------------
// Weights fp32 -> bf16 into one contiguous ws region.
// Order: Wq,Wk,Wv,Wo,Wl,Wc1,Wc2 (3407872 elements).
// ---------------------------------------------------------------------------
struct WArg { const float* w[7]; unsigned short* wd; };
__global__ __launch_bounds__(256) void conv_w(WArg p)
{
    const int i = (blockIdx.x * 256 + threadIdx.x) * 4;
    if (i >= 3407872) return;
    const float* s; int off;
    if      (i < 262144)  { s = p.w[0]; off = i; }
    else if (i < 524288)  { s = p.w[1]; off = i - 262144; }
    else if (i < 786432)  { s = p.w[2]; off = i - 524288; }
    else if (i < 1048576) { s = p.w[3]; off = i - 786432; }
    else if (i < 1310720) { s = p.w[4]; off = i - 1048576; }
    else if (i < 2359296) { s = p.w[5]; off = i - 1310720; }
    else                  { s = p.w[6]; off = i - 2359296; }
    const float4 v = *(const float4*)(s + off);
    *(uint2*)(p.wd + i) = make_uint2(pk_bf16(v.x, v.y), pk_bf16(v.z, v.w));
}

// ---------------------------------------------------------------------------
// Batched QKV GEMM (grid.z = 0,1,2). A fp32 staged coalesced (16 lanes/row,
// chunk-XOR over 16); W bf16 (8 lanes/row, XOR over 8). BK=64.
// z=0: scaled by QSCALE -> Qb. z=1 -> Kb. z=2: written TRANSPOSED into
// Vt[B*H,64,L].
// ---------------------------------------------------------------------------
struct QkvArg {
    const float *A0, *A1, *A2;
    const float *b0, *b1, *b2;
    unsigned short *C0, *C1;      // Qb, Kb [B,L,H,64]
    unsigned short *Vt;           // [B*H,64,L]
};
__global__ __launch_bounds__(256) void gemm_qkv(QkvArg ar, const unsigned short* __restrict__ Wall,
                                                int M, int N, int K)
{
    const int z = blockIdx.z;
    const float* A = z == 0 ? ar.A0 : (z == 1 ? ar.A1 : ar.A2);
    const unsigned short* W = Wall + (size_t)z * 262144;
    const float* bias = z == 0 ? ar.b0 : (z == 1 ? ar.b1 : ar.b2);

    __shared__ float AsF[8192];            // 32 KB: [row:128][chunk:16][4 fp32] swz
    __shared__ unsigned short BsL[8192];   // 16 KB: [row:128][chunk:8][8 bf16] swz
    const int t    = threadIdx.x;
    const int wave = t >> 6, lane = t & 63;
    const int quad = lane >> 4, col = lane & 15;
    const int wm   = wave >> 1, wn = wave & 1;
    const int m0   = blockIdx.y * 128, n0 = blockIdx.x * 128;

    f32x4 acc[4][4];
    #pragma unroll
    for (int mt = 0; mt < 4; mt++)
        #pragma unroll
        for (int nt = 0; nt < 4; nt++)
            acc[mt][nt] = (f32x4){0.f, 0.f, 0.f, 0.f};

    for (int k0 = 0; k0 < K; k0 += 64) {
        #pragma unroll
        for (int seg = 0; seg < 8; seg++) {        // A fp32: 4 rows/instr, 256 B/row
            const int r0  = (seg * 4 + wave) * 4;  // wave-uniform
            const int row = r0 + (lane >> 4);
            const int ck  = (lane & 15) ^ (row & 15);
            gl_lds16(A + (size_t)(m0 + row) * K + k0 + ck * 4, &AsF[r0 * 64]);
        }
        #pragma unroll
        for (int seg = 0; seg < 4; seg++) {        // W bf16: 8 rows/instr, 128 B/row
            const int r0  = (seg * 4 + wave) * 8;
            const int row = r0 + (lane >> 3);
            const int ck  = (lane & 7) ^ (row & 7);
            gl_lds16(W + (size_t)(n0 + row) * K + k0 + ck * 8, &BsL[r0 * 64]);
        }
        __syncthreads();
        #pragma unroll
        for (int kc = 0; kc < 2; kc++) {
            sh8 af[4], bf[4];
            #pragma unroll
            for (int mt = 0; mt < 4; mt++) {
                const int mr  = wm * 64 + mt * 16 + col;
                const int q0  = kc * 8 + quad * 2;
                const int m16 = mr & 15;
                float4 f0 = *(const float4*)&AsF[mr * 64 + ((q0 ^ m16) << 2)];
                float4 f1 = *(const float4*)&AsF[mr * 64 + (((q0 + 1) ^ m16) << 2)];
                af[mt] = pk8(f0, f1);
            }
            #pragma unroll
            for (int nt = 0; nt < 4; nt++) {
                const int nr = wn * 64 + nt * 16 + col;
                bf[nt] = *(const sh8*)&BsL[nr * 64 + (((kc * 4 + quad) ^ (nr & 7)) << 3)];
            }
            #pragma unroll
            for (int mt = 0; mt < 4; mt++)
                #pragma unroll
                for (int nt = 0; nt < 4; nt++)
                    acc[mt][nt] = __builtin_amdgcn_mfma_f32_16x16x32_bf16(af[mt], bf[nt], acc[mt][nt], 0, 0, 0);
        }
        __syncthreads();
    }

    if (z < 2) {
        unsigned short* C = z == 0 ? ar.C0 : ar.C1;
        const float scale = z == 0 ? QSCALE : 1.0f;
        #pragma unroll
        for (int nt = 0; nt < 4; nt++) {
            const int cn = n0 + wn * 64 + nt * 16 + col;
            const float bj = bias[cn];
            #pragma unroll
            for (int mt = 0; mt < 4; mt++) {
                const int rm = m0 + wm * 64 + mt * 16 + quad * 4;
                #pragma unroll
                for (int reg = 0; reg < 4; reg++)
                    C[(size_t)(rm + reg) * N + cn] =
                        (unsigned short)__bfloat16_as_ushort(__float2bfloat16((acc[mt][nt][reg] + bj) * scale));
            }
        }
    } else {
        // V: write transposed [B*H, 64, L]; 4 consecutive s rows pack to 8 B.
        const int b = m0 >> 11;                    // L = 2048
        #pragma unroll
        for (int nt = 0; nt < 4; nt++) {
            const int cn = n0 + wn * 64 + nt * 16 + col;
            const int h = cn >> 6, e = cn & 63;
            const float bj = bias[cn];
            #pragma unroll
            for (int mt = 0; mt < 4; mt++) {
                const int s0r = (m0 + wm * 64 + mt * 16 + quad * 4) & 2047;
                float cv[4];
                #pragma unroll
                for (int reg = 0; reg < 4; reg++) cv[reg] = acc[mt][nt][reg] + bj;
                *(uint2*)(ar.Vt + ((size_t)(b * 8 + h) * 64 + e) * 2048 + s0r) =
                    make_uint2(pk_bf16(cv[0], cv[1]), pk_bf16(cv[2], cv[3]));
            }
        }
    }
}

// ---------------------------------------------------------------------------
// MFMA GEMM 128x128, BK=64 (FFN1): coalesced+swizzled staging (R6).
// ---------------------------------------------------------------------------
template <typename TOUT, bool RELU>
__global__ __launch_bounds__(256) void gemm_mfma(const unsigned short* __restrict__ A,
                                                 const unsigned short* __restrict__ W,
                                                 const float* __restrict__ bias,
                                                 TOUT* __restrict__ C,
                                                 int M, int N, int K)
{
    __shared__ unsigned short AsL[8192];   // [row:128][chunk:8][8 bf16] swz
    __shared__ unsigned short BsL[8192];
    const int t    = threadIdx.x;
    const int wave = t >> 6, lane = t & 63;
    const int quad = lane >> 4, col = lane & 15;
    const int wm   = wave >> 1, wn = wave & 1;
    const int m0   = blockIdx.y * 128, n0 = blockIdx.x * 128;

    f32x4 acc[4][4];
    #pragma unroll
    for (int mt = 0; mt < 4; mt++)
        #pragma unroll
        for (int nt = 0; nt < 4; nt++)
            acc[mt][nt] = (f32x4){0.f, 0.f, 0.f, 0.f};

    for (int k0 = 0; k0 < K; k0 += 64) {
        #pragma unroll
        for (int seg = 0; seg < 4; seg++) {
            const int r0  = (seg * 4 + wave) * 8;  // wave-uniform
            const int row = r0 + (lane >> 3);
            const int ck  = (lane & 7) ^ (row & 7);
            gl_lds16(A + (size_t)(m0 + row) * K + k0 + ck * 8, &AsL[r0 * 64]);
            gl_lds16(W + (size_t)(n0 + row) * K + k0 + ck * 8, &BsL[r0 * 64]);
        }
        __syncthreads();
        #pragma unroll
        for (int kc = 0; kc < 2; kc++) {
            sh8 af[4], bf[4];
            #pragma unroll
            for (int mt = 0; mt < 4; mt++) {
                const int ar = wm * 64 + mt * 16 + col;
                af[mt] = *(const sh8*)&AsL[ar * 64 + (((kc * 4 + quad) ^ (ar & 7)) << 3)];
            }
            #pragma unroll
            for (int nt = 0; nt < 4; nt++) {
                const int nr = wn * 64 + nt * 16 + col;
                bf[nt] = *(const sh8*)&BsL[nr * 64 + (((kc * 4 + quad) ^ (nr & 7)) << 3)];
            }
            #pragma unroll
            for (int mt = 0; mt < 4; mt++)
                #pragma unroll
                for (int nt = 0; nt < 4; nt++)
                    acc[mt][nt] = __builtin_amdgcn_mfma_f32_16x16x32_bf16(af[mt], bf[nt], acc[mt][nt], 0, 0, 0);
        }
        __syncthreads();
    }
    #pragma unroll
    for (int nt = 0; nt < 4; nt++) {
        const int cn = n0 + wn * 64 + nt * 16 + col;
        const float bj = bias[cn];
        #pragma unroll
        for (int mt = 0; mt < 4; mt++) {
            const int rm = m0 + wm * 64 + mt * 16 + quad * 4;
            #pragma unroll
            for (int reg = 0; reg < 4; reg++) {
                float cv = acc[mt][nt][reg] + bj;
                if (RELU) cv = fmaxf(cv, 0.f);
                storeOut(&C[(size_t)(rm + reg) * N + cn], cv);
            }
        }
    }
}

// ---------------------------------------------------------------------------
// MFMA GEMM 64x128 tile, BK=64: coalesced+swizzled staging (R6).
// ---------------------------------------------------------------------------
template <typename TOUT, bool RELU>
__global__ __launch_bounds__(256) void gemm_mfma64(const unsigned short* __restrict__ A,
                                                   const unsigned short* __restrict__ W,
                                                   const float* __restrict__ bias,
                                                   TOUT* __restrict__ C,
                                                   int M, int N, int K)
{
    __shared__ unsigned short AsL[4096];   // [row:64][chunk:8][8 bf16] swz
    __shared__ unsigned short BsL[8192];
    const int t    = threadIdx.x;
    const int wave = t >> 6, lane = t & 63;
    const int quad = lane >> 4, col = lane & 15;
    const int wm   = wave >> 1, wn = wave & 1;
    const int m0   = blockIdx.y * 64, n0 = blockIdx.x * 128;

    f32x4 acc[2][4];
    #pragma unroll
    for (int mt = 0; mt < 2; mt++)
        #pragma unroll
        for (int nt = 0; nt < 4; nt++)
            acc[mt][nt] = (f32x4){0.f, 0.f, 0.f, 0.f};

    for (int k0 = 0; k0 < K; k0 += 64) {
        #pragma unroll
        for (int seg = 0; seg < 2; seg++) {
            const int r0  = (seg * 4 + wave) * 8;  // wave-uniform, 0..56
            const int row = r0 + (lane >> 3);
            const int ck  = (lane & 7) ^ (row & 7);
            gl_lds16(A + (size_t)(m0 + row) * K + k0 + ck * 8, &AsL[r0 * 64]);
        }
        #pragma unroll
        for (int seg = 0; seg < 4; seg++) {
            const int r0  = (seg * 4 + wave) * 8;
            const int row = r0 + (lane >> 3);
            const int ck  = (lane & 7) ^ (row & 7);
            gl_lds16(W + (size_t)(n0 + row) * K + k0 + ck * 8, &BsL[r0 * 64]);
        }
        __syncthreads();
        #pragma unroll
        for (int kc = 0; kc < 2; kc++) {
            sh8 af[2], bf[4];
            #pragma unroll
            for (int mt = 0; mt < 2; mt++) {
                const int ar = wm * 32 + mt * 16 + col;
                af[mt] = *(const sh8*)&AsL[ar * 64 + (((kc * 4 + quad) ^ (ar & 7)) << 3)];
            }
            #pragma unroll
            for (int nt = 0; nt < 4; nt++) {
                const int nr = wn * 64 + nt * 16 + col;
                bf[nt] = *(const sh8*)&BsL[nr * 64 + (((kc * 4 + quad) ^ (nr & 7)) << 3)];
            }
            #pragma unroll
            for (int mt = 0; mt < 2; mt++)
                #pragma unroll
                for (int nt = 0; nt < 4; nt++)
                    acc[mt][nt] = __builtin_amdgcn_mfma_f32_16x16x32_bf16(af[mt], bf[nt], acc[mt][nt], 0, 0, 0);
        }
        __syncthreads();
    }
    #pragma unroll
    for (int nt = 0; nt < 4; nt++) {
        const int cn = n0 + wn * 64 + nt * 16 + col;
        const float bj = bias[cn];
        #pragma unroll
        for (int mt = 0; mt < 2; mt++) {
            const int rm = m0 + wm * 32 + mt * 16 + quad * 4;
            #pragma unroll
            for (int reg = 0; reg < 4; reg++) {
                float cv = acc[mt][nt][reg] + bj;
                if (RELU) cv = fmaxf(cv, 0.f);
                storeOut(&C[(size_t)(rm + reg) * N + cn], cv);
            }
        }
    }
}

// ---------------------------------------------------------------------------
// MFMA flash attention v11 (causal, reverse-paired tiles, split-KV x2,
// coalesced staging). Block (x,y): i = x>>1 (pair (i,31-i)), sp = x&1.
// S = 32-i rounds total; split sp covers [sp? h0:0, sp? S:h0), h0=(S+1)/2
// -> every block runs 8..16 rounds; co-resident blocks share x -> uniform
// per-CU load; worst-CU makespan 16 rounds (v9: 32).
// LDS 25 KB (K/V single-buffered + ONE Ps used serially B-then-A; Ps is
// per-wave private so no extra sync) -> 4 blocks/CU.
// FIXED-MAX softmax (m=0): partials additive, O = O0+O1, l = l0+l1
// (combined by attn_combine). Masking depends only on absolute r.
// Qb/Kb: [B,L,H,64] bf16; Vt: [B*H,64,L] bf16.
// Op: fp32 [2][B,L,H,64]; Lp: fp32 [2][B,L,H].
// ---------------------------------------------------------------------------
__global__ __launch_bounds__(256, 2) void attn_mfma(const unsigned short* __restrict__ Qb,
                                                    const unsigned short* __restrict__ Kb,
                                                    const unsigned short* __restrict__ Vt,
                                                    float* __restrict__ Op,
                                                    float* __restrict__ Lp,
                                                    int L)
{
    __shared__ unsigned short Ks[4096];          // [key:64][e-chunk swz] 8 KB
    __shared__ unsigned short Vs[4096];          // [e:64][key-chunk swz] 8 KB
    __shared__ unsigned short Ps[4][16][72];     // per wave [qrow:16][key:64+pad] 9 KB

    const int x    = blockIdx.x;                 // 0..31 (x=0,1 -> i=0 heaviest first)
    const int i    = x >> 1;
    const int sp   = x & 1;
    const int bh   = blockIdx.y;
    const int b    = bh >> 3, h = bh & 7;        // H = 8
    const int t    = threadIdx.x;
    const int w    = t >> 6, lane = t & 63;
    const int quad = lane >> 4, col = lane & 15;

    const int qtA = i, qtB = 31 - i;             // light / heavy tile
    const int qrowA = qtA * 64 + w * 16 + col;
    const int qrowB = qtB * 64 + w * 16 + col;
    const int S  = 32 - i;                       // total rounds for the pair
    const int h0 = (S + 1) >> 1;
    const int r0 = sp ? h0 : 0;
    const int r1 = sp ? S : h0;

    // staging lane decomposition: 8 lanes cover one 128 B row
    const int srow = lane >> 3;
    const int scp  = lane & 7;

    // Q B-frags (QSCALE pre-applied in projection)
    sh8 qfA[2], qfB[2];
    {
        const size_t qa = ((size_t)(b * L + qrowA) * 8 + h) * 64;
        qfA[0] = *(const sh8*)(Qb + qa + quad * 8);
        qfA[1] = *(const sh8*)(Qb + qa + 32 + quad * 8);
        const size_t qb2 = ((size_t)(b * L + qrowB) * 8 + h) * 64;
        qfB[0] = *(const sh8*)(Qb + qb2 + quad * 8);
        qfB[1] = *(const sh8*)(Qb + qb2 + 32 + quad * 8);
    }

    f32x4 OA[4], OB[4];
    #pragma unroll
    for (int nt = 0; nt < 4; nt++) { OA[nt] = (f32x4){0.f,0.f,0.f,0.f}; OB[nt] = (f32x4){0.f,0.f,0.f,0.f}; }
    float lA = 0.f, lB = 0.f;

    for (int r = r0; r < r1; r++) {
        const int k0 = r * 64;
        // ---- coalesced, source-swizzled staging of this round's K/V
        #pragma unroll
        for (int seg = 0; seg < 2; seg++) {
            const int rr  = (seg * 4 + w) * 8;   // wave-uniform row base
            const int row = rr + srow;
            const int ck  = scp ^ (row & 7);     // involution
            gl_lds16(Kb + ((size_t)(b * L + k0 + row) * 8 + h) * 64 + ck * 8, &Ks[rr * 64]);
            gl_lds16(Vt + (size_t)(bh * 64 + row) * L + k0 + ck * 8, &Vs[rr * 64]);
        }
        __syncthreads();

        const bool actA  = (r <= i);
        const bool maskA = (r == i);
        const bool maskB = (r == S - 1);

        // ---- S^T for both tiles (K-frags read once)
        f32x4 stA[4], stB[4];
        const f32x4 zz = {0.f, 0.f, 0.f, 0.f};
        #pragma unroll
        for (int ntk = 0; ntk < 4; ntk++) {
            const int key = ntk * 16 + col;
            const int sw  = key & 7;
            sh8 kf0 = *(const sh8*)&Ks[key * 64 + ((quad ^ sw) << 3)];
            sh8 kf1 = *(const sh8*)&Ks[key * 64 + (((quad + 4) ^ sw) << 3)];
            f32x4 aB = __builtin_amdgcn_mfma_f32_16x16x32_bf16(kf0, qfB[0], zz, 0, 0, 0);
            stB[ntk] = __builtin_amdgcn_mfma_f32_16x16x32_bf16(kf1, qfB[1], aB, 0, 0, 0);
            if (actA) {
                f32x4 aA = __builtin_amdgcn_mfma_f32_16x16x32_bf16(kf0, qfA[0], zz, 0, 0, 0);
                stA[ntk] = __builtin_amdgcn_mfma_f32_16x16x32_bf16(kf1, qfA[1], aA, 0, 0, 0);
            }
        }

        // ---- tile B: softmax -> Ps -> PV
        {
            if (maskB) {
                #pragma unroll
                for (int ntk = 0; ntk < 4; ntk++)
                    #pragma unroll
                    for (int reg = 0; reg < 4; reg++)
                        if (k0 + ntk * 16 + quad * 4 + reg > qrowB) stB[ntk][reg] = -1e30f;
            }
            #pragma unroll
            for (int ntk = 0; ntk < 4; ntk++) {
                #pragma unroll
                for (int reg = 0; reg < 4; reg++)
                    stB[ntk][reg] = exp2f(stB[ntk][reg]);
                lB += (stB[ntk][0] + stB[ntk][1]) + (stB[ntk][2] + stB[ntk][3]);
                *(uint2*)&Ps[w][col][ntk * 16 + quad * 4] =
                    make_uint2(pk_bf16(stB[ntk][0], stB[ntk][1]), pk_bf16(stB[ntk][2], stB[ntk][3]));
            }
            #pragma unroll
            for (int kchunk = 0; kchunk < 2; kchunk++) {
                sh8 pf = *(const sh8*)&Ps[w][col][kchunk * 32 + quad * 8];
                #pragma unroll
                for (int nt = 0; nt < 4; nt++) {
                    const int e = nt * 16 + col;
                    sh8 vf = *(const sh8*)&Vs[e * 64 + (((kchunk * 4 + quad) ^ (e & 7)) << 3)];
                    OB[nt] = __builtin_amdgcn_mfma_f32_16x16x32_bf16(pf, vf, OB[nt], 0, 0, 0);
                }
            }
        }

        // ---- tile A: softmax -> Ps (reuse) -> PV   (per-wave private Ps)
        if (actA) {
            if (maskA) {
                #pragma unroll
                for (int ntk = 0; ntk < 4; ntk++)
                    #pragma unroll
                    for (int reg = 0; reg < 4; reg++)
                        if (k0 + ntk * 16 + quad * 4 + reg > qrowA) stA[ntk][reg] = -1e30f;
            }
            #pragma unroll
            for (int ntk = 0; ntk < 4; ntk++) {
                #pragma unroll
                for (int reg = 0; reg < 4; reg++)
                    stA[ntk][reg] = exp2f(stA[ntk][reg]);
                lA += (stA[ntk][0] + stA[ntk][1]) + (stA[ntk][2] + stA[ntk][3]);
                *(uint2*)&Ps[w][col][ntk * 16 + quad * 4] =
                    make_uint2(pk_bf16(stA[ntk][0], stA[ntk][1]), pk_bf16(stA[ntk][2], stA[ntk][3]));
            }
            #pragma unroll
            for (int kchunk = 0; kchunk < 2; kchunk++) {
                sh8 pf = *(const sh8*)&Ps[w][col][kchunk * 32 + quad * 8];
                #pragma unroll
                for (int nt = 0; nt < 4; nt++) {
                    const int e = nt * 16 + col;
                    sh8 vf = *(const sh8*)&Vs[e * 64 + (((kchunk * 4 + quad) ^ (e & 7)) << 3)];
                    OA[nt] = __builtin_amdgcn_mfma_f32_16x16x32_bf16(pf, vf, OA[nt], 0, 0, 0);
                }
            }
        }
        __syncthreads();                          // protect Ks/Vs for next round
    }

    // ---- epilogue: reduce l across quads, store fp32 partial O and l
    lA += __shfl_xor(lA, 16); lA += __shfl_xor(lA, 32);
    lB += __shfl_xor(lB, 16); lB += __shfl_xor(lB, 32);
    {
        float* Od = Op + (size_t)sp * 4194304;    // 8192*512 per split
        float* Ld = Lp + (size_t)sp * 65536;      // 8192*8 per split
        if (quad == 0) {
            Ld[(size_t)(b * L + qtA * 64 + w * 16 + col) * 8 + h] = lA;
            Ld[(size_t)(b * L + qtB * 64 + w * 16 + col) * 8 + h] = lB;
        }
        #pragma unroll
        for (int reg = 0; reg < 4; reg++) {
            const int qrA = qtA * 64 + w * 16 + quad * 4 + reg;
            const int qrB = qtB * 64 + w * 16 + quad * 4 + reg;
            #pragma unroll
            for (int nt = 0; nt < 4; nt++) {
                Od[((size_t)(b * L + qrA) * 8 + h) * 64 + nt * 16 + col] = OA[nt][reg];
                Od[((size_t)(b * L + qrB) * 8 + h) * 64 + nt * 16 + col] = OB[nt][reg];
            }
        }
    }
}

// ---------------------------------------------------------------------------
// Combine split-KV partials: O = (O0+O1)/(l0+l1), bf16 out. Pure streaming:
// 32 MB read + 0.5 MB l + 8 MB write. (R1-verified.)
// ---------------------------------------------------------------------------
__global__ __launch_bounds__(256) void attn_combine(const float* __restrict__ Op,
                                                    const float* __restrict__ Lp,
                                                    unsigned short* __restrict__ O)
{
    const int row = blockIdx.x;                  // b*L + l, 8192 rows
    const int t   = threadIdx.x;
    const int e   = t * 2;                       // 0..510
    const int h   = e >> 6;
    const float l0 = Lp[(size_t)row * 8 + h];
    const float l1 = Lp[65536 + (size_t)row * 8 + h];
    const float inv = 1.f / (l0 + l1);
    const size_t idx = (size_t)row * 512 + e;
    const float2 o0 = *(const float2*)(Op + idx);
    const float2 o1 = *(const float2*)(Op + 4194304 + idx);
    *(unsigned*)&O[idx] = pk_bf16((o0.x + o1.x) * inv, (o0.y + o1.y) * inv);
}

// ---------------------------------------------------------------------------
// LayerNorm over last dim (512). x = f1 [+ f2] [+ rb]. Dual output.
// ---------------------------------------------------------------------------
__global__ __launch_bounds__(256) void layernorm_k(const float* __restrict__ f1,
                                                   const float* __restrict__ f2,
                                                   const float* __restrict__ rb,
                                                   const float* __restrict__ g,
                                                   const float* __restrict__ bb,
                                                   float* __restrict__ out32,
                                                   __hip_bfloat16* __restrict__ out16)
{
    const int row = blockIdx.x;
    const int t   = threadIdx.x;
    const size_t base = (size_t)row * 512;
    const int i0 = t * 2;

    float a0 = f1[base + i0], a1 = f1[base + i0 + 1];
    if (f2) { a0 += f2[base + i0]; a1 += f2[base + i0 + 1]; }
    if (rb) { a0 += rb[base + i0]; a1 += rb[base + i0 + 1]; }

    float s = a0 + a1, ss = a0 * a0 + a1 * a1;
    #pragma unroll
    for (int off = 32; off > 0; off >>= 1) {
        s  += __shfl_xor(s, off);
        ss += __shfl_xor(ss, off);
    }
    __shared__ float red[16];
    const int lane = t & 63, wid = t >> 6;
    if (lane == 0) { red[wid] = s; red[8 + wid] = ss; }
    __syncthreads();
    if (t == 0) {
        const float S  = red[0] + red[1] + red[2] + red[3];
        const float SS = red[8] + red[9] + red[10] + red[11];
        const float mu = S * (1.f / 512.f);
        const float var = SS * (1.f / 512.f) - mu * mu;
        red[0] = mu;
        red[1] = rsqrtf(fmaxf(var, 0.f) + 1e-5f);
    }
    __syncthreads();
    const float mu = red[0], rstd = red[1];
    const float y0 = (a0 - mu) * rstd * g[i0]     + bb[i0];
    const float y1 = (a1 - mu) * rstd * g[i0 + 1] + bb[i0 + 1];
    if (out32) { out32[base + i0] = y0; out32[base + i0 + 1] = y1; }
    if (out16) { out16[base + i0] = __float2bfloat16(y0); out16[base + i0 + 1] = __float2bfloat16(y1); }
}

// ---------------------------------------------------------------------------
extern "C" void kernel_launch(void* const* d_in, const int* in_sizes, int n_in,
                              void* d_out, int out_size, void* d_ws, size_t ws_size,
                              hipStream_t stream)
{
    const float* q   = (const float*)d_in[0];
    const float* k   = (const float*)d_in[1];
    const float* v   = (const float*)d_in[2];
    const float* Wq  = (const float*)d_in[3];
    const float* bq  = (const float*)d_in[4];
    const float* Wk  = (const float*)d_in[5];
    const float* bk  = (const float*)d_in[6];
    const float* Wv  = (const float*)d_in[7];
    const float* bv  = (const float*)d_in[8];
    const float* Wo  = (const float*)d_in[9];
    const float* bo  = (const float*)d_in[10];
    const float* Wc1 = (const float*)d_in[11];
    const float* bc1 = (const float*)d_in[12];
    const float* Wc2 = (const float*)d_in[13];
    const float* bc2 = (const float*)d_in[14];
    const float* g1  = (const float*)d_in[15];
    const float* b1  = (const float*)d_in[16];
    const float* g2  = (const float*)d_in[17];
    const float* b2  = (const float*)d_in[18];
    const float* Wl  = (const float*)d_in[19];
    const float* bl  = (const float*)d_in[20];
    float* out = (float*)d_out;

    const int B = 4, L = 2048, H = 8;
    const int M = B * L;                        // 8192

    // Workspace map (bytes; peak 82.3 MB):
    //   Attn partials Op (33.5 MB) overlay A2+X1 (dead during attn); Lp
    //   (512 KB) overlays X1b. A1 (combine output) untouched by partials.
    //   (R1-verified overlay.)
    char* base = (char*)d_ws;
    unsigned short* Wall = (unsigned short*)(base + 0);          // 6.8 MB, live all
    unsigned short* Wob  = (unsigned short*)(base + 1572864);
    unsigned short* Wlb  = (unsigned short*)(base + 2097152);
    unsigned short* Wc1b = (unsigned short*)(base + 2621440);
    unsigned short* Wc2b = (unsigned short*)(base + 4718592);
    unsigned short* Qb   = (unsigned short*)(base + 6815744);    // -> dead after attn
    unsigned short* Kb   = (unsigned short*)(base + 15204352);   // -> dead after attn
    unsigned short* Vt   = (unsigned short*)(base + 23592960);   // -> dead after attn
    unsigned short* A1   = (unsigned short*)(base + 31981568);   // attn out (combine)
    float*          Oprt = (float*)(base + 40370176);            // 33.5 MB partials
    float*          Lprt = (float*)(base + 73924608);            // 512 KB partial l
    float*          A2   = (float*)(base + 40370176);            // -> dead after LN1
    float*          X1   = (float*)(base + 57147392);            // live to LN2
    unsigned short* X1b  = (unsigned short*)(base + 73924608);   // -> dead after FFN1
    unsigned short* X2b  = (unsigned short*)(base + 73924608);   // reuse
    unsigned short* H1   = (unsigned short*)(base + 6815744);    // 33.5 MB over Qb..A1
    float*          Y2   = (float*)(base + 40370176);            // reuse A2

    const dim3 blk(256);

    // 1: weights fp32 -> bf16
    WArg wa;
    wa.w[0] = Wq; wa.w[1] = Wk; wa.w[2] = Wv; wa.w[3] = Wo; wa.w[4] = Wl;
    wa.w[5] = Wc1; wa.w[6] = Wc2; wa.wd = Wall;
    conv_w<<<dim3(3328), blk, 0, stream>>>(wa);

    // 2: batched QKV projections (fp32 A direct; z=2 writes Vt transposed)
    QkvArg qa;
    qa.A0 = q;  qa.A1 = k;  qa.A2 = v;
    qa.b0 = bq; qa.b1 = bk; qa.b2 = bv;
    qa.C0 = Qb; qa.C1 = Kb; qa.Vt = Vt;
    gemm_qkv<<<dim3(4, 64, 3), blk, 0, stream>>>(qa, Wall, M, 512, 512);

    // 3: flash attention v11 (split-KV x2, 4 blocks/CU) -> fp32 partials
    attn_mfma<<<dim3(32, B * H), blk, 0, stream>>>(Qb, Kb, Vt, Oprt, Lprt, L);

    // 3b: combine partials -> bf16 A1
    attn_combine<<<dim3(M), blk, 0, stream>>>(Oprt, Lprt, A1);

    // 4: att @ Wo^T + bo -> fp32
    gemm_mfma64<float, false><<<dim3(4, 128), blk, 0, stream>>>(A1, Wob, bo, A2, M, 512, 512);

    // 5: x = LN(v + attO) -> fp32 X1 + bf16 X1b
    layernorm_k<<<dim3(M), blk, 0, stream>>>(A2, nullptr, v, g1, b1, X1, (__hip_bfloat16*)X1b);

    // 6: h1 = relu(x @ Wc1^T + bc1) -> bf16 [M,2048]
    gemm_mfma<__hip_bfloat16, true><<<dim3(16, 64), blk, 0, stream>>>(X1b, Wc1b, bc1, (__hip_bfloat16*)H1, M, 2048, 512);

    // 7: y2 = h1 @ Wc2^T + bc2 -> fp32
    gemm_mfma64<float, false><<<dim3(4, 128), blk, 0, stream>>>(H1, Wc2b, bc2, Y2, M, 512, 2048);

    // 8: x2 = LN(x + y2) -> bf16
    layernorm_k<<<dim3(M), blk, 0, stream>>>(X1, Y2, nullptr, g2, b2, nullptr, (__hip_bfloat16*)X2b);

    // 9: out = x2 @ Wl^T + bl -> fp32 d_out
    gemm_mfma64<float, false><<<dim3(4, 128), blk, 0, stream>>>(X2b, Wlb, bl, out, M, 512, 512);
}

// Round 10
// 329.478 us; speedup vs baseline: 1.1729x; 1.0041x over previous
//
#include <hip/hip_runtime.h>
#include <hip/hip_bf16.h>

// Problem constants: B=4, L=2048, d_model=d_value=512, H=8, E=64, d4=2048.
// External inputs/output fp32. Internal compute: bf16 MFMA.
//
// R9 lesson: split-KV x2 with SINGLE-buffered K/V gained nothing - the
// per-round vmcnt(0)-before-compute exposed the staging latency (~2x cost
// per round), exactly cancelling the halved round count. v12 keeps BOTH:
// split-KV x2 (16-round makespan) AND v9's double-buffer (1 barrier/round,
// staging hidden under compute). LDS = 2x8K K + 2x8K V + 9K single-Ps
// (used serially B-then-A, per-wave private) = 41 KB -> 3 blocks/CU.

typedef __attribute__((ext_vector_type(8))) short sh8;    // 8 bf16 (A/B frag)
typedef __attribute__((ext_vector_type(4))) float f32x4;  // C/D frag

#define QSCALE 0.18033688011110543f   // 0.125 * log2(e): folded into Q projection

__device__ __forceinline__ void storeOut(float* p, float v) { *p = v; }
__device__ __forceinline__ void storeOut(__hip_bfloat16* p, float v) { *p = __float2bfloat16(v); }

// async global->LDS, 16 B per lane, wave-uniform LDS base (m97 pattern)
__device__ __forceinline__ void gl_lds16(const void* g, void* l) {
    __builtin_amdgcn_global_load_lds((const __attribute__((address_space(1))) void*)g,
                                     (__attribute__((address_space(3))) void*)l, 16, 0, 0);
}

// pack two fp32 into one dword of two bf16 (RNE)
__device__ __forceinline__ unsigned pk_bf16(float a, float b) {
    __hip_bfloat162 h = __float22bfloat162_rn(make_float2(a, b));
    return *(unsigned*)&h;
}
// 8 fp32 -> sh8 bf16 fragment
__device__ __forceinline__ sh8 pk8(float4 a, float4 b) {
    int4 iv = make_int4(pk_bf16(a.x, a.y), pk_bf16(a.z, a.w),
                        pk_bf16(b.x, b.y), pk_bf16(b.z, b.w));
    return *(sh8*)&iv;
}

// ---------------------------------------------------------------------------
// Weights fp32 -> bf16 into one contiguous ws region.
// Order: Wq,Wk,Wv,Wo,Wl,Wc1,Wc2 (3407872 elements).
// ---------------------------------------------------------------------------
struct WArg { const float* w[7]; unsigned short* wd; };
__global__ __launch_bounds__(256) void conv_w(WArg p)
{
    const int i = (blockIdx.x * 256 + threadIdx.x) * 4;
    if (i >= 3407872) return;
    const float* s; int off;
    if      (i < 262144)  { s = p.w[0]; off = i; }
    else if (i < 524288)  { s = p.w[1]; off = i - 262144; }
    else if (i < 786432)  { s = p.w[2]; off = i - 524288; }
    else if (i < 1048576) { s = p.w[3]; off = i - 786432; }
    else if (i < 1310720) { s = p.w[4]; off = i - 1048576; }
    else if (i < 2359296) { s = p.w[5]; off = i - 1310720; }
    else                  { s = p.w[6]; off = i - 2359296; }
    const float4 v = *(const float4*)(s + off);
    *(uint2*)(p.wd + i) = make_uint2(pk_bf16(v.x, v.y), pk_bf16(v.z, v.w));
}

// ---------------------------------------------------------------------------
// Batched QKV GEMM (grid.z = 0,1,2). A fp32 staged coalesced (16 lanes/row,
// chunk-XOR over 16); W bf16 (8 lanes/row, XOR over 8). BK=64.
// z=0: scaled by QSCALE -> Qb. z=1 -> Kb. z=2: written TRANSPOSED into
// Vt[B*H,64,L].
// ---------------------------------------------------------------------------
struct QkvArg {
    const float *A0, *A1, *A2;
    const float *b0, *b1, *b2;
    unsigned short *C0, *C1;      // Qb, Kb [B,L,H,64]
    unsigned short *Vt;           // [B*H,64,L]
};
__global__ __launch_bounds__(256) void gemm_qkv(QkvArg ar, const unsigned short* __restrict__ Wall,
                                                int M, int N, int K)
{
    const int z = blockIdx.z;
    const float* A = z == 0 ? ar.A0 : (z == 1 ? ar.A1 : ar.A2);
    const unsigned short* W = Wall + (size_t)z * 262144;
    const float* bias = z == 0 ? ar.b0 : (z == 1 ? ar.b1 : ar.b2);

    __shared__ float AsF[8192];            // 32 KB: [row:128][chunk:16][4 fp32] swz
    __shared__ unsigned short BsL[8192];   // 16 KB: [row:128][chunk:8][8 bf16] swz
    const int t    = threadIdx.x;
    const int wave = t >> 6, lane = t & 63;
    const int quad = lane >> 4, col = lane & 15;
    const int wm   = wave >> 1, wn = wave & 1;
    const int m0   = blockIdx.y * 128, n0 = blockIdx.x * 128;

    f32x4 acc[4][4];
    #pragma unroll
    for (int mt = 0; mt < 4; mt++)
        #pragma unroll
        for (int nt = 0; nt < 4; nt++)
            acc[mt][nt] = (f32x4){0.f, 0.f, 0.f, 0.f};

    for (int k0 = 0; k0 < K; k0 += 64) {
        #pragma unroll
        for (int seg = 0; seg < 8; seg++) {        // A fp32: 4 rows/instr, 256 B/row
            const int r0  = (seg * 4 + wave) * 4;  // wave-uniform
            const int row = r0 + (lane >> 4);
            const int ck  = (lane & 15) ^ (row & 15);
            gl_lds16(A + (size_t)(m0 + row) * K + k0 + ck * 4, &AsF[r0 * 64]);
        }
        #pragma unroll
        for (int seg = 0; seg < 4; seg++) {        // W bf16: 8 rows/instr, 128 B/row
            const int r0  = (seg * 4 + wave) * 8;
            const int row = r0 + (lane >> 3);
            const int ck  = (lane & 7) ^ (row & 7);
            gl_lds16(W + (size_t)(n0 + row) * K + k0 + ck * 8, &BsL[r0 * 64]);
        }
        __syncthreads();
        #pragma unroll
        for (int kc = 0; kc < 2; kc++) {
            sh8 af[4], bf[4];
            #pragma unroll
            for (int mt = 0; mt < 4; mt++) {
                const int mr  = wm * 64 + mt * 16 + col;
                const int q0  = kc * 8 + quad * 2;
                const int m16 = mr & 15;
                float4 f0 = *(const float4*)&AsF[mr * 64 + ((q0 ^ m16) << 2)];
                float4 f1 = *(const float4*)&AsF[mr * 64 + (((q0 + 1) ^ m16) << 2)];
                af[mt] = pk8(f0, f1);
            }
            #pragma unroll
            for (int nt = 0; nt < 4; nt++) {
                const int nr = wn * 64 + nt * 16 + col;
                bf[nt] = *(const sh8*)&BsL[nr * 64 + (((kc * 4 + quad) ^ (nr & 7)) << 3)];
            }
            #pragma unroll
            for (int mt = 0; mt < 4; mt++)
                #pragma unroll
                for (int nt = 0; nt < 4; nt++)
                    acc[mt][nt] = __builtin_amdgcn_mfma_f32_16x16x32_bf16(af[mt], bf[nt], acc[mt][nt], 0, 0, 0);
        }
        __syncthreads();
    }

    if (z < 2) {
        unsigned short* C = z == 0 ? ar.C0 : ar.C1;
        const float scale = z == 0 ? QSCALE : 1.0f;
        #pragma unroll
        for (int nt = 0; nt < 4; nt++) {
            const int cn = n0 + wn * 64 + nt * 16 + col;
            const float bj = bias[cn];
            #pragma unroll
            for (int mt = 0; mt < 4; mt++) {
                const int rm = m0 + wm * 64 + mt * 16 + quad * 4;
                #pragma unroll
                for (int reg = 0; reg < 4; reg++)
                    C[(size_t)(rm + reg) * N + cn] =
                        (unsigned short)__bfloat16_as_ushort(__float2bfloat16((acc[mt][nt][reg] + bj) * scale));
            }
        }
    } else {
        // V: write transposed [B*H, 64, L]; 4 consecutive s rows pack to 8 B.
        const int b = m0 >> 11;                    // L = 2048
        #pragma unroll
        for (int nt = 0; nt < 4; nt++) {
            const int cn = n0 + wn * 64 + nt * 16 + col;
            const int h = cn >> 6, e = cn & 63;
            const float bj = bias[cn];
            #pragma unroll
            for (int mt = 0; mt < 4; mt++) {
                const int s0r = (m0 + wm * 64 + mt * 16 + quad * 4) & 2047;
                float cv[4];
                #pragma unroll
                for (int reg = 0; reg < 4; reg++) cv[reg] = acc[mt][nt][reg] + bj;
                *(uint2*)(ar.Vt + ((size_t)(b * 8 + h) * 64 + e) * 2048 + s0r) =
                    make_uint2(pk_bf16(cv[0], cv[1]), pk_bf16(cv[2], cv[3]));
            }
        }
    }
}

// ---------------------------------------------------------------------------
// MFMA GEMM 128x128, BK=64 (FFN1): coalesced+swizzled staging (R6).
// ---------------------------------------------------------------------------
template <typename TOUT, bool RELU>
__global__ __launch_bounds__(256) void gemm_mfma(const unsigned short* __restrict__ A,
                                                 const unsigned short* __restrict__ W,
                                                 const float* __restrict__ bias,
                                                 TOUT* __restrict__ C,
                                                 int M, int N, int K)
{
    __shared__ unsigned short AsL[8192];   // [row:128][chunk:8][8 bf16] swz
    __shared__ unsigned short BsL[8192];
    const int t    = threadIdx.x;
    const int wave = t >> 6, lane = t & 63;
    const int quad = lane >> 4, col = lane & 15;
    const int wm   = wave >> 1, wn = wave & 1;
    const int m0   = blockIdx.y * 128, n0 = blockIdx.x * 128;

    f32x4 acc[4][4];
    #pragma unroll
    for (int mt = 0; mt < 4; mt++)
        #pragma unroll
        for (int nt = 0; nt < 4; nt++)
            acc[mt][nt] = (f32x4){0.f, 0.f, 0.f, 0.f};

    for (int k0 = 0; k0 < K; k0 += 64) {
        #pragma unroll
        for (int seg = 0; seg < 4; seg++) {
            const int r0  = (seg * 4 + wave) * 8;  // wave-uniform
            const int row = r0 + (lane >> 3);
            const int ck  = (lane & 7) ^ (row & 7);
            gl_lds16(A + (size_t)(m0 + row) * K + k0 + ck * 8, &AsL[r0 * 64]);
            gl_lds16(W + (size_t)(n0 + row) * K + k0 + ck * 8, &BsL[r0 * 64]);
        }
        __syncthreads();
        #pragma unroll
        for (int kc = 0; kc < 2; kc++) {
            sh8 af[4], bf[4];
            #pragma unroll
            for (int mt = 0; mt < 4; mt++) {
                const int ar = wm * 64 + mt * 16 + col;
                af[mt] = *(const sh8*)&AsL[ar * 64 + (((kc * 4 + quad) ^ (ar & 7)) << 3)];
            }
            #pragma unroll
            for (int nt = 0; nt < 4; nt++) {
                const int nr = wn * 64 + nt * 16 + col;
                bf[nt] = *(const sh8*)&BsL[nr * 64 + (((kc * 4 + quad) ^ (nr & 7)) << 3)];
            }
            #pragma unroll
            for (int mt = 0; mt < 4; mt++)
                #pragma unroll
                for (int nt = 0; nt < 4; nt++)
                    acc[mt][nt] = __builtin_amdgcn_mfma_f32_16x16x32_bf16(af[mt], bf[nt], acc[mt][nt], 0, 0, 0);
        }
        __syncthreads();
    }
    #pragma unroll
    for (int nt = 0; nt < 4; nt++) {
        const int cn = n0 + wn * 64 + nt * 16 + col;
        const float bj = bias[cn];
        #pragma unroll
        for (int mt = 0; mt < 4; mt++) {
            const int rm = m0 + wm * 64 + mt * 16 + quad * 4;
            #pragma unroll
            for (int reg = 0; reg < 4; reg++) {
                float cv = acc[mt][nt][reg] + bj;
                if (RELU) cv = fmaxf(cv, 0.f);
                storeOut(&C[(size_t)(rm + reg) * N + cn], cv);
            }
        }
    }
}

// ---------------------------------------------------------------------------
// MFMA GEMM 64x128 tile, BK=64: coalesced+swizzled staging (R6).
// ---------------------------------------------------------------------------
template <typename TOUT, bool RELU>
__global__ __launch_bounds__(256) void gemm_mfma64(const unsigned short* __restrict__ A,
                                                   const unsigned short* __restrict__ W,
                                                   const float* __restrict__ bias,
                                                   TOUT* __restrict__ C,
                                                   int M, int N, int K)
{
    __shared__ unsigned short AsL[4096];   // [row:64][chunk:8][8 bf16] swz
    __shared__ unsigned short BsL[8192];
    const int t    = threadIdx.x;
    const int wave = t >> 6, lane = t & 63;
    const int quad = lane >> 4, col = lane & 15;
    const int wm   = wave >> 1, wn = wave & 1;
    const int m0   = blockIdx.y * 64, n0 = blockIdx.x * 128;

    f32x4 acc[2][4];
    #pragma unroll
    for (int mt = 0; mt < 2; mt++)
        #pragma unroll
        for (int nt = 0; nt < 4; nt++)
            acc[mt][nt] = (f32x4){0.f, 0.f, 0.f, 0.f};

    for (int k0 = 0; k0 < K; k0 += 64) {
        #pragma unroll
        for (int seg = 0; seg < 2; seg++) {
            const int r0  = (seg * 4 + wave) * 8;  // wave-uniform, 0..56
            const int row = r0 + (lane >> 3);
            const int ck  = (lane & 7) ^ (row & 7);
            gl_lds16(A + (size_t)(m0 + row) * K + k0 + ck * 8, &AsL[r0 * 64]);
        }
        #pragma unroll
        for (int seg = 0; seg < 4; seg++) {
            const int r0  = (seg * 4 + wave) * 8;
            const int row = r0 + (lane >> 3);
            const int ck  = (lane & 7) ^ (row & 7);
            gl_lds16(W + (size_t)(n0 + row) * K + k0 + ck * 8, &BsL[r0 * 64]);
        }
        __syncthreads();
        #pragma unroll
        for (int kc = 0; kc < 2; kc++) {
            sh8 af[2], bf[4];
            #pragma unroll
            for (int mt = 0; mt < 2; mt++) {
                const int ar = wm * 32 + mt * 16 + col;
                af[mt] = *(const sh8*)&AsL[ar * 64 + (((kc * 4 + quad) ^ (ar & 7)) << 3)];
            }
            #pragma unroll
            for (int nt = 0; nt < 4; nt++) {
                const int nr = wn * 64 + nt * 16 + col;
                bf[nt] = *(const sh8*)&BsL[nr * 64 + (((kc * 4 + quad) ^ (nr & 7)) << 3)];
            }
            #pragma unroll
            for (int mt = 0; mt < 2; mt++)
                #pragma unroll
                for (int nt = 0; nt < 4; nt++)
                    acc[mt][nt] = __builtin_amdgcn_mfma_f32_16x16x32_bf16(af[mt], bf[nt], acc[mt][nt], 0, 0, 0);
        }
        __syncthreads();
    }
    #pragma unroll
    for (int nt = 0; nt < 4; nt++) {
        const int cn = n0 + wn * 64 + nt * 16 + col;
        const float bj = bias[cn];
        #pragma unroll
        for (int mt = 0; mt < 2; mt++) {
            const int rm = m0 + wm * 32 + mt * 16 + quad * 4;
            #pragma unroll
            for (int reg = 0; reg < 4; reg++) {
                float cv = acc[mt][nt][reg] + bj;
                if (RELU) cv = fmaxf(cv, 0.f);
                storeOut(&C[(size_t)(rm + reg) * N + cn], cv);
            }
        }
    }
}

// ---------------------------------------------------------------------------
// MFMA flash attention v12 (causal, reverse-paired tiles, split-KV x2,
// DOUBLE-BUFFERED coalesced staging). Block (x,y): i = x>>1, sp = x&1.
// S = 32-i total rounds; split sp covers [sp? h0:0, sp? S:h0), h0=(S+1)/2
// -> 8..16 rounds/block; co-resident blocks share x -> uniform per-CU load;
// worst-CU makespan 16 rounds at v9's hidden-latency per-round cost
// (stage r+1 issued before compute of r, ONE barrier/round).
// LDS 41 KB (Ks[2]+Vs[2]+single Ps used serially B-then-A) -> 3 blocks/CU.
// FIXED-MAX softmax: partials additive (attn_combine sums).
// Qb/Kb: [B,L,H,64] bf16; Vt: [B*H,64,L] bf16.
// Op: fp32 [2][B,L,H,64]; Lp: fp32 [2][B,L,H].
// ---------------------------------------------------------------------------
__global__ __launch_bounds__(256, 3) void attn_mfma(const unsigned short* __restrict__ Qb,
                                                    const unsigned short* __restrict__ Kb,
                                                    const unsigned short* __restrict__ Vt,
                                                    float* __restrict__ Op,
                                                    float* __restrict__ Lp,
                                                    int L)
{
    __shared__ unsigned short Ks[2][4096];       // [buf][key:64][e-chunk swz] 16 KB
    __shared__ unsigned short Vs[2][4096];       // [buf][e:64][key-chunk swz] 16 KB
    __shared__ unsigned short Ps[4][16][72];     // per wave [qrow:16][key:64+pad] 9 KB

    const int x    = blockIdx.x;                 // 0..31 (x=0,1 -> i=0 heaviest first)
    const int i    = x >> 1;
    const int sp   = x & 1;
    const int bh   = blockIdx.y;
    const int b    = bh >> 3, h = bh & 7;        // H = 8
    const int t    = threadIdx.x;
    const int w    = t >> 6, lane = t & 63;
    const int quad = lane >> 4, col = lane & 15;

    const int qtA = i, qtB = 31 - i;             // light / heavy tile
    const int qrowA = qtA * 64 + w * 16 + col;
    const int qrowB = qtB * 64 + w * 16 + col;
    const int S  = 32 - i;                       // total rounds for the pair
    const int h0 = (S + 1) >> 1;
    const int r0 = sp ? h0 : 0;
    const int r1 = sp ? S : h0;

    // staging lane decomposition: 8 lanes cover one 128 B row
    const int srow = lane >> 3;
    const int scp  = lane & 7;

    // Q B-frags (QSCALE pre-applied in projection)
    sh8 qfA[2], qfB[2];
    {
        const size_t qa = ((size_t)(b * L + qrowA) * 8 + h) * 64;
        qfA[0] = *(const sh8*)(Qb + qa + quad * 8);
        qfA[1] = *(const sh8*)(Qb + qa + 32 + quad * 8);
        const size_t qb2 = ((size_t)(b * L + qrowB) * 8 + h) * 64;
        qfB[0] = *(const sh8*)(Qb + qb2 + quad * 8);
        qfB[1] = *(const sh8*)(Qb + qb2 + 32 + quad * 8);
    }

    f32x4 OA[4], OB[4];
    #pragma unroll
    for (int nt = 0; nt < 4; nt++) { OA[nt] = (f32x4){0.f,0.f,0.f,0.f}; OB[nt] = (f32x4){0.f,0.f,0.f,0.f}; }
    float lA = 0.f, lB = 0.f;

    // ---- prologue: stage round r0 into buf 0 (coalesced, source-swizzled)
    {
        const int k0 = r0 * 64;
        #pragma unroll
        for (int seg = 0; seg < 2; seg++) {
            const int rr  = (seg * 4 + w) * 8;   // wave-uniform row base
            const int row = rr + srow;
            const int ck  = scp ^ (row & 7);     // involution
            gl_lds16(Kb + ((size_t)(b * L + k0 + row) * 8 + h) * 64 + ck * 8, &Ks[0][rr * 64]);
            gl_lds16(Vt + (size_t)(bh * 64 + row) * L + k0 + ck * 8, &Vs[0][rr * 64]);
        }
        __syncthreads();
    }

    int cur = 0;
    for (int r = r0; r < r1; r++) {
        // ---- issue stage of round r+1 into the other buffer (hidden by compute)
        if (r + 1 < r1) {
            const int k1 = (r + 1) * 64;
            #pragma unroll
            for (int seg = 0; seg < 2; seg++) {
                const int rr  = (seg * 4 + w) * 8;
                const int row = rr + srow;
                const int ck  = scp ^ (row & 7);
                gl_lds16(Kb + ((size_t)(b * L + k1 + row) * 8 + h) * 64 + ck * 8, &Ks[cur ^ 1][rr * 64]);
                gl_lds16(Vt + (size_t)(bh * 64 + row) * L + k1 + ck * 8, &Vs[cur ^ 1][rr * 64]);
            }
        }

        const int k0 = r * 64;
        const bool actA  = (r <= i);
        const bool maskA = (r == i);
        const bool maskB = (r == S - 1);

        // ---- S^T for both tiles (K-frags read once)
        f32x4 stA[4], stB[4];
        const f32x4 zz = {0.f, 0.f, 0.f, 0.f};
        #pragma unroll
        for (int ntk = 0; ntk < 4; ntk++) {
            const int key = ntk * 16 + col;
            const int sw  = key & 7;
            sh8 kf0 = *(const sh8*)&Ks[cur][key * 64 + ((quad ^ sw) << 3)];
            sh8 kf1 = *(const sh8*)&Ks[cur][key * 64 + (((quad + 4) ^ sw) << 3)];
            f32x4 aB = __builtin_amdgcn_mfma_f32_16x16x32_bf16(kf0, qfB[0], zz, 0, 0, 0);
            stB[ntk] = __builtin_amdgcn_mfma_f32_16x16x32_bf16(kf1, qfB[1], aB, 0, 0, 0);
            if (actA) {
                f32x4 aA = __builtin_amdgcn_mfma_f32_16x16x32_bf16(kf0, qfA[0], zz, 0, 0, 0);
                stA[ntk] = __builtin_amdgcn_mfma_f32_16x16x32_bf16(kf1, qfA[1], aA, 0, 0, 0);
            }
        }

        // ---- tile B: softmax -> Ps -> PV
        {
            if (maskB) {
                #pragma unroll
                for (int ntk = 0; ntk < 4; ntk++)
                    #pragma unroll
                    for (int reg = 0; reg < 4; reg++)
                        if (k0 + ntk * 16 + quad * 4 + reg > qrowB) stB[ntk][reg] = -1e30f;
            }
            #pragma unroll
            for (int ntk = 0; ntk < 4; ntk++) {
                #pragma unroll
                for (int reg = 0; reg < 4; reg++)
                    stB[ntk][reg] = exp2f(stB[ntk][reg]);
                lB += (stB[ntk][0] + stB[ntk][1]) + (stB[ntk][2] + stB[ntk][3]);
                *(uint2*)&Ps[w][col][ntk * 16 + quad * 4] =
                    make_uint2(pk_bf16(stB[ntk][0], stB[ntk][1]), pk_bf16(stB[ntk][2], stB[ntk][3]));
            }
            #pragma unroll
            for (int kchunk = 0; kchunk < 2; kchunk++) {
                sh8 pf = *(const sh8*)&Ps[w][col][kchunk * 32 + quad * 8];
                #pragma unroll
                for (int nt = 0; nt < 4; nt++) {
                    const int e = nt * 16 + col;
                    sh8 vf = *(const sh8*)&Vs[cur][e * 64 + (((kchunk * 4 + quad) ^ (e & 7)) << 3)];
                    OB[nt] = __builtin_amdgcn_mfma_f32_16x16x32_bf16(pf, vf, OB[nt], 0, 0, 0);
                }
            }
        }

        // ---- tile A: softmax -> Ps (reuse, per-wave private) -> PV
        if (actA) {
            if (maskA) {
                #pragma unroll
                for (int ntk = 0; ntk < 4; ntk++)
                    #pragma unroll
                    for (int reg = 0; reg < 4; reg++)
                        if (k0 + ntk * 16 + quad * 4 + reg > qrowA) stA[ntk][reg] = -1e30f;
            }
            #pragma unroll
            for (int ntk = 0; ntk < 4; ntk++) {
                #pragma unroll
                for (int reg = 0; reg < 4; reg++)
                    stA[ntk][reg] = exp2f(stA[ntk][reg]);
                lA += (stA[ntk][0] + stA[ntk][1]) + (stA[ntk][2] + stA[ntk][3]);
                *(uint2*)&Ps[w][col][ntk * 16 + quad * 4] =
                    make_uint2(pk_bf16(stA[ntk][0], stA[ntk][1]), pk_bf16(stA[ntk][2], stA[ntk][3]));
            }
            #pragma unroll
            for (int kchunk = 0; kchunk < 2; kchunk++) {
                sh8 pf = *(const sh8*)&Ps[w][col][kchunk * 32 + quad * 8];
                #pragma unroll
                for (int nt = 0; nt < 4; nt++) {
                    const int e = nt * 16 + col;
                    sh8 vf = *(const sh8*)&Vs[cur][e * 64 + (((kchunk * 4 + quad) ^ (e & 7)) << 3)];
                    OA[nt] = __builtin_amdgcn_mfma_f32_16x16x32_bf16(pf, vf, OA[nt], 0, 0, 0);
                }
            }
        }
        // ---- one barrier/round: drains stage(r+1) (vmcnt 0) and protects
        // buf cur from being overwritten while still being read
        __syncthreads();
        cur ^= 1;
    }

    // ---- epilogue: reduce l across quads, store fp32 partial O and l
    lA += __shfl_xor(lA, 16); lA += __shfl_xor(lA, 32);
    lB += __shfl_xor(lB, 16); lB += __shfl_xor(lB, 32);
    {
        float* Od = Op + (size_t)sp * 4194304;    // 8192*512 per split
        float* Ld = Lp + (size_t)sp * 65536;      // 8192*8 per split
        if (quad == 0) {
            Ld[(size_t)(b * L + qtA * 64 + w * 16 + col) * 8 + h] = lA;
            Ld[(size_t)(b * L + qtB * 64 + w * 16 + col) * 8 + h] = lB;
        }
        #pragma unroll
        for (int reg = 0; reg < 4; reg++) {
            const int qrA = qtA * 64 + w * 16 + quad * 4 + reg;
            const int qrB = qtB * 64 + w * 16 + quad * 4 + reg;
            #pragma unroll
            for (int nt = 0; nt < 4; nt++) {
                Od[((size_t)(b * L + qrA) * 8 + h) * 64 + nt * 16 + col] = OA[nt][reg];
                Od[((size_t)(b * L + qrB) * 8 + h) * 64 + nt * 16 + col] = OB[nt][reg];
            }
        }
    }
}

// ---------------------------------------------------------------------------
// Combine split-KV partials: O = (O0+O1)/(l0+l1), bf16 out. Pure streaming:
// 32 MB read + 0.5 MB l + 8 MB write. (R1-verified.)
// ---------------------------------------------------------------------------
__global__ __launch_bounds__(256) void attn_combine(const float* __restrict__ Op,
                                                    const float* __restrict__ Lp,
                                                    unsigned short* __restrict__ O)
{
    const int row = blockIdx.x;                  // b*L + l, 8192 rows
    const int t   = threadIdx.x;
    const int e   = t * 2;                       // 0..510
    const int h   = e >> 6;
    const float l0 = Lp[(size_t)row * 8 + h];
    const float l1 = Lp[65536 + (size_t)row * 8 + h];
    const float inv = 1.f / (l0 + l1);
    const size_t idx = (size_t)row * 512 + e;
    const float2 o0 = *(const float2*)(Op + idx);
    const float2 o1 = *(const float2*)(Op + 4194304 + idx);
    *(unsigned*)&O[idx] = pk_bf16((o0.x + o1.x) * inv, (o0.y + o1.y) * inv);
}

// ---------------------------------------------------------------------------
// LayerNorm over last dim (512). x = f1 [+ f2] [+ rb]. Dual output.
// ---------------------------------------------------------------------------
__global__ __launch_bounds__(256) void layernorm_k(const float* __restrict__ f1,
                                                   const float* __restrict__ f2,
                                                   const float* __restrict__ rb,
                                                   const float* __restrict__ g,
                                                   const float* __restrict__ bb,
                                                   float* __restrict__ out32,
                                                   __hip_bfloat16* __restrict__ out16)
{
    const int row = blockIdx.x;
    const int t   = threadIdx.x;
    const size_t base = (size_t)row * 512;
    const int i0 = t * 2;

    float a0 = f1[base + i0], a1 = f1[base + i0 + 1];
    if (f2) { a0 += f2[base + i0]; a1 += f2[base + i0 + 1]; }
    if (rb) { a0 += rb[base + i0]; a1 += rb[base + i0 + 1]; }

    float s = a0 + a1, ss = a0 * a0 + a1 * a1;
    #pragma unroll
    for (int off = 32; off > 0; off >>= 1) {
        s  += __shfl_xor(s, off);
        ss += __shfl_xor(ss, off);
    }
    __shared__ float red[16];
    const int lane = t & 63, wid = t >> 6;
    if (lane == 0) { red[wid] = s; red[8 + wid] = ss; }
    __syncthreads();
    if (t == 0) {
        const float S  = red[0] + red[1] + red[2] + red[3];
        const float SS = red[8] + red[9] + red[10] + red[11];
        const float mu = S * (1.f / 512.f);
        const float var = SS * (1.f / 512.f) - mu * mu;
        red[0] = mu;
        red[1] = rsqrtf(fmaxf(var, 0.f) + 1e-5f);
    }
    __syncthreads();
    const float mu = red[0], rstd = red[1];
    const float y0 = (a0 - mu) * rstd * g[i0]     + bb[i0];
    const float y1 = (a1 - mu) * rstd * g[i0 + 1] + bb[i0 + 1];
    if (out32) { out32[base + i0] = y0; out32[base + i0 + 1] = y1; }
    if (out16) { out16[base + i0] = __float2bfloat16(y0); out16[base + i0 + 1] = __float2bfloat16(y1); }
}

// ---------------------------------------------------------------------------
extern "C" void kernel_launch(void* const* d_in, const int* in_sizes, int n_in,
                              void* d_out, int out_size, void* d_ws, size_t ws_size,
                              hipStream_t stream)
{
    const float* q   = (const float*)d_in[0];
    const float* k   = (const float*)d_in[1];
    const float* v   = (const float*)d_in[2];
    const float* Wq  = (const float*)d_in[3];
    const float* bq  = (const float*)d_in[4];
    const float* Wk  = (const float*)d_in[5];
    const float* bk  = (const float*)d_in[6];
    const float* Wv  = (const float*)d_in[7];
    const float* bv  = (const float*)d_in[8];
    const float* Wo  = (const float*)d_in[9];
    const float* bo  = (const float*)d_in[10];
    const float* Wc1 = (const float*)d_in[11];
    const float* bc1 = (const float*)d_in[12];
    const float* Wc2 = (const float*)d_in[13];
    const float* bc2 = (const float*)d_in[14];
    const float* g1  = (const float*)d_in[15];
    const float* b1  = (const float*)d_in[16];
    const float* g2  = (const float*)d_in[17];
    const float* b2  = (const float*)d_in[18];
    const float* Wl  = (const float*)d_in[19];
    const float* bl  = (const float*)d_in[20];
    float* out = (float*)d_out;

    const int B = 4, L = 2048, H = 8;
    const int M = B * L;                        // 8192

    // Workspace map (bytes; peak 82.3 MB):
    //   Attn partials Op (33.5 MB) overlay A2+X1 (dead during attn); Lp
    //   (512 KB) overlays X1b. A1 (combine output) untouched by partials.
    //   (R1/R9-verified overlay.)
    char* base = (char*)d_ws;
    unsigned short* Wall = (unsigned short*)(base + 0);          // 6.8 MB, live all
    unsigned short* Wob  = (unsigned short*)(base + 1572864);
    unsigned short* Wlb  = (unsigned short*)(base + 2097152);
    unsigned short* Wc1b = (unsigned short*)(base + 2621440);
    unsigned short* Wc2b = (unsigned short*)(base + 4718592);
    unsigned short* Qb   = (unsigned short*)(base + 6815744);    // -> dead after attn
    unsigned short* Kb   = (unsigned short*)(base + 15204352);   // -> dead after attn
    unsigned short* Vt   = (unsigned short*)(base + 23592960);   // -> dead after attn
    unsigned short* A1   = (unsigned short*)(base + 31981568);   // attn out (combine)
    float*          Oprt = (float*)(base + 40370176);            // 33.5 MB partials
    float*          Lprt = (float*)(base + 73924608);            // 512 KB partial l
    float*          A2   = (float*)(base + 40370176);            // -> dead after LN1
    float*          X1   = (float*)(base + 57147392);            // live to LN2
    unsigned short* X1b  = (unsigned short*)(base + 73924608);   // -> dead after FFN1
    unsigned short* X2b  = (unsigned short*)(base + 73924608);   // reuse
    unsigned short* H1   = (unsigned short*)(base + 6815744);    // 33.5 MB over Qb..A1
    float*          Y2   = (float*)(base + 40370176);            // reuse A2

    const dim3 blk(256);

    // 1: weights fp32 -> bf16
    WArg wa;
    wa.w[0] = Wq; wa.w[1] = Wk; wa.w[2] = Wv; wa.w[3] = Wo; wa.w[4] = Wl;
    wa.w[5] = Wc1; wa.w[6] = Wc2; wa.wd = Wall;
    conv_w<<<dim3(3328), blk, 0, stream>>>(wa);

    // 2: batched QKV projections (fp32 A direct; z=2 writes Vt transposed)
    QkvArg qa;
    qa.A0 = q;  qa.A1 = k;  qa.A2 = v;
    qa.b0 = bq; qa.b1 = bk; qa.b2 = bv;
    qa.C0 = Qb; qa.C1 = Kb; qa.Vt = Vt;
    gemm_qkv<<<dim3(4, 64, 3), blk, 0, stream>>>(qa, Wall, M, 512, 512);

    // 3: flash attention v12 (split-KV x2 + double-buffer, 3 blocks/CU)
    attn_mfma<<<dim3(32, B * H), blk, 0, stream>>>(Qb, Kb, Vt, Oprt, Lprt, L);

    // 3b: combine partials -> bf16 A1
    attn_combine<<<dim3(M), blk, 0, stream>>>(Oprt, Lprt, A1);

    // 4: att @ Wo^T + bo -> fp32
    gemm_mfma64<float, false><<<dim3(4, 128), blk, 0, stream>>>(A1, Wob, bo, A2, M, 512, 512);

    // 5: x = LN(v + attO) -> fp32 X1 + bf16 X1b
    layernorm_k<<<dim3(M), blk, 0, stream>>>(A2, nullptr, v, g1, b1, X1, (__hip_bfloat16*)X1b);

    // 6: h1 = relu(x @ Wc1^T + bc1) -> bf16 [M,2048]
    gemm_mfma<__hip_bfloat16, true><<<dim3(16, 64), blk, 0, stream>>>(X1b, Wc1b, bc1, (__hip_bfloat16*)H1, M, 2048, 512);

    // 7: y2 = h1 @ Wc2^T + bc2 -> fp32
    gemm_mfma64<float, false><<<dim3(4, 128), blk, 0, stream>>>(H1, Wc2b, bc2, Y2, M, 512, 2048);

    // 8: x2 = LN(x + y2) -> bf16
    layernorm_k<<<dim3(M), blk, 0, stream>>>(X1, Y2, nullptr, g2, b2, nullptr, (__hip_bfloat16*)X2b);

    // 9: out = x2 @ Wl^T + bl -> fp32 d_out
    gemm_mfma64<float, false><<<dim3(4, 128), blk, 0, stream>>>(X2b, Wlb, bl, out, M, 512, 512);
}

// Round 11
// 318.842 us; speedup vs baseline: 1.2120x; 1.0334x over previous
//
#include <hip/hip_runtime.h>
#include <hip/hip_bf16.h>

// Problem constants: B=4, L=2048, d_model=d_value=512, H=8, E=64, d4=2048.
// External inputs/output fp32. Internal compute: bf16 MFMA.
//
// R10 lesson: attn is per-CU round-throughput-bound (~1.12 us/round/CU,
// invariant across split/pairing/residency) -> 64x64 structure is at its
// fixed point ~55 us. Reverted to v9 (no split, no combine = best total).
// R11: the GEMMs still had {stage -> barrier -> compute -> barrier} x 8
// K-steps = R9's exposed-latency disease. All GEMMs now 2-phase
// double-buffered (stage k+1 issued before compute k, ONE barrier/step,
// v9-proven). qkv A pre-converted to bf16 (conv_in) so the dbuf fits:
// qkv/FFN1 64 KB LDS (2 blk/CU), gemm64 48 KB (3 blk/CU).

typedef __attribute__((ext_vector_type(8))) short sh8;    // 8 bf16 (A/B frag)
typedef __attribute__((ext_vector_type(4))) float f32x4;  // C/D frag

#define QSCALE 0.18033688011110543f   // 0.125 * log2(e): folded into Q projection

__device__ __forceinline__ void storeOut(float* p, float v) { *p = v; }
__device__ __forceinline__ void storeOut(__hip_bfloat16* p, float v) { *p = __float2bfloat16(v); }

// async global->LDS, 16 B per lane, wave-uniform LDS base (m97 pattern)
__device__ __forceinline__ void gl_lds16(const void* g, void* l) {
    __builtin_amdgcn_global_load_lds((const __attribute__((address_space(1))) void*)g,
                                     (__attribute__((address_space(3))) void*)l, 16, 0, 0);
}

// pack two fp32 into one dword of two bf16 (RNE)
__device__ __forceinline__ unsigned pk_bf16(float a, float b) {
    __hip_bfloat162 h = __float22bfloat162_rn(make_float2(a, b));
    return *(unsigned*)&h;
}

// ---------------------------------------------------------------------------
// Weights fp32 -> bf16 into one contiguous ws region.
// Order: Wq,Wk,Wv,Wo,Wl,Wc1,Wc2 (3407872 elements).
// ---------------------------------------------------------------------------
struct WArg { const float* w[7]; unsigned short* wd; };
__global__ __launch_bounds__(256) void conv_w(WArg p)
{
    const int i = (blockIdx.x * 256 + threadIdx.x) * 4;
    if (i >= 3407872) return;
    const float* s; int off;
    if      (i < 262144)  { s = p.w[0]; off = i; }
    else if (i < 524288)  { s = p.w[1]; off = i - 262144; }
    else if (i < 786432)  { s = p.w[2]; off = i - 524288; }
    else if (i < 1048576) { s = p.w[3]; off = i - 786432; }
    else if (i < 1310720) { s = p.w[4]; off = i - 1048576; }
    else if (i < 2359296) { s = p.w[5]; off = i - 1310720; }
    else                  { s = p.w[6]; off = i - 2359296; }
    const float4 v = *(const float4*)(s + off);
    *(uint2*)(p.wd + i) = make_uint2(pk_bf16(v.x, v.y), pk_bf16(v.z, v.w));
}

// ---------------------------------------------------------------------------
// Inputs q,k,v fp32 -> bf16 (3 x 4194304 elements) into Ab region.
// ---------------------------------------------------------------------------
__global__ __launch_bounds__(256) void conv_in(const float* __restrict__ q,
                                               const float* __restrict__ k,
                                               const float* __restrict__ v,
                                               unsigned short* __restrict__ dst)
{
    const int i = (blockIdx.x * 256 + threadIdx.x) * 4;
    if (i >= 12582912) return;
    const float* s; int off;
    if      (i < 4194304) { s = q; off = i; }
    else if (i < 8388608) { s = k; off = i - 4194304; }
    else                  { s = v; off = i - 8388608; }
    const float4 x = *(const float4*)(s + off);
    *(uint2*)(dst + i) = make_uint2(pk_bf16(x.x, x.y), pk_bf16(x.z, x.w));
}

// ---------------------------------------------------------------------------
// Batched QKV GEMM (grid.z = 0,1,2), 2-PHASE double-buffered. A now bf16
// (conv_in), staged like W: 8 lanes/row, chunk-XOR over 8. BK=64.
// z=0: scaled by QSCALE -> Qb. z=1 -> Kb. z=2: written TRANSPOSED into
// Vt[B*H,64,L]. LDS 64 KB -> 2 blocks/CU.
// ---------------------------------------------------------------------------
struct QkvArg {
    const unsigned short *A0, *A1, *A2;    // bf16 [M,512]
    const float *b0, *b1, *b2;
    unsigned short *C0, *C1;               // Qb, Kb [B,L,H,64]
    unsigned short *Vt;                    // [B*H,64,L]
};
__global__ __launch_bounds__(256, 2) void gemm_qkv(QkvArg ar, const unsigned short* __restrict__ Wall,
                                                   int M, int N, int K)
{
    const int z = blockIdx.z;
    const unsigned short* A = z == 0 ? ar.A0 : (z == 1 ? ar.A1 : ar.A2);
    const unsigned short* W = Wall + (size_t)z * 262144;
    const float* bias = z == 0 ? ar.b0 : (z == 1 ? ar.b1 : ar.b2);

    __shared__ unsigned short AsL[2][8192];   // [buf][row:128][chunk:8][8 bf16] swz
    __shared__ unsigned short BsL[2][8192];
    const int t    = threadIdx.x;
    const int wave = t >> 6, lane = t & 63;
    const int quad = lane >> 4, col = lane & 15;
    const int wm   = wave >> 1, wn = wave & 1;
    const int m0   = blockIdx.y * 128, n0 = blockIdx.x * 128;

    auto stage = [&](int k0, int buf) {
        #pragma unroll
        for (int seg = 0; seg < 4; seg++) {
            const int r0  = (seg * 4 + wave) * 8;  // wave-uniform
            const int row = r0 + (lane >> 3);
            const int ck  = (lane & 7) ^ (row & 7);
            gl_lds16(A + (size_t)(m0 + row) * K + k0 + ck * 8, &AsL[buf][r0 * 64]);
            gl_lds16(W + (size_t)(n0 + row) * K + k0 + ck * 8, &BsL[buf][r0 * 64]);
        }
    };

    f32x4 acc[4][4];
    #pragma unroll
    for (int mt = 0; mt < 4; mt++)
        #pragma unroll
        for (int nt = 0; nt < 4; nt++)
            acc[mt][nt] = (f32x4){0.f, 0.f, 0.f, 0.f};

    stage(0, 0);
    __syncthreads();
    int cur = 0;
    for (int k0 = 0; k0 < K; k0 += 64) {
        if (k0 + 64 < K) stage(k0 + 64, cur ^ 1);
        #pragma unroll
        for (int kc = 0; kc < 2; kc++) {
            sh8 af[4], bf[4];
            #pragma unroll
            for (int mt = 0; mt < 4; mt++) {
                const int arow = wm * 64 + mt * 16 + col;
                af[mt] = *(const sh8*)&AsL[cur][arow * 64 + (((kc * 4 + quad) ^ (arow & 7)) << 3)];
            }
            #pragma unroll
            for (int nt = 0; nt < 4; nt++) {
                const int nr = wn * 64 + nt * 16 + col;
                bf[nt] = *(const sh8*)&BsL[cur][nr * 64 + (((kc * 4 + quad) ^ (nr & 7)) << 3)];
            }
            #pragma unroll
            for (int mt = 0; mt < 4; mt++)
                #pragma unroll
                for (int nt = 0; nt < 4; nt++)
                    acc[mt][nt] = __builtin_amdgcn_mfma_f32_16x16x32_bf16(af[mt], bf[nt], acc[mt][nt], 0, 0, 0);
        }
        __syncthreads();
        cur ^= 1;
    }

    if (z < 2) {
        unsigned short* C = z == 0 ? ar.C0 : ar.C1;
        const float scale = z == 0 ? QSCALE : 1.0f;
        #pragma unroll
        for (int nt = 0; nt < 4; nt++) {
            const int cn = n0 + wn * 64 + nt * 16 + col;
            const float bj = bias[cn];
            #pragma unroll
            for (int mt = 0; mt < 4; mt++) {
                const int rm = m0 + wm * 64 + mt * 16 + quad * 4;
                #pragma unroll
                for (int reg = 0; reg < 4; reg++)
                    C[(size_t)(rm + reg) * N + cn] =
                        (unsigned short)__bfloat16_as_ushort(__float2bfloat16((acc[mt][nt][reg] + bj) * scale));
            }
        }
    } else {
        // V: write transposed [B*H, 64, L]; 4 consecutive s rows pack to 8 B.
        const int b = m0 >> 11;                    // L = 2048
        #pragma unroll
        for (int nt = 0; nt < 4; nt++) {
            const int cn = n0 + wn * 64 + nt * 16 + col;
            const int h = cn >> 6, e = cn & 63;
            const float bj = bias[cn];
            #pragma unroll
            for (int mt = 0; mt < 4; mt++) {
                const int s0r = (m0 + wm * 64 + mt * 16 + quad * 4) & 2047;
                float cv[4];
                #pragma unroll
                for (int reg = 0; reg < 4; reg++) cv[reg] = acc[mt][nt][reg] + bj;
                *(uint2*)(ar.Vt + ((size_t)(b * 8 + h) * 64 + e) * 2048 + s0r) =
                    make_uint2(pk_bf16(cv[0], cv[1]), pk_bf16(cv[2], cv[3]));
            }
        }
    }
}

// ---------------------------------------------------------------------------
// MFMA GEMM 128x128, BK=64 (FFN1), 2-PHASE double-buffered (R11).
// LDS 64 KB -> 2 blocks/CU.
// ---------------------------------------------------------------------------
template <typename TOUT, bool RELU>
__global__ __launch_bounds__(256, 2) void gemm_mfma(const unsigned short* __restrict__ A,
                                                    const unsigned short* __restrict__ W,
                                                    const float* __restrict__ bias,
                                                    TOUT* __restrict__ C,
                                                    int M, int N, int K)
{
    __shared__ unsigned short AsL[2][8192];   // [buf][row:128][chunk:8][8 bf16] swz
    __shared__ unsigned short BsL[2][8192];
    const int t    = threadIdx.x;
    const int wave = t >> 6, lane = t & 63;
    const int quad = lane >> 4, col = lane & 15;
    const int wm   = wave >> 1, wn = wave & 1;
    const int m0   = blockIdx.y * 128, n0 = blockIdx.x * 128;

    auto stage = [&](int k0, int buf) {
        #pragma unroll
        for (int seg = 0; seg < 4; seg++) {
            const int r0  = (seg * 4 + wave) * 8;  // wave-uniform
            const int row = r0 + (lane >> 3);
            const int ck  = (lane & 7) ^ (row & 7);
            gl_lds16(A + (size_t)(m0 + row) * K + k0 + ck * 8, &AsL[buf][r0 * 64]);
            gl_lds16(W + (size_t)(n0 + row) * K + k0 + ck * 8, &BsL[buf][r0 * 64]);
        }
    };

    f32x4 acc[4][4];
    #pragma unroll
    for (int mt = 0; mt < 4; mt++)
        #pragma unroll
        for (int nt = 0; nt < 4; nt++)
            acc[mt][nt] = (f32x4){0.f, 0.f, 0.f, 0.f};

    stage(0, 0);
    __syncthreads();
    int cur = 0;
    for (int k0 = 0; k0 < K; k0 += 64) {
        if (k0 + 64 < K) stage(k0 + 64, cur ^ 1);
        #pragma unroll
        for (int kc = 0; kc < 2; kc++) {
            sh8 af[4], bf[4];
            #pragma unroll
            for (int mt = 0; mt < 4; mt++) {
                const int ar = wm * 64 + mt * 16 + col;
                af[mt] = *(const sh8*)&AsL[cur][ar * 64 + (((kc * 4 + quad) ^ (ar & 7)) << 3)];
            }
            #pragma unroll
            for (int nt = 0; nt < 4; nt++) {
                const int nr = wn * 64 + nt * 16 + col;
                bf[nt] = *(const sh8*)&BsL[cur][nr * 64 + (((kc * 4 + quad) ^ (nr & 7)) << 3)];
            }
            #pragma unroll
            for (int mt = 0; mt < 4; mt++)
                #pragma unroll
                for (int nt = 0; nt < 4; nt++)
                    acc[mt][nt] = __builtin_amdgcn_mfma_f32_16x16x32_bf16(af[mt], bf[nt], acc[mt][nt], 0, 0, 0);
        }
        __syncthreads();
        cur ^= 1;
    }
    #pragma unroll
    for (int nt = 0; nt < 4; nt++) {
        const int cn = n0 + wn * 64 + nt * 16 + col;
        const float bj = bias[cn];
        #pragma unroll
        for (int mt = 0; mt < 4; mt++) {
            const int rm = m0 + wm * 64 + mt * 16 + quad * 4;
            #pragma unroll
            for (int reg = 0; reg < 4; reg++) {
                float cv = acc[mt][nt][reg] + bj;
                if (RELU) cv = fmaxf(cv, 0.f);
                storeOut(&C[(size_t)(rm + reg) * N + cn], cv);
            }
        }
    }
}

// ---------------------------------------------------------------------------
// MFMA GEMM 64x128 tile, BK=64, 2-PHASE double-buffered (R11).
// LDS 48 KB -> 3 blocks/CU.
// ---------------------------------------------------------------------------
template <typename TOUT, bool RELU>
__global__ __launch_bounds__(256, 2) void gemm_mfma64(const unsigned short* __restrict__ A,
                                                      const unsigned short* __restrict__ W,
                                                      const float* __restrict__ bias,
                                                      TOUT* __restrict__ C,
                                                      int M, int N, int K)
{
    __shared__ unsigned short AsL[2][4096];   // [buf][row:64][chunk:8][8 bf16] swz
    __shared__ unsigned short BsL[2][8192];
    const int t    = threadIdx.x;
    const int wave = t >> 6, lane = t & 63;
    const int quad = lane >> 4, col = lane & 15;
    const int wm   = wave >> 1, wn = wave & 1;
    const int m0   = blockIdx.y * 64, n0 = blockIdx.x * 128;

    auto stage = [&](int k0, int buf) {
        #pragma unroll
        for (int seg = 0; seg < 2; seg++) {
            const int r0  = (seg * 4 + wave) * 8;  // wave-uniform, 0..56
            const int row = r0 + (lane >> 3);
            const int ck  = (lane & 7) ^ (row & 7);
            gl_lds16(A + (size_t)(m0 + row) * K + k0 + ck * 8, &AsL[buf][r0 * 64]);
        }
        #pragma unroll
        for (int seg = 0; seg < 4; seg++) {
            const int r0  = (seg * 4 + wave) * 8;
            const int row = r0 + (lane >> 3);
            const int ck  = (lane & 7) ^ (row & 7);
            gl_lds16(W + (size_t)(n0 + row) * K + k0 + ck * 8, &BsL[buf][r0 * 64]);
        }
    };

    f32x4 acc[2][4];
    #pragma unroll
    for (int mt = 0; mt < 2; mt++)
        #pragma unroll
        for (int nt = 0; nt < 4; nt++)
            acc[mt][nt] = (f32x4){0.f, 0.f, 0.f, 0.f};

    stage(0, 0);
    __syncthreads();
    int cur = 0;
    for (int k0 = 0; k0 < K; k0 += 64) {
        if (k0 + 64 < K) stage(k0 + 64, cur ^ 1);
        #pragma unroll
        for (int kc = 0; kc < 2; kc++) {
            sh8 af[2], bf[4];
            #pragma unroll
            for (int mt = 0; mt < 2; mt++) {
                const int ar = wm * 32 + mt * 16 + col;
                af[mt] = *(const sh8*)&AsL[cur][ar * 64 + (((kc * 4 + quad) ^ (ar & 7)) << 3)];
            }
            #pragma unroll
            for (int nt = 0; nt < 4; nt++) {
                const int nr = wn * 64 + nt * 16 + col;
                bf[nt] = *(const sh8*)&BsL[cur][nr * 64 + (((kc * 4 + quad) ^ (nr & 7)) << 3)];
            }
            #pragma unroll
            for (int mt = 0; mt < 2; mt++)
                #pragma unroll
                for (int nt = 0; nt < 4; nt++)
                    acc[mt][nt] = __builtin_amdgcn_mfma_f32_16x16x32_bf16(af[mt], bf[nt], acc[mt][nt], 0, 0, 0);
        }
        __syncthreads();
        cur ^= 1;
    }
    #pragma unroll
    for (int nt = 0; nt < 4; nt++) {
        const int cn = n0 + wn * 64 + nt * 16 + col;
        const float bj = bias[cn];
        #pragma unroll
        for (int mt = 0; mt < 2; mt++) {
            const int rm = m0 + wm * 32 + mt * 16 + quad * 4;
            #pragma unroll
            for (int reg = 0; reg < 4; reg++) {
                float cv = acc[mt][nt][reg] + bj;
                if (RELU) cv = fmaxf(cv, 0.f);
                storeOut(&C[(size_t)(rm + reg) * N + cn], cv);
            }
        }
    }
}

// ---------------------------------------------------------------------------
// MFMA flash attention v9 (causal, reverse-paired tiles, COALESCED staging).
// R6-verified config (56 us; R10 showed split/pairing/residency levers are
// all null - this structure is per-CU round-throughput-bound).
// Block = 4 waves, q-tiles (i, 31-i), S = 32-i rounds, fixed-max softmax,
// K/V double-buffered, ONE barrier/round, direct bf16 output.
// ---------------------------------------------------------------------------
__global__ __launch_bounds__(256, 2) void attn_mfma(const unsigned short* __restrict__ Qb,
                                                    const unsigned short* __restrict__ Kb,
                                                    const unsigned short* __restrict__ Vt,
                                                    __hip_bfloat16* __restrict__ O,
                                                    int L)
{
    __shared__ unsigned short Ks[2][4096];       // [buf][key:64][e-chunk swz] 16 KB
    __shared__ unsigned short Vs[2][4096];       // [buf][e:64][key-chunk swz] 16 KB
    __shared__ unsigned short PsA[4][16][72];    // per wave [qrow:16][key:64+pad] 9 KB
    __shared__ unsigned short PsB[4][16][72];

    const int i    = blockIdx.x;                 // 0..15
    const int bh   = blockIdx.y;
    const int b    = bh >> 3, h = bh & 7;        // H = 8
    const int t    = threadIdx.x;
    const int w    = t >> 6, lane = t & 63;
    const int quad = lane >> 4, col = lane & 15;

    const int qtA = i, qtB = 31 - i;             // light / heavy tile
    const int qrowA = qtA * 64 + w * 16 + col;
    const int qrowB = qtB * 64 + w * 16 + col;
    const int S = 32 - i;                        // rounds (tile B needs all)

    const int srow = lane >> 3;                  // row offset within instr (0..7)
    const int scp  = lane & 7;                   // destination chunk

    sh8 qfA[2], qfB[2];
    {
        const size_t qa = ((size_t)(b * L + qrowA) * 8 + h) * 64;
        qfA[0] = *(const sh8*)(Qb + qa + quad * 8);
        qfA[1] = *(const sh8*)(Qb + qa + 32 + quad * 8);
        const size_t qb2 = ((size_t)(b * L + qrowB) * 8 + h) * 64;
        qfB[0] = *(const sh8*)(Qb + qb2 + quad * 8);
        qfB[1] = *(const sh8*)(Qb + qb2 + 32 + quad * 8);
    }

    f32x4 OA[4], OB[4];
    #pragma unroll
    for (int nt = 0; nt < 4; nt++) { OA[nt] = (f32x4){0.f,0.f,0.f,0.f}; OB[nt] = (f32x4){0.f,0.f,0.f,0.f}; }
    float lA = 0.f, lB = 0.f;

    {
        #pragma unroll
        for (int seg = 0; seg < 2; seg++) {
            const int r0  = (seg * 4 + w) * 8;   // wave-uniform row base
            const int row = r0 + srow;
            const int ck  = scp ^ (row & 7);     // source chunk (involution)
            gl_lds16(Kb + ((size_t)(b * L + row) * 8 + h) * 64 + ck * 8, &Ks[0][r0 * 64]);
            gl_lds16(Vt + (size_t)(bh * 64 + row) * L + ck * 8, &Vs[0][r0 * 64]);
        }
        __syncthreads();
    }

    int cur = 0;
    for (int r = 0; r < S; r++) {
        if (r + 1 < S) {
            const int k1 = (r + 1) * 64;
            #pragma unroll
            for (int seg = 0; seg < 2; seg++) {
                const int r0  = (seg * 4 + w) * 8;
                const int row = r0 + srow;
                const int ck  = scp ^ (row & 7);
                gl_lds16(Kb + ((size_t)(b * L + k1 + row) * 8 + h) * 64 + ck * 8, &Ks[cur ^ 1][r0 * 64]);
                gl_lds16(Vt + (size_t)(bh * 64 + row) * L + k1 + ck * 8, &Vs[cur ^ 1][r0 * 64]);
            }
        }

        const int k0 = r * 64;
        const bool actA  = (r <= i);
        const bool maskA = (r == i);
        const bool maskB = (r == S - 1);

        f32x4 stA[4], stB[4];
        const f32x4 zz = {0.f, 0.f, 0.f, 0.f};
        #pragma unroll
        for (int ntk = 0; ntk < 4; ntk++) {
            const int key = ntk * 16 + col;
            const int sw  = key & 7;
            sh8 kf0 = *(const sh8*)&Ks[cur][key * 64 + ((quad ^ sw) << 3)];
            sh8 kf1 = *(const sh8*)&Ks[cur][key * 64 + (((quad + 4) ^ sw) << 3)];
            f32x4 aB = __builtin_amdgcn_mfma_f32_16x16x32_bf16(kf0, qfB[0], zz, 0, 0, 0);
            stB[ntk] = __builtin_amdgcn_mfma_f32_16x16x32_bf16(kf1, qfB[1], aB, 0, 0, 0);
            if (actA) {
                f32x4 aA = __builtin_amdgcn_mfma_f32_16x16x32_bf16(kf0, qfA[0], zz, 0, 0, 0);
                stA[ntk] = __builtin_amdgcn_mfma_f32_16x16x32_bf16(kf1, qfA[1], aA, 0, 0, 0);
            }
        }

        {
            if (maskB) {
                #pragma unroll
                for (int ntk = 0; ntk < 4; ntk++)
                    #pragma unroll
                    for (int reg = 0; reg < 4; reg++)
                        if (k0 + ntk * 16 + quad * 4 + reg > qrowB) stB[ntk][reg] = -1e30f;
            }
            #pragma unroll
            for (int ntk = 0; ntk < 4; ntk++) {
                #pragma unroll
                for (int reg = 0; reg < 4; reg++)
                    stB[ntk][reg] = exp2f(stB[ntk][reg]);
                lB += (stB[ntk][0] + stB[ntk][1]) + (stB[ntk][2] + stB[ntk][3]);
                *(uint2*)&PsB[w][col][ntk * 16 + quad * 4] =
                    make_uint2(pk_bf16(stB[ntk][0], stB[ntk][1]), pk_bf16(stB[ntk][2], stB[ntk][3]));
            }
        }
        if (actA) {
            if (maskA) {
                #pragma unroll
                for (int ntk = 0; ntk < 4; ntk++)
                    #pragma unroll
                    for (int reg = 0; reg < 4; reg++)
                        if (k0 + ntk * 16 + quad * 4 + reg > qrowA) stA[ntk][reg] = -1e30f;
            }
            #pragma unroll
            for (int ntk = 0; ntk < 4; ntk++) {
                #pragma unroll
                for (int reg = 0; reg < 4; reg++)
                    stA[ntk][reg] = exp2f(stA[ntk][reg]);
                lA += (stA[ntk][0] + stA[ntk][1]) + (stA[ntk][2] + stA[ntk][3]);
                *(uint2*)&PsA[w][col][ntk * 16 + quad * 4] =
                    make_uint2(pk_bf16(stA[ntk][0], stA[ntk][1]), pk_bf16(stA[ntk][2], stA[ntk][3]));
            }
        }

        #pragma unroll
        for (int kchunk = 0; kchunk < 2; kchunk++) {
            sh8 pfB = *(const sh8*)&PsB[w][col][kchunk * 32 + quad * 8];
            sh8 pfA;
            if (actA) pfA = *(const sh8*)&PsA[w][col][kchunk * 32 + quad * 8];
            #pragma unroll
            for (int nt = 0; nt < 4; nt++) {
                const int e  = nt * 16 + col;
                sh8 vf = *(const sh8*)&Vs[cur][e * 64 + (((kchunk * 4 + quad) ^ (e & 7)) << 3)];
                OB[nt] = __builtin_amdgcn_mfma_f32_16x16x32_bf16(pfB, vf, OB[nt], 0, 0, 0);
                if (actA) OA[nt] = __builtin_amdgcn_mfma_f32_16x16x32_bf16(pfA, vf, OA[nt], 0, 0, 0);
            }
        }
        __syncthreads();
        cur ^= 1;
    }

    lA += __shfl_xor(lA, 16); lA += __shfl_xor(lA, 32);
    lB += __shfl_xor(lB, 16); lB += __shfl_xor(lB, 32);
    {
        const float li = 1.f / lA;
        float lr[4];
        #pragma unroll
        for (int reg = 0; reg < 4; reg++) lr[reg] = __shfl(li, quad * 4 + reg);
        #pragma unroll
        for (int reg = 0; reg < 4; reg++) {
            const int qr = qtA * 64 + w * 16 + quad * 4 + reg;
            #pragma unroll
            for (int nt = 0; nt < 4; nt++)
                O[((size_t)(b * L + qr) * 8 + h) * 64 + nt * 16 + col] =
                    __float2bfloat16(OA[nt][reg] * lr[reg]);
        }
    }
    {
        const float li = 1.f / lB;
        float lr[4];
        #pragma unroll
        for (int reg = 0; reg < 4; reg++) lr[reg] = __shfl(li, quad * 4 + reg);
        #pragma unroll
        for (int reg = 0; reg < 4; reg++) {
            const int qr = qtB * 64 + w * 16 + quad * 4 + reg;
            #pragma unroll
            for (int nt = 0; nt < 4; nt++)
                O[((size_t)(b * L + qr) * 8 + h) * 64 + nt * 16 + col] =
                    __float2bfloat16(OB[nt][reg] * lr[reg]);
        }
    }
}

// ---------------------------------------------------------------------------
// LayerNorm over last dim (512). x = f1 [+ f2] [+ rb]. Dual output.
// ---------------------------------------------------------------------------
__global__ __launch_bounds__(256) void layernorm_k(const float* __restrict__ f1,
                                                   const float* __restrict__ f2,
                                                   const float* __restrict__ rb,
                                                   const float* __restrict__ g,
                                                   const float* __restrict__ bb,
                                                   float* __restrict__ out32,
                                                   __hip_bfloat16* __restrict__ out16)
{
    const int row = blockIdx.x;
    const int t   = threadIdx.x;
    const size_t base = (size_t)row * 512;
    const int i0 = t * 2;

    float a0 = f1[base + i0], a1 = f1[base + i0 + 1];
    if (f2) { a0 += f2[base + i0]; a1 += f2[base + i0 + 1]; }
    if (rb) { a0 += rb[base + i0]; a1 += rb[base + i0 + 1]; }

    float s = a0 + a1, ss = a0 * a0 + a1 * a1;
    #pragma unroll
    for (int off = 32; off > 0; off >>= 1) {
        s  += __shfl_xor(s, off);
        ss += __shfl_xor(ss, off);
    }
    __shared__ float red[16];
    const int lane = t & 63, wid = t >> 6;
    if (lane == 0) { red[wid] = s; red[8 + wid] = ss; }
    __syncthreads();
    if (t == 0) {
        const float S  = red[0] + red[1] + red[2] + red[3];
        const float SS = red[8] + red[9] + red[10] + red[11];
        const float mu = S * (1.f / 512.f);
        const float var = SS * (1.f / 512.f) - mu * mu;
        red[0] = mu;
        red[1] = rsqrtf(fmaxf(var, 0.f) + 1e-5f);
    }
    __syncthreads();
    const float mu = red[0], rstd = red[1];
    const float y0 = (a0 - mu) * rstd * g[i0]     + bb[i0];
    const float y1 = (a1 - mu) * rstd * g[i0 + 1] + bb[i0 + 1];
    if (out32) { out32[base + i0] = y0; out32[base + i0 + 1] = y1; }
    if (out16) { out16[base + i0] = __float2bfloat16(y0); out16[base + i0 + 1] = __float2bfloat16(y1); }
}

// ---------------------------------------------------------------------------
extern "C" void kernel_launch(void* const* d_in, const int* in_sizes, int n_in,
                              void* d_out, int out_size, void* d_ws, size_t ws_size,
                              hipStream_t stream)
{
    const float* q   = (const float*)d_in[0];
    const float* k   = (const float*)d_in[1];
    const float* v   = (const float*)d_in[2];
    const float* Wq  = (const float*)d_in[3];
    const float* bq  = (const float*)d_in[4];
    const float* Wk  = (const float*)d_in[5];
    const float* bk  = (const float*)d_in[6];
    const float* Wv  = (const float*)d_in[7];
    const float* bv  = (const float*)d_in[8];
    const float* Wo  = (const float*)d_in[9];
    const float* bo  = (const float*)d_in[10];
    const float* Wc1 = (const float*)d_in[11];
    const float* bc1 = (const float*)d_in[12];
    const float* Wc2 = (const float*)d_in[13];
    const float* bc2 = (const float*)d_in[14];
    const float* g1  = (const float*)d_in[15];
    const float* b1  = (const float*)d_in[16];
    const float* g2  = (const float*)d_in[17];
    const float* b2  = (const float*)d_in[18];
    const float* Wl  = (const float*)d_in[19];
    const float* bl  = (const float*)d_in[20];
    float* out = (float*)d_out;

    const int B = 4, L = 2048, H = 8;
    const int M = B * L;                        // 8192

    // Workspace map (bytes; peak 82.3 MB):
    //   Ab (25.2 MB bf16 inputs) overlays A2+X1 start (dead until LN1;
    //   Ab dead after qkv). Other overlays R6-verified.
    char* base = (char*)d_ws;
    unsigned short* Wall = (unsigned short*)(base + 0);          // 6.8 MB, live all
    unsigned short* Wob  = (unsigned short*)(base + 1572864);
    unsigned short* Wlb  = (unsigned short*)(base + 2097152);
    unsigned short* Wc1b = (unsigned short*)(base + 2621440);
    unsigned short* Wc2b = (unsigned short*)(base + 4718592);
    unsigned short* Qb   = (unsigned short*)(base + 6815744);    // -> dead after attn
    unsigned short* Kb   = (unsigned short*)(base + 15204352);   // -> dead after attn
    unsigned short* Vt   = (unsigned short*)(base + 23592960);   // -> dead after attn
    unsigned short* A1   = (unsigned short*)(base + 31981568);   // -> dead after Wo
    unsigned short* Ab   = (unsigned short*)(base + 40370176);   // bf16 q,k,v -> dead after qkv
    float*          A2   = (float*)(base + 40370176);            // -> dead after LN1
    float*          X1   = (float*)(base + 57147392);            // live to LN2
    unsigned short* X1b  = (unsigned short*)(base + 73924608);   // -> dead after FFN1
    unsigned short* X2b  = (unsigned short*)(base + 73924608);   // reuse
    unsigned short* H1   = (unsigned short*)(base + 6815744);    // 33.5 MB over Qb..A1
    float*          Y2   = (float*)(base + 40370176);            // reuse A2

    const dim3 blk(256);

    // 1a: weights fp32 -> bf16
    WArg wa;
    wa.w[0] = Wq; wa.w[1] = Wk; wa.w[2] = Wv; wa.w[3] = Wo; wa.w[4] = Wl;
    wa.w[5] = Wc1; wa.w[6] = Wc2; wa.wd = Wall;
    conv_w<<<dim3(3328), blk, 0, stream>>>(wa);

    // 1b: inputs q,k,v fp32 -> bf16 (12.58M elems)
    conv_in<<<dim3(12288), blk, 0, stream>>>(q, k, v, Ab);

    // 2: batched QKV projections (bf16 A, 2-phase; z=2 writes Vt transposed)
    QkvArg qa;
    qa.A0 = Ab; qa.A1 = Ab + 4194304; qa.A2 = Ab + 8388608;
    qa.b0 = bq; qa.b1 = bk; qa.b2 = bv;
    qa.C0 = Qb; qa.C1 = Kb; qa.Vt = Vt;
    gemm_qkv<<<dim3(4, 64, 3), blk, 0, stream>>>(qa, Wall, M, 512, 512);

    // 3: flash attention v9 (R6-verified) -> bf16 A1
    attn_mfma<<<dim3(16, B * H), blk, 0, stream>>>(Qb, Kb, Vt, (__hip_bfloat16*)A1, L);

    // 4: att @ Wo^T + bo -> fp32
    gemm_mfma64<float, false><<<dim3(4, 128), blk, 0, stream>>>(A1, Wob, bo, A2, M, 512, 512);

    // 5: x = LN(v + attO) -> fp32 X1 + bf16 X1b
    layernorm_k<<<dim3(M), blk, 0, stream>>>(A2, nullptr, v, g1, b1, X1, (__hip_bfloat16*)X1b);

    // 6: h1 = relu(x @ Wc1^T + bc1) -> bf16 [M,2048]
    gemm_mfma<__hip_bfloat16, true><<<dim3(16, 64), blk, 0, stream>>>(X1b, Wc1b, bc1, (__hip_bfloat16*)H1, M, 2048, 512);

    // 7: y2 = h1 @ Wc2^T + bc2 -> fp32
    gemm_mfma64<float, false><<<dim3(4, 128), blk, 0, stream>>>(H1, Wc2b, bc2, Y2, M, 512, 2048);

    // 8: x2 = LN(x + y2) -> bf16
    layernorm_k<<<dim3(M), blk, 0, stream>>>(X1, Y2, nullptr, g2, b2, nullptr, (__hip_bfloat16*)X2b);

    // 9: out = x2 @ Wl^T + bl -> fp32 d_out
    gemm_mfma64<float, false><<<dim3(4, 128), blk, 0, stream>>>(X2b, Wlb, bl, out, M, 512, 512);
}

// Round 12
// 313.158 us; speedup vs baseline: 1.2340x; 1.0182x over previous
//
#include <hip/hip_runtime.h>
#include <hip/hip_bf16.h>

// Problem constants: B=4, L=2048, d_model=d_value=512, H=8, E=64, d4=2048.
// External inputs/output fp32. Internal compute: bf16 MFMA.
//
// R11: 2-phase double-buffered GEMMs (verified, total 318.8).
// R12: intermediate-precision diet - A2/Y2/X1 fp32 intermediates -> bf16.
// LN reads bf16 (+fp32 residual input v), writes bf16 only; LN2 runs
// in-place on X1b (reads precede writes per thread). Saves ~110 MB HBM
// (~18 us). LN internal math stays fp32.

typedef __attribute__((ext_vector_type(8))) short sh8;    // 8 bf16 (A/B frag)
typedef __attribute__((ext_vector_type(4))) float f32x4;  // C/D frag

#define QSCALE 0.18033688011110543f   // 0.125 * log2(e): folded into Q projection

__device__ __forceinline__ void storeOut(float* p, float v) { *p = v; }
__device__ __forceinline__ void storeOut(__hip_bfloat16* p, float v) { *p = __float2bfloat16(v); }

// async global->LDS, 16 B per lane, wave-uniform LDS base (m97 pattern)
__device__ __forceinline__ void gl_lds16(const void* g, void* l) {
    __builtin_amdgcn_global_load_lds((const __attribute__((address_space(1))) void*)g,
                                     (__attribute__((address_space(3))) void*)l, 16, 0, 0);
}

// pack two fp32 into one dword of two bf16 (RNE)
__device__ __forceinline__ unsigned pk_bf16(float a, float b) {
    __hip_bfloat162 h = __float22bfloat162_rn(make_float2(a, b));
    return *(unsigned*)&h;
}
__device__ __forceinline__ float bf2f(unsigned short u) {
    unsigned x = (unsigned)u << 16;
    return *(float*)&x;
}

// ---------------------------------------------------------------------------
// Weights fp32 -> bf16 into one contiguous ws region.
// Order: Wq,Wk,Wv,Wo,Wl,Wc1,Wc2 (3407872 elements).
// ---------------------------------------------------------------------------
struct WArg { const float* w[7]; unsigned short* wd; };
__global__ __launch_bounds__(256) void conv_w(WArg p)
{
    const int i = (blockIdx.x * 256 + threadIdx.x) * 4;
    if (i >= 3407872) return;
    const float* s; int off;
    if      (i < 262144)  { s = p.w[0]; off = i; }
    else if (i < 524288)  { s = p.w[1]; off = i - 262144; }
    else if (i < 786432)  { s = p.w[2]; off = i - 524288; }
    else if (i < 1048576) { s = p.w[3]; off = i - 786432; }
    else if (i < 1310720) { s = p.w[4]; off = i - 1048576; }
    else if (i < 2359296) { s = p.w[5]; off = i - 1310720; }
    else                  { s = p.w[6]; off = i - 2359296; }
    const float4 v = *(const float4*)(s + off);
    *(uint2*)(p.wd + i) = make_uint2(pk_bf16(v.x, v.y), pk_bf16(v.z, v.w));
}

// ---------------------------------------------------------------------------
// Inputs q,k,v fp32 -> bf16 (3 x 4194304 elements) into Ab region.
// ---------------------------------------------------------------------------
__global__ __launch_bounds__(256) void conv_in(const float* __restrict__ q,
                                               const float* __restrict__ k,
                                               const float* __restrict__ v,
                                               unsigned short* __restrict__ dst)
{
    const int i = (blockIdx.x * 256 + threadIdx.x) * 4;
    if (i >= 12582912) return;
    const float* s; int off;
    if      (i < 4194304) { s = q; off = i; }
    else if (i < 8388608) { s = k; off = i - 4194304; }
    else                  { s = v; off = i - 8388608; }
    const float4 x = *(const float4*)(s + off);
    *(uint2*)(dst + i) = make_uint2(pk_bf16(x.x, x.y), pk_bf16(x.z, x.w));
}

// ---------------------------------------------------------------------------
// Batched QKV GEMM (grid.z = 0,1,2), 2-PHASE double-buffered. A bf16
// (conv_in), staged 8 lanes/row, chunk-XOR over 8. BK=64.
// z=0: scaled by QSCALE -> Qb. z=1 -> Kb. z=2: written TRANSPOSED into
// Vt[B*H,64,L]. LDS 64 KB -> 2 blocks/CU.
// ---------------------------------------------------------------------------
struct QkvArg {
    const unsigned short *A0, *A1, *A2;    // bf16 [M,512]
    const float *b0, *b1, *b2;
    unsigned short *C0, *C1;               // Qb, Kb [B,L,H,64]
    unsigned short *Vt;                    // [B*H,64,L]
};
__global__ __launch_bounds__(256, 2) void gemm_qkv(QkvArg ar, const unsigned short* __restrict__ Wall,
                                                   int M, int N, int K)
{
    const int z = blockIdx.z;
    const unsigned short* A = z == 0 ? ar.A0 : (z == 1 ? ar.A1 : ar.A2);
    const unsigned short* W = Wall + (size_t)z * 262144;
    const float* bias = z == 0 ? ar.b0 : (z == 1 ? ar.b1 : ar.b2);

    __shared__ unsigned short AsL[2][8192];   // [buf][row:128][chunk:8][8 bf16] swz
    __shared__ unsigned short BsL[2][8192];
    const int t    = threadIdx.x;
    const int wave = t >> 6, lane = t & 63;
    const int quad = lane >> 4, col = lane & 15;
    const int wm   = wave >> 1, wn = wave & 1;
    const int m0   = blockIdx.y * 128, n0 = blockIdx.x * 128;

    auto stage = [&](int k0, int buf) {
        #pragma unroll
        for (int seg = 0; seg < 4; seg++) {
            const int r0  = (seg * 4 + wave) * 8;  // wave-uniform
            const int row = r0 + (lane >> 3);
            const int ck  = (lane & 7) ^ (row & 7);
            gl_lds16(A + (size_t)(m0 + row) * K + k0 + ck * 8, &AsL[buf][r0 * 64]);
            gl_lds16(W + (size_t)(n0 + row) * K + k0 + ck * 8, &BsL[buf][r0 * 64]);
        }
    };

    f32x4 acc[4][4];
    #pragma unroll
    for (int mt = 0; mt < 4; mt++)
        #pragma unroll
        for (int nt = 0; nt < 4; nt++)
            acc[mt][nt] = (f32x4){0.f, 0.f, 0.f, 0.f};

    stage(0, 0);
    __syncthreads();
    int cur = 0;
    for (int k0 = 0; k0 < K; k0 += 64) {
        if (k0 + 64 < K) stage(k0 + 64, cur ^ 1);
        #pragma unroll
        for (int kc = 0; kc < 2; kc++) {
            sh8 af[4], bf[4];
            #pragma unroll
            for (int mt = 0; mt < 4; mt++) {
                const int arow = wm * 64 + mt * 16 + col;
                af[mt] = *(const sh8*)&AsL[cur][arow * 64 + (((kc * 4 + quad) ^ (arow & 7)) << 3)];
            }
            #pragma unroll
            for (int nt = 0; nt < 4; nt++) {
                const int nr = wn * 64 + nt * 16 + col;
                bf[nt] = *(const sh8*)&BsL[cur][nr * 64 + (((kc * 4 + quad) ^ (nr & 7)) << 3)];
            }
            #pragma unroll
            for (int mt = 0; mt < 4; mt++)
                #pragma unroll
                for (int nt = 0; nt < 4; nt++)
                    acc[mt][nt] = __builtin_amdgcn_mfma_f32_16x16x32_bf16(af[mt], bf[nt], acc[mt][nt], 0, 0, 0);
        }
        __syncthreads();
        cur ^= 1;
    }

    if (z < 2) {
        unsigned short* C = z == 0 ? ar.C0 : ar.C1;
        const float scale = z == 0 ? QSCALE : 1.0f;
        #pragma unroll
        for (int nt = 0; nt < 4; nt++) {
            const int cn = n0 + wn * 64 + nt * 16 + col;
            const float bj = bias[cn];
            #pragma unroll
            for (int mt = 0; mt < 4; mt++) {
                const int rm = m0 + wm * 64 + mt * 16 + quad * 4;
                #pragma unroll
                for (int reg = 0; reg < 4; reg++)
                    C[(size_t)(rm + reg) * N + cn] =
                        (unsigned short)__bfloat16_as_ushort(__float2bfloat16((acc[mt][nt][reg] + bj) * scale));
            }
        }
    } else {
        // V: write transposed [B*H, 64, L]; 4 consecutive s rows pack to 8 B.
        const int b = m0 >> 11;                    // L = 2048
        #pragma unroll
        for (int nt = 0; nt < 4; nt++) {
            const int cn = n0 + wn * 64 + nt * 16 + col;
            const int h = cn >> 6, e = cn & 63;
            const float bj = bias[cn];
            #pragma unroll
            for (int mt = 0; mt < 4; mt++) {
                const int s0r = (m0 + wm * 64 + mt * 16 + quad * 4) & 2047;
                float cv[4];
                #pragma unroll
                for (int reg = 0; reg < 4; reg++) cv[reg] = acc[mt][nt][reg] + bj;
                *(uint2*)(ar.Vt + ((size_t)(b * 8 + h) * 64 + e) * 2048 + s0r) =
                    make_uint2(pk_bf16(cv[0], cv[1]), pk_bf16(cv[2], cv[3]));
            }
        }
    }
}

// ---------------------------------------------------------------------------
// MFMA GEMM 128x128, BK=64 (FFN1), 2-PHASE double-buffered (R11).
// LDS 64 KB -> 2 blocks/CU.
// ---------------------------------------------------------------------------
template <typename TOUT, bool RELU>
__global__ __launch_bounds__(256, 2) void gemm_mfma(const unsigned short* __restrict__ A,
                                                    const unsigned short* __restrict__ W,
                                                    const float* __restrict__ bias,
                                                    TOUT* __restrict__ C,
                                                    int M, int N, int K)
{
    __shared__ unsigned short AsL[2][8192];   // [buf][row:128][chunk:8][8 bf16] swz
    __shared__ unsigned short BsL[2][8192];
    const int t    = threadIdx.x;
    const int wave = t >> 6, lane = t & 63;
    const int quad = lane >> 4, col = lane & 15;
    const int wm   = wave >> 1, wn = wave & 1;
    const int m0   = blockIdx.y * 128, n0 = blockIdx.x * 128;

    auto stage = [&](int k0, int buf) {
        #pragma unroll
        for (int seg = 0; seg < 4; seg++) {
            const int r0  = (seg * 4 + wave) * 8;  // wave-uniform
            const int row = r0 + (lane >> 3);
            const int ck  = (lane & 7) ^ (row & 7);
            gl_lds16(A + (size_t)(m0 + row) * K + k0 + ck * 8, &AsL[buf][r0 * 64]);
            gl_lds16(W + (size_t)(n0 + row) * K + k0 + ck * 8, &BsL[buf][r0 * 64]);
        }
    };

    f32x4 acc[4][4];
    #pragma unroll
    for (int mt = 0; mt < 4; mt++)
        #pragma unroll
        for (int nt = 0; nt < 4; nt++)
            acc[mt][nt] = (f32x4){0.f, 0.f, 0.f, 0.f};

    stage(0, 0);
    __syncthreads();
    int cur = 0;
    for (int k0 = 0; k0 < K; k0 += 64) {
        if (k0 + 64 < K) stage(k0 + 64, cur ^ 1);
        #pragma unroll
        for (int kc = 0; kc < 2; kc++) {
            sh8 af[4], bf[4];
            #pragma unroll
            for (int mt = 0; mt < 4; mt++) {
                const int ar = wm * 64 + mt * 16 + col;
                af[mt] = *(const sh8*)&AsL[cur][ar * 64 + (((kc * 4 + quad) ^ (ar & 7)) << 3)];
            }
            #pragma unroll
            for (int nt = 0; nt < 4; nt++) {
                const int nr = wn * 64 + nt * 16 + col;
                bf[nt] = *(const sh8*)&BsL[cur][nr * 64 + (((kc * 4 + quad) ^ (nr & 7)) << 3)];
            }
            #pragma unroll
            for (int mt = 0; mt < 4; mt++)
                #pragma unroll
                for (int nt = 0; nt < 4; nt++)
                    acc[mt][nt] = __builtin_amdgcn_mfma_f32_16x16x32_bf16(af[mt], bf[nt], acc[mt][nt], 0, 0, 0);
        }
        __syncthreads();
        cur ^= 1;
    }
    #pragma unroll
    for (int nt = 0; nt < 4; nt++) {
        const int cn = n0 + wn * 64 + nt * 16 + col;
        const float bj = bias[cn];
        #pragma unroll
        for (int mt = 0; mt < 4; mt++) {
            const int rm = m0 + wm * 64 + mt * 16 + quad * 4;
            #pragma unroll
            for (int reg = 0; reg < 4; reg++) {
                float cv = acc[mt][nt][reg] + bj;
                if (RELU) cv = fmaxf(cv, 0.f);
                storeOut(&C[(size_t)(rm + reg) * N + cn], cv);
            }
        }
    }
}

// ---------------------------------------------------------------------------
// MFMA GEMM 64x128 tile, BK=64, 2-PHASE double-buffered (R11).
// LDS 48 KB -> 3 blocks/CU.
// ---------------------------------------------------------------------------
template <typename TOUT, bool RELU>
__global__ __launch_bounds__(256, 2) void gemm_mfma64(const unsigned short* __restrict__ A,
                                                      const unsigned short* __restrict__ W,
                                                      const float* __restrict__ bias,
                                                      TOUT* __restrict__ C,
                                                      int M, int N, int K)
{
    __shared__ unsigned short AsL[2][4096];   // [buf][row:64][chunk:8][8 bf16] swz
    __shared__ unsigned short BsL[2][8192];
    const int t    = threadIdx.x;
    const int wave = t >> 6, lane = t & 63;
    const int quad = lane >> 4, col = lane & 15;
    const int wm   = wave >> 1, wn = wave & 1;
    const int m0   = blockIdx.y * 64, n0 = blockIdx.x * 128;

    auto stage = [&](int k0, int buf) {
        #pragma unroll
        for (int seg = 0; seg < 2; seg++) {
            const int r0  = (seg * 4 + wave) * 8;  // wave-uniform, 0..56
            const int row = r0 + (lane >> 3);
            const int ck  = (lane & 7) ^ (row & 7);
            gl_lds16(A + (size_t)(m0 + row) * K + k0 + ck * 8, &AsL[buf][r0 * 64]);
        }
        #pragma unroll
        for (int seg = 0; seg < 4; seg++) {
            const int r0  = (seg * 4 + wave) * 8;
            const int row = r0 + (lane >> 3);
            const int ck  = (lane & 7) ^ (row & 7);
            gl_lds16(W + (size_t)(n0 + row) * K + k0 + ck * 8, &BsL[buf][r0 * 64]);
        }
    };

    f32x4 acc[2][4];
    #pragma unroll
    for (int mt = 0; mt < 2; mt++)
        #pragma unroll
        for (int nt = 0; nt < 4; nt++)
            acc[mt][nt] = (f32x4){0.f, 0.f, 0.f, 0.f};

    stage(0, 0);
    __syncthreads();
    int cur = 0;
    for (int k0 = 0; k0 < K; k0 += 64) {
        if (k0 + 64 < K) stage(k0 + 64, cur ^ 1);
        #pragma unroll
        for (int kc = 0; kc < 2; kc++) {
            sh8 af[2], bf[4];
            #pragma unroll
            for (int mt = 0; mt < 2; mt++) {
                const int ar = wm * 32 + mt * 16 + col;
                af[mt] = *(const sh8*)&AsL[cur][ar * 64 + (((kc * 4 + quad) ^ (ar & 7)) << 3)];
            }
            #pragma unroll
            for (int nt = 0; nt < 4; nt++) {
                const int nr = wn * 64 + nt * 16 + col;
                bf[nt] = *(const sh8*)&BsL[cur][nr * 64 + (((kc * 4 + quad) ^ (nr & 7)) << 3)];
            }
            #pragma unroll
            for (int mt = 0; mt < 2; mt++)
                #pragma unroll
                for (int nt = 0; nt < 4; nt++)
                    acc[mt][nt] = __builtin_amdgcn_mfma_f32_16x16x32_bf16(af[mt], bf[nt], acc[mt][nt], 0, 0, 0);
        }
        __syncthreads();
        cur ^= 1;
    }
    #pragma unroll
    for (int nt = 0; nt < 4; nt++) {
        const int cn = n0 + wn * 64 + nt * 16 + col;
        const float bj = bias[cn];
        #pragma unroll
        for (int mt = 0; mt < 2; mt++) {
            const int rm = m0 + wm * 32 + mt * 16 + quad * 4;
            #pragma unroll
            for (int reg = 0; reg < 4; reg++) {
                float cv = acc[mt][nt][reg] + bj;
                if (RELU) cv = fmaxf(cv, 0.f);
                storeOut(&C[(size_t)(rm + reg) * N + cn], cv);
            }
        }
    }
}

// ---------------------------------------------------------------------------
// MFMA flash attention v9 (causal, reverse-paired tiles, COALESCED staging).
// R6-verified config (~56 us; R10: structure is round-throughput-bound).
// ---------------------------------------------------------------------------
__global__ __launch_bounds__(256, 2) void attn_mfma(const unsigned short* __restrict__ Qb,
                                                    const unsigned short* __restrict__ Kb,
                                                    const unsigned short* __restrict__ Vt,
                                                    __hip_bfloat16* __restrict__ O,
                                                    int L)
{
    __shared__ unsigned short Ks[2][4096];       // [buf][key:64][e-chunk swz] 16 KB
    __shared__ unsigned short Vs[2][4096];       // [buf][e:64][key-chunk swz] 16 KB
    __shared__ unsigned short PsA[4][16][72];    // per wave [qrow:16][key:64+pad] 9 KB
    __shared__ unsigned short PsB[4][16][72];

    const int i    = blockIdx.x;                 // 0..15
    const int bh   = blockIdx.y;
    const int b    = bh >> 3, h = bh & 7;        // H = 8
    const int t    = threadIdx.x;
    const int w    = t >> 6, lane = t & 63;
    const int quad = lane >> 4, col = lane & 15;

    const int qtA = i, qtB = 31 - i;             // light / heavy tile
    const int qrowA = qtA * 64 + w * 16 + col;
    const int qrowB = qtB * 64 + w * 16 + col;
    const int S = 32 - i;                        // rounds (tile B needs all)

    const int srow = lane >> 3;                  // row offset within instr (0..7)
    const int scp  = lane & 7;                   // destination chunk

    sh8 qfA[2], qfB[2];
    {
        const size_t qa = ((size_t)(b * L + qrowA) * 8 + h) * 64;
        qfA[0] = *(const sh8*)(Qb + qa + quad * 8);
        qfA[1] = *(const sh8*)(Qb + qa + 32 + quad * 8);
        const size_t qb2 = ((size_t)(b * L + qrowB) * 8 + h) * 64;
        qfB[0] = *(const sh8*)(Qb + qb2 + quad * 8);
        qfB[1] = *(const sh8*)(Qb + qb2 + 32 + quad * 8);
    }

    f32x4 OA[4], OB[4];
    #pragma unroll
    for (int nt = 0; nt < 4; nt++) { OA[nt] = (f32x4){0.f,0.f,0.f,0.f}; OB[nt] = (f32x4){0.f,0.f,0.f,0.f}; }
    float lA = 0.f, lB = 0.f;

    {
        #pragma unroll
        for (int seg = 0; seg < 2; seg++) {
            const int r0  = (seg * 4 + w) * 8;   // wave-uniform row base
            const int row = r0 + srow;
            const int ck  = scp ^ (row & 7);     // source chunk (involution)
            gl_lds16(Kb + ((size_t)(b * L + row) * 8 + h) * 64 + ck * 8, &Ks[0][r0 * 64]);
            gl_lds16(Vt + (size_t)(bh * 64 + row) * L + ck * 8, &Vs[0][r0 * 64]);
        }
        __syncthreads();
    }

    int cur = 0;
    for (int r = 0; r < S; r++) {
        if (r + 1 < S) {
            const int k1 = (r + 1) * 64;
            #pragma unroll
            for (int seg = 0; seg < 2; seg++) {
                const int r0  = (seg * 4 + w) * 8;
                const int row = r0 + srow;
                const int ck  = scp ^ (row & 7);
                gl_lds16(Kb + ((size_t)(b * L + k1 + row) * 8 + h) * 64 + ck * 8, &Ks[cur ^ 1][r0 * 64]);
                gl_lds16(Vt + (size_t)(bh * 64 + row) * L + k1 + ck * 8, &Vs[cur ^ 1][r0 * 64]);
            }
        }

        const int k0 = r * 64;
        const bool actA  = (r <= i);
        const bool maskA = (r == i);
        const bool maskB = (r == S - 1);

        f32x4 stA[4], stB[4];
        const f32x4 zz = {0.f, 0.f, 0.f, 0.f};
        #pragma unroll
        for (int ntk = 0; ntk < 4; ntk++) {
            const int key = ntk * 16 + col;
            const int sw  = key & 7;
            sh8 kf0 = *(const sh8*)&Ks[cur][key * 64 + ((quad ^ sw) << 3)];
            sh8 kf1 = *(const sh8*)&Ks[cur][key * 64 + (((quad + 4) ^ sw) << 3)];
            f32x4 aB = __builtin_amdgcn_mfma_f32_16x16x32_bf16(kf0, qfB[0], zz, 0, 0, 0);
            stB[ntk] = __builtin_amdgcn_mfma_f32_16x16x32_bf16(kf1, qfB[1], aB, 0, 0, 0);
            if (actA) {
                f32x4 aA = __builtin_amdgcn_mfma_f32_16x16x32_bf16(kf0, qfA[0], zz, 0, 0, 0);
                stA[ntk] = __builtin_amdgcn_mfma_f32_16x16x32_bf16(kf1, qfA[1], aA, 0, 0, 0);
            }
        }

        {
            if (maskB) {
                #pragma unroll
                for (int ntk = 0; ntk < 4; ntk++)
                    #pragma unroll
                    for (int reg = 0; reg < 4; reg++)
                        if (k0 + ntk * 16 + quad * 4 + reg > qrowB) stB[ntk][reg] = -1e30f;
            }
            #pragma unroll
            for (int ntk = 0; ntk < 4; ntk++) {
                #pragma unroll
                for (int reg = 0; reg < 4; reg++)
                    stB[ntk][reg] = exp2f(stB[ntk][reg]);
                lB += (stB[ntk][0] + stB[ntk][1]) + (stB[ntk][2] + stB[ntk][3]);
                *(uint2*)&PsB[w][col][ntk * 16 + quad * 4] =
                    make_uint2(pk_bf16(stB[ntk][0], stB[ntk][1]), pk_bf16(stB[ntk][2], stB[ntk][3]));
            }
        }
        if (actA) {
            if (maskA) {
                #pragma unroll
                for (int ntk = 0; ntk < 4; ntk++)
                    #pragma unroll
                    for (int reg = 0; reg < 4; reg++)
                        if (k0 + ntk * 16 + quad * 4 + reg > qrowA) stA[ntk][reg] = -1e30f;
            }
            #pragma unroll
            for (int ntk = 0; ntk < 4; ntk++) {
                #pragma unroll
                for (int reg = 0; reg < 4; reg++)
                    stA[ntk][reg] = exp2f(stA[ntk][reg]);
                lA += (stA[ntk][0] + stA[ntk][1]) + (stA[ntk][2] + stA[ntk][3]);
                *(uint2*)&PsA[w][col][ntk * 16 + quad * 4] =
                    make_uint2(pk_bf16(stA[ntk][0], stA[ntk][1]), pk_bf16(stA[ntk][2], stA[ntk][3]));
            }
        }

        #pragma unroll
        for (int kchunk = 0; kchunk < 2; kchunk++) {
            sh8 pfB = *(const sh8*)&PsB[w][col][kchunk * 32 + quad * 8];
            sh8 pfA;
            if (actA) pfA = *(const sh8*)&PsA[w][col][kchunk * 32 + quad * 8];
            #pragma unroll
            for (int nt = 0; nt < 4; nt++) {
                const int e  = nt * 16 + col;
                sh8 vf = *(const sh8*)&Vs[cur][e * 64 + (((kchunk * 4 + quad) ^ (e & 7)) << 3)];
                OB[nt] = __builtin_amdgcn_mfma_f32_16x16x32_bf16(pfB, vf, OB[nt], 0, 0, 0);
                if (actA) OA[nt] = __builtin_amdgcn_mfma_f32_16x16x32_bf16(pfA, vf, OA[nt], 0, 0, 0);
            }
        }
        __syncthreads();
        cur ^= 1;
    }

    lA += __shfl_xor(lA, 16); lA += __shfl_xor(lA, 32);
    lB += __shfl_xor(lB, 16); lB += __shfl_xor(lB, 32);
    {
        const float li = 1.f / lA;
        float lr[4];
        #pragma unroll
        for (int reg = 0; reg < 4; reg++) lr[reg] = __shfl(li, quad * 4 + reg);
        #pragma unroll
        for (int reg = 0; reg < 4; reg++) {
            const int qr = qtA * 64 + w * 16 + quad * 4 + reg;
            #pragma unroll
            for (int nt = 0; nt < 4; nt++)
                O[((size_t)(b * L + qr) * 8 + h) * 64 + nt * 16 + col] =
                    __float2bfloat16(OA[nt][reg] * lr[reg]);
        }
    }
    {
        const float li = 1.f / lB;
        float lr[4];
        #pragma unroll
        for (int reg = 0; reg < 4; reg++) lr[reg] = __shfl(li, quad * 4 + reg);
        #pragma unroll
        for (int reg = 0; reg < 4; reg++) {
            const int qr = qtB * 64 + w * 16 + quad * 4 + reg;
            #pragma unroll
            for (int nt = 0; nt < 4; nt++)
                O[((size_t)(b * L + qr) * 8 + h) * 64 + nt * 16 + col] =
                    __float2bfloat16(OB[nt][reg] * lr[reg]);
        }
    }
}

// ---------------------------------------------------------------------------
// LayerNorm over last dim (512), bf16 in / bf16 out (R12 diet).
// x = f1 [+ f2] [+ rb(fp32)]. In-place safe (reads precede writes/thread).
// ---------------------------------------------------------------------------
__global__ __launch_bounds__(256) void layernorm_k(const unsigned short* __restrict__ f1,
                                                   const unsigned short* __restrict__ f2,
                                                   const float* __restrict__ rb,
                                                   const float* __restrict__ g,
                                                   const float* __restrict__ bb,
                                                   unsigned short* __restrict__ out16)
{
    const int row = blockIdx.x;
    const int t   = threadIdx.x;
    const size_t base = (size_t)row * 512;
    const int i0 = t * 2;

    const unsigned u1 = *(const unsigned*)(f1 + base + i0);
    float a0 = bf2f((unsigned short)(u1 & 0xffff));
    float a1 = bf2f((unsigned short)(u1 >> 16));
    if (f2) {
        const unsigned u2 = *(const unsigned*)(f2 + base + i0);
        a0 += bf2f((unsigned short)(u2 & 0xffff));
        a1 += bf2f((unsigned short)(u2 >> 16));
    }
    if (rb) { a0 += rb[base + i0]; a1 += rb[base + i0 + 1]; }

    float s = a0 + a1, ss = a0 * a0 + a1 * a1;
    #pragma unroll
    for (int off = 32; off > 0; off >>= 1) {
        s  += __shfl_xor(s, off);
        ss += __shfl_xor(ss, off);
    }
    __shared__ float red[16];
    const int lane = t & 63, wid = t >> 6;
    if (lane == 0) { red[wid] = s; red[8 + wid] = ss; }
    __syncthreads();
    if (t == 0) {
        const float S  = red[0] + red[1] + red[2] + red[3];
        const float SS = red[8] + red[9] + red[10] + red[11];
        const float mu = S * (1.f / 512.f);
        const float var = SS * (1.f / 512.f) - mu * mu;
        red[0] = mu;
        red[1] = rsqrtf(fmaxf(var, 0.f) + 1e-5f);
    }
    __syncthreads();
    const float mu = red[0], rstd = red[1];
    const float y0 = (a0 - mu) * rstd * g[i0]     + bb[i0];
    const float y1 = (a1 - mu) * rstd * g[i0 + 1] + bb[i0 + 1];
    *(unsigned*)(out16 + base + i0) = pk_bf16(y0, y1);
}

// ---------------------------------------------------------------------------
extern "C" void kernel_launch(void* const* d_in, const int* in_sizes, int n_in,
                              void* d_out, int out_size, void* d_ws, size_t ws_size,
                              hipStream_t stream)
{
    const float* q   = (const float*)d_in[0];
    const float* k   = (const float*)d_in[1];
    const float* v   = (const float*)d_in[2];
    const float* Wq  = (const float*)d_in[3];
    const float* bq  = (const float*)d_in[4];
    const float* Wk  = (const float*)d_in[5];
    const float* bk  = (const float*)d_in[6];
    const float* Wv  = (const float*)d_in[7];
    const float* bv  = (const float*)d_in[8];
    const float* Wo  = (const float*)d_in[9];
    const float* bo  = (const float*)d_in[10];
    const float* Wc1 = (const float*)d_in[11];
    const float* bc1 = (const float*)d_in[12];
    const float* Wc2 = (const float*)d_in[13];
    const float* bc2 = (const float*)d_in[14];
    const float* g1  = (const float*)d_in[15];
    const float* b1  = (const float*)d_in[16];
    const float* g2  = (const float*)d_in[17];
    const float* b2  = (const float*)d_in[18];
    const float* Wl  = (const float*)d_in[19];
    const float* bl  = (const float*)d_in[20];
    float* out = (float*)d_out;

    const int B = 4, L = 2048, H = 8;
    const int M = B * L;                        // 8192

    // Workspace map (bytes):
    //   Ab (25.2 MB bf16 inputs) at 40370176, dead after qkv.
    //   A2b (8 MB) reuses 40370176 after qkv (written by Wo-GEMM, read LN1).
    //   Y2b (8 MB) at 48758784 (after A2b; A2b dead post-LN1 but keep apart
    //   for clarity; region was Ab's tail, dead).
    //   X1b (16 MB) at 73924608, live LN1 -> FFN1 -> LN2 (in-place X2b).
    char* base = (char*)d_ws;
    unsigned short* Wall = (unsigned short*)(base + 0);          // 6.8 MB, live all
    unsigned short* Wob  = (unsigned short*)(base + 1572864);
    unsigned short* Wlb  = (unsigned short*)(base + 2097152);
    unsigned short* Wc1b = (unsigned short*)(base + 2621440);
    unsigned short* Wc2b = (unsigned short*)(base + 4718592);
    unsigned short* Qb   = (unsigned short*)(base + 6815744);    // -> dead after attn
    unsigned short* Kb   = (unsigned short*)(base + 15204352);   // -> dead after attn
    unsigned short* Vt   = (unsigned short*)(base + 23592960);   // -> dead after attn
    unsigned short* A1   = (unsigned short*)(base + 31981568);   // -> dead after Wo
    unsigned short* Ab   = (unsigned short*)(base + 40370176);   // bf16 q,k,v -> dead after qkv
    unsigned short* A2b  = (unsigned short*)(base + 40370176);   // att@Wo bf16 -> dead after LN1
    unsigned short* Y2b  = (unsigned short*)(base + 48758784);   // FFN2 out bf16 -> dead after LN2
    unsigned short* X1b  = (unsigned short*)(base + 73924608);   // x bf16, live to LN2 (in-place)
    unsigned short* X2b  = (unsigned short*)(base + 73924608);   // = X1b (in-place LN2)
    unsigned short* H1   = (unsigned short*)(base + 6815744);    // 33.5 MB over Qb..A1
    const dim3 blk(256);

    // 1a: weights fp32 -> bf16
    WArg wa;
    wa.w[0] = Wq; wa.w[1] = Wk; wa.w[2] = Wv; wa.w[3] = Wo; wa.w[4] = Wl;
    wa.w[5] = Wc1; wa.w[6] = Wc2; wa.wd = Wall;
    conv_w<<<dim3(3328), blk, 0, stream>>>(wa);

    // 1b: inputs q,k,v fp32 -> bf16 (12.58M elems)
    conv_in<<<dim3(12288), blk, 0, stream>>>(q, k, v, Ab);

    // 2: batched QKV projections (bf16 A, 2-phase; z=2 writes Vt transposed)
    QkvArg qa;
    qa.A0 = Ab; qa.A1 = Ab + 4194304; qa.A2 = Ab + 8388608;
    qa.b0 = bq; qa.b1 = bk; qa.b2 = bv;
    qa.C0 = Qb; qa.C1 = Kb; qa.Vt = Vt;
    gemm_qkv<<<dim3(4, 64, 3), blk, 0, stream>>>(qa, Wall, M, 512, 512);

    // 3: flash attention v9 (R6-verified) -> bf16 A1
    attn_mfma<<<dim3(16, B * H), blk, 0, stream>>>(Qb, Kb, Vt, (__hip_bfloat16*)A1, L);

    // 4: att @ Wo^T + bo -> bf16 A2b (R12: bf16 intermediate)
    gemm_mfma64<__hip_bfloat16, false><<<dim3(4, 128), blk, 0, stream>>>(A1, Wob, bo, (__hip_bfloat16*)A2b, M, 512, 512);

    // 5: x = LN(A2b + v) -> bf16 X1b
    layernorm_k<<<dim3(M), blk, 0, stream>>>(A2b, nullptr, v, g1, b1, X1b);

    // 6: h1 = relu(x @ Wc1^T + bc1) -> bf16 [M,2048]
    gemm_mfma<__hip_bfloat16, true><<<dim3(16, 64), blk, 0, stream>>>(X1b, Wc1b, bc1, (__hip_bfloat16*)H1, M, 2048, 512);

    // 7: y2 = h1 @ Wc2^T + bc2 -> bf16 Y2b
    gemm_mfma64<__hip_bfloat16, false><<<dim3(4, 128), blk, 0, stream>>>(H1, Wc2b, bc2, (__hip_bfloat16*)Y2b, M, 512, 2048);

    // 8: x2 = LN(X1b + Y2b) -> bf16, in place on X1b
    layernorm_k<<<dim3(M), blk, 0, stream>>>(X1b, Y2b, nullptr, g2, b2, X2b);

    // 9: out = x2 @ Wl^T + bl -> fp32 d_out
    gemm_mfma64<float, false><<<dim3(4, 128), blk, 0, stream>>>(X2b, Wlb, bl, out, M, 512, 512);
}

// Round 13
// 309.045 us; speedup vs baseline: 1.2505x; 1.0133x over previous
//
#include <hip/hip_runtime.h>
#include <hip/hip_bf16.h>

// Problem constants: B=4, L=2048, d_model=d_value=512, H=8, E=64, d4=2048.
// External inputs/output fp32. Internal compute: bf16 MFMA.
//
// R12: bf16 intermediates (verified, 313.2).
// R13: (a) conv_in deleted - qkv stages fp32 A directly, BK=32 2-phase
// (A 2x16KB 8 lanes/row XOR8; W 2x8KB 4 lanes/row XOR4; 16 hidden steps);
// (b) XCD-affinity block remap in gemm_mfma/gemm_mfma64: same-A-panel
// n-blocks land on one XCD (lin&7 = XCD slot) -> panel re-reads become
// L2 hits instead of per-XCD L3 fetches (FFN2 reads H1 32MB x4).

typedef __attribute__((ext_vector_type(8))) short sh8;    // 8 bf16 (A/B frag)
typedef __attribute__((ext_vector_type(4))) float f32x4;  // C/D frag

#define QSCALE 0.18033688011110543f   // 0.125 * log2(e): folded into Q projection

__device__ __forceinline__ void storeOut(float* p, float v) { *p = v; }
__device__ __forceinline__ void storeOut(__hip_bfloat16* p, float v) { *p = __float2bfloat16(v); }

// async global->LDS, 16 B per lane, wave-uniform LDS base (m97 pattern)
__device__ __forceinline__ void gl_lds16(const void* g, void* l) {
    __builtin_amdgcn_global_load_lds((const __attribute__((address_space(1))) void*)g,
                                     (__attribute__((address_space(3))) void*)l, 16, 0, 0);
}

// pack two fp32 into one dword of two bf16 (RNE)
__device__ __forceinline__ unsigned pk_bf16(float a, float b) {
    __hip_bfloat162 h = __float22bfloat162_rn(make_float2(a, b));
    return *(unsigned*)&h;
}
__device__ __forceinline__ float bf2f(unsigned short u) {
    unsigned x = (unsigned)u << 16;
    return *(float*)&x;
}
// 8 fp32 -> sh8 bf16 fragment
__device__ __forceinline__ sh8 pk8(float4 a, float4 b) {
    int4 iv = make_int4(pk_bf16(a.x, a.y), pk_bf16(a.z, a.w),
                        pk_bf16(b.x, b.y), pk_bf16(b.z, b.w));
    return *(sh8*)&iv;
}

// ---------------------------------------------------------------------------
// Weights fp32 -> bf16 into one contiguous ws region.
// Order: Wq,Wk,Wv,Wo,Wl,Wc1,Wc2 (3407872 elements).
// ---------------------------------------------------------------------------
struct WArg { const float* w[7]; unsigned short* wd; };
__global__ __launch_bounds__(256) void conv_w(WArg p)
{
    const int i = (blockIdx.x * 256 + threadIdx.x) * 4;
    if (i >= 3407872) return;
    const float* s; int off;
    if      (i < 262144)  { s = p.w[0]; off = i; }
    else if (i < 524288)  { s = p.w[1]; off = i - 262144; }
    else if (i < 786432)  { s = p.w[2]; off = i - 524288; }
    else if (i < 1048576) { s = p.w[3]; off = i - 786432; }
    else if (i < 1310720) { s = p.w[4]; off = i - 1048576; }
    else if (i < 2359296) { s = p.w[5]; off = i - 1310720; }
    else                  { s = p.w[6]; off = i - 2359296; }
    const float4 v = *(const float4*)(s + off);
    *(uint2*)(p.wd + i) = make_uint2(pk_bf16(v.x, v.y), pk_bf16(v.z, v.w));
}

// ---------------------------------------------------------------------------
// Batched QKV GEMM (grid.z = 0,1,2), fp32 A direct, BK=32, 2-PHASE.
// A fp32 staged coalesced: 8 rows/instr, 8 lanes/row (128 B), chunk-XOR
// over 8. W bf16: 16 rows/instr, 4 lanes/row (64 B), chunk-XOR over 4.
// z=0: scaled by QSCALE -> Qb. z=1 -> Kb. z=2 -> Vt[B*H,64,L] transposed.
// LDS 48 KB -> 2 blocks/CU.
// ---------------------------------------------------------------------------
struct QkvArg {
    const float *A0, *A1, *A2;
    const float *b0, *b1, *b2;
    unsigned short *C0, *C1;               // Qb, Kb [B,L,H,64]
    unsigned short *Vt;                    // [B*H,64,L]
};
__global__ __launch_bounds__(256, 2) void gemm_qkv(QkvArg ar, const unsigned short* __restrict__ Wall,
                                                   int M, int N, int K)
{
    const int z = blockIdx.z;
    const float* A = z == 0 ? ar.A0 : (z == 1 ? ar.A1 : ar.A2);
    const unsigned short* W = Wall + (size_t)z * 262144;
    const float* bias = z == 0 ? ar.b0 : (z == 1 ? ar.b1 : ar.b2);

    __shared__ float AsF[2][4096];            // [buf][row:128][chunk:8][4 fp32] 16 KB ea
    __shared__ unsigned short BsL[2][4096];   // [buf][row:128][chunk:4][8 bf16] 8 KB ea
    const int t    = threadIdx.x;
    const int wave = t >> 6, lane = t & 63;
    const int quad = lane >> 4, col = lane & 15;
    const int wm   = wave >> 1, wn = wave & 1;
    const int m0   = blockIdx.y * 128, n0 = blockIdx.x * 128;

    auto stage = [&](int k0, int buf) {
        #pragma unroll
        for (int seg = 0; seg < 4; seg++) {        // A: 8 rows/instr
            const int r0  = (seg * 4 + wave) * 8;  // wave-uniform
            const int row = r0 + (lane >> 3);
            const int ck  = (lane & 7) ^ (row & 7);
            gl_lds16(A + (size_t)(m0 + row) * K + k0 + ck * 4, &AsF[buf][r0 * 32]);
        }
        #pragma unroll
        for (int seg = 0; seg < 2; seg++) {        // W: 16 rows/instr
            const int r0  = (seg * 4 + wave) * 16;
            const int row = r0 + (lane >> 2);
            const int ck  = (lane & 3) ^ (row & 3);
            gl_lds16(W + (size_t)(n0 + row) * K + k0 + ck * 8, &BsL[buf][r0 * 32]);
        }
    };

    f32x4 acc[4][4];
    #pragma unroll
    for (int mt = 0; mt < 4; mt++)
        #pragma unroll
        for (int nt = 0; nt < 4; nt++)
            acc[mt][nt] = (f32x4){0.f, 0.f, 0.f, 0.f};

    stage(0, 0);
    __syncthreads();
    int cur = 0;
    for (int k0 = 0; k0 < K; k0 += 32) {
        if (k0 + 32 < K) stage(k0 + 32, cur ^ 1);
        sh8 af[4], bf[4];
        #pragma unroll
        for (int mt = 0; mt < 4; mt++) {
            const int mr = wm * 64 + mt * 16 + col;
            const int q0 = quad * 2;
            const int m8 = mr & 7;
            float4 f0 = *(const float4*)&AsF[cur][mr * 32 + ((q0 ^ m8) << 2)];
            float4 f1 = *(const float4*)&AsF[cur][mr * 32 + (((q0 + 1) ^ m8) << 2)];
            af[mt] = pk8(f0, f1);
        }
        #pragma unroll
        for (int nt = 0; nt < 4; nt++) {
            const int nr = wn * 64 + nt * 16 + col;
            bf[nt] = *(const sh8*)&BsL[cur][nr * 32 + ((quad ^ (nr & 3)) << 3)];
        }
        #pragma unroll
        for (int mt = 0; mt < 4; mt++)
            #pragma unroll
            for (int nt = 0; nt < 4; nt++)
                acc[mt][nt] = __builtin_amdgcn_mfma_f32_16x16x32_bf16(af[mt], bf[nt], acc[mt][nt], 0, 0, 0);
        __syncthreads();
        cur ^= 1;
    }

    if (z < 2) {
        unsigned short* C = z == 0 ? ar.C0 : ar.C1;
        const float scale = z == 0 ? QSCALE : 1.0f;
        #pragma unroll
        for (int nt = 0; nt < 4; nt++) {
            const int cn = n0 + wn * 64 + nt * 16 + col;
            const float bj = bias[cn];
            #pragma unroll
            for (int mt = 0; mt < 4; mt++) {
                const int rm = m0 + wm * 64 + mt * 16 + quad * 4;
                #pragma unroll
                for (int reg = 0; reg < 4; reg++)
                    C[(size_t)(rm + reg) * N + cn] =
                        (unsigned short)__bfloat16_as_ushort(__float2bfloat16((acc[mt][nt][reg] + bj) * scale));
            }
        }
    } else {
        // V: write transposed [B*H, 64, L]; 4 consecutive s rows pack to 8 B.
        const int b = m0 >> 11;                    // L = 2048
        #pragma unroll
        for (int nt = 0; nt < 4; nt++) {
            const int cn = n0 + wn * 64 + nt * 16 + col;
            const int h = cn >> 6, e = cn & 63;
            const float bj = bias[cn];
            #pragma unroll
            for (int mt = 0; mt < 4; mt++) {
                const int s0r = (m0 + wm * 64 + mt * 16 + quad * 4) & 2047;
                float cv[4];
                #pragma unroll
                for (int reg = 0; reg < 4; reg++) cv[reg] = acc[mt][nt][reg] + bj;
                *(uint2*)(ar.Vt + ((size_t)(b * 8 + h) * 64 + e) * 2048 + s0r) =
                    make_uint2(pk_bf16(cv[0], cv[1]), pk_bf16(cv[2], cv[3]));
            }
        }
    }
}

// ---------------------------------------------------------------------------
// MFMA GEMM 128x128, BK=64 (FFN1), 2-PHASE + XCD-affinity remap (R13).
// lin&7 selects XCD slot; all NB n-blocks of an A-panel land on one XCD.
// ---------------------------------------------------------------------------
template <typename TOUT, bool RELU>
__global__ __launch_bounds__(256, 2) void gemm_mfma(const unsigned short* __restrict__ A,
                                                    const unsigned short* __restrict__ W,
                                                    const float* __restrict__ bias,
                                                    TOUT* __restrict__ C,
                                                    int M, int N, int K)
{
    __shared__ unsigned short AsL[2][8192];   // [buf][row:128][chunk:8][8 bf16] swz
    __shared__ unsigned short BsL[2][8192];
    const int t    = threadIdx.x;
    const int wave = t >> 6, lane = t & 63;
    const int quad = lane >> 4, col = lane & 15;
    const int wm   = wave >> 1, wn = wave & 1;
    // XCD-affinity remap (MB divisible by 8)
    const int NB  = gridDim.x, MB = gridDim.y;
    const int lin = blockIdx.x + NB * blockIdx.y;
    const int mi  = (lin & 7) * (MB >> 3) + (lin >> 3) / NB;
    const int ni  = (lin >> 3) % NB;
    const int m0  = mi * 128, n0 = ni * 128;

    auto stage = [&](int k0, int buf) {
        #pragma unroll
        for (int seg = 0; seg < 4; seg++) {
            const int r0  = (seg * 4 + wave) * 8;  // wave-uniform
            const int row = r0 + (lane >> 3);
            const int ck  = (lane & 7) ^ (row & 7);
            gl_lds16(A + (size_t)(m0 + row) * K + k0 + ck * 8, &AsL[buf][r0 * 64]);
            gl_lds16(W + (size_t)(n0 + row) * K + k0 + ck * 8, &BsL[buf][r0 * 64]);
        }
    };

    f32x4 acc[4][4];
    #pragma unroll
    for (int mt = 0; mt < 4; mt++)
        #pragma unroll
        for (int nt = 0; nt < 4; nt++)
            acc[mt][nt] = (f32x4){0.f, 0.f, 0.f, 0.f};

    stage(0, 0);
    __syncthreads();
    int cur = 0;
    for (int k0 = 0; k0 < K; k0 += 64) {
        if (k0 + 64 < K) stage(k0 + 64, cur ^ 1);
        #pragma unroll
        for (int kc = 0; kc < 2; kc++) {
            sh8 af[4], bf[4];
            #pragma unroll
            for (int mt = 0; mt < 4; mt++) {
                const int ar = wm * 64 + mt * 16 + col;
                af[mt] = *(const sh8*)&AsL[cur][ar * 64 + (((kc * 4 + quad) ^ (ar & 7)) << 3)];
            }
            #pragma unroll
            for (int nt = 0; nt < 4; nt++) {
                const int nr = wn * 64 + nt * 16 + col;
                bf[nt] = *(const sh8*)&BsL[cur][nr * 64 + (((kc * 4 + quad) ^ (nr & 7)) << 3)];
            }
            #pragma unroll
            for (int mt = 0; mt < 4; mt++)
                #pragma unroll
                for (int nt = 0; nt < 4; nt++)
                    acc[mt][nt] = __builtin_amdgcn_mfma_f32_16x16x32_bf16(af[mt], bf[nt], acc[mt][nt], 0, 0, 0);
        }
        __syncthreads();
        cur ^= 1;
    }
    #pragma unroll
    for (int nt = 0; nt < 4; nt++) {
        const int cn = n0 + wn * 64 + nt * 16 + col;
        const float bj = bias[cn];
        #pragma unroll
        for (int mt = 0; mt < 4; mt++) {
            const int rm = m0 + wm * 64 + mt * 16 + quad * 4;
            #pragma unroll
            for (int reg = 0; reg < 4; reg++) {
                float cv = acc[mt][nt][reg] + bj;
                if (RELU) cv = fmaxf(cv, 0.f);
                storeOut(&C[(size_t)(rm + reg) * N + cn], cv);
            }
        }
    }
}

// ---------------------------------------------------------------------------
// MFMA GEMM 64x128 tile, BK=64, 2-PHASE + XCD-affinity remap (R13).
// ---------------------------------------------------------------------------
template <typename TOUT, bool RELU>
__global__ __launch_bounds__(256, 2) void gemm_mfma64(const unsigned short* __restrict__ A,
                                                      const unsigned short* __restrict__ W,
                                                      const float* __restrict__ bias,
                                                      TOUT* __restrict__ C,
                                                      int M, int N, int K)
{
    __shared__ unsigned short AsL[2][4096];   // [buf][row:64][chunk:8][8 bf16] swz
    __shared__ unsigned short BsL[2][8192];
    const int t    = threadIdx.x;
    const int wave = t >> 6, lane = t & 63;
    const int quad = lane >> 4, col = lane & 15;
    const int wm   = wave >> 1, wn = wave & 1;
    // XCD-affinity remap (MB divisible by 8)
    const int NB  = gridDim.x, MB = gridDim.y;
    const int lin = blockIdx.x + NB * blockIdx.y;
    const int mi  = (lin & 7) * (MB >> 3) + (lin >> 3) / NB;
    const int ni  = (lin >> 3) % NB;
    const int m0  = mi * 64, n0 = ni * 128;

    auto stage = [&](int k0, int buf) {
        #pragma unroll
        for (int seg = 0; seg < 2; seg++) {
            const int r0  = (seg * 4 + wave) * 8;  // wave-uniform, 0..56
            const int row = r0 + (lane >> 3);
            const int ck  = (lane & 7) ^ (row & 7);
            gl_lds16(A + (size_t)(m0 + row) * K + k0 + ck * 8, &AsL[buf][r0 * 64]);
        }
        #pragma unroll
        for (int seg = 0; seg < 4; seg++) {
            const int r0  = (seg * 4 + wave) * 8;
            const int row = r0 + (lane >> 3);
            const int ck  = (lane & 7) ^ (row & 7);
            gl_lds16(W + (size_t)(n0 + row) * K + k0 + ck * 8, &BsL[buf][r0 * 64]);
        }
    };

    f32x4 acc[2][4];
    #pragma unroll
    for (int mt = 0; mt < 2; mt++)
        #pragma unroll
        for (int nt = 0; nt < 4; nt++)
            acc[mt][nt] = (f32x4){0.f, 0.f, 0.f, 0.f};

    stage(0, 0);
    __syncthreads();
    int cur = 0;
    for (int k0 = 0; k0 < K; k0 += 64) {
        if (k0 + 64 < K) stage(k0 + 64, cur ^ 1);
        #pragma unroll
        for (int kc = 0; kc < 2; kc++) {
            sh8 af[2], bf[4];
            #pragma unroll
            for (int mt = 0; mt < 2; mt++) {
                const int ar = wm * 32 + mt * 16 + col;
                af[mt] = *(const sh8*)&AsL[cur][ar * 64 + (((kc * 4 + quad) ^ (ar & 7)) << 3)];
            }
            #pragma unroll
            for (int nt = 0; nt < 4; nt++) {
                const int nr = wn * 64 + nt * 16 + col;
                bf[nt] = *(const sh8*)&BsL[cur][nr * 64 + (((kc * 4 + quad) ^ (nr & 7)) << 3)];
            }
            #pragma unroll
            for (int mt = 0; mt < 2; mt++)
                #pragma unroll
                for (int nt = 0; nt < 4; nt++)
                    acc[mt][nt] = __builtin_amdgcn_mfma_f32_16x16x32_bf16(af[mt], bf[nt], acc[mt][nt], 0, 0, 0);
        }
        __syncthreads();
        cur ^= 1;
    }
    #pragma unroll
    for (int nt = 0; nt < 4; nt++) {
        const int cn = n0 + wn * 64 + nt * 16 + col;
        const float bj = bias[cn];
        #pragma unroll
        for (int mt = 0; mt < 2; mt++) {
            const int rm = m0 + wm * 32 + mt * 16 + quad * 4;
            #pragma unroll
            for (int reg = 0; reg < 4; reg++) {
                float cv = acc[mt][nt][reg] + bj;
                if (RELU) cv = fmaxf(cv, 0.f);
                storeOut(&C[(size_t)(rm + reg) * N + cn], cv);
            }
        }
    }
}

// ---------------------------------------------------------------------------
// MFMA flash attention v9 (causal, reverse-paired tiles, COALESCED staging).
// R6-verified config (~56 us; R10: structure is round-throughput-bound).
// ---------------------------------------------------------------------------
__global__ __launch_bounds__(256, 2) void attn_mfma(const unsigned short* __restrict__ Qb,
                                                    const unsigned short* __restrict__ Kb,
                                                    const unsigned short* __restrict__ Vt,
                                                    __hip_bfloat16* __restrict__ O,
                                                    int L)
{
    __shared__ unsigned short Ks[2][4096];       // [buf][key:64][e-chunk swz] 16 KB
    __shared__ unsigned short Vs[2][4096];       // [buf][e:64][key-chunk swz] 16 KB
    __shared__ unsigned short PsA[4][16][72];    // per wave [qrow:16][key:64+pad] 9 KB
    __shared__ unsigned short PsB[4][16][72];

    const int i    = blockIdx.x;                 // 0..15
    const int bh   = blockIdx.y;
    const int b    = bh >> 3, h = bh & 7;        // H = 8
    const int t    = threadIdx.x;
    const int w    = t >> 6, lane = t & 63;
    const int quad = lane >> 4, col = lane & 15;

    const int qtA = i, qtB = 31 - i;             // light / heavy tile
    const int qrowA = qtA * 64 + w * 16 + col;
    const int qrowB = qtB * 64 + w * 16 + col;
    const int S = 32 - i;                        // rounds (tile B needs all)

    const int srow = lane >> 3;                  // row offset within instr (0..7)
    const int scp  = lane & 7;                   // destination chunk

    sh8 qfA[2], qfB[2];
    {
        const size_t qa = ((size_t)(b * L + qrowA) * 8 + h) * 64;
        qfA[0] = *(const sh8*)(Qb + qa + quad * 8);
        qfA[1] = *(const sh8*)(Qb + qa + 32 + quad * 8);
        const size_t qb2 = ((size_t)(b * L + qrowB) * 8 + h) * 64;
        qfB[0] = *(const sh8*)(Qb + qb2 + quad * 8);
        qfB[1] = *(const sh8*)(Qb + qb2 + 32 + quad * 8);
    }

    f32x4 OA[4], OB[4];
    #pragma unroll
    for (int nt = 0; nt < 4; nt++) { OA[nt] = (f32x4){0.f,0.f,0.f,0.f}; OB[nt] = (f32x4){0.f,0.f,0.f,0.f}; }
    float lA = 0.f, lB = 0.f;

    {
        #pragma unroll
        for (int seg = 0; seg < 2; seg++) {
            const int r0  = (seg * 4 + w) * 8;   // wave-uniform row base
            const int row = r0 + srow;
            const int ck  = scp ^ (row & 7);     // source chunk (involution)
            gl_lds16(Kb + ((size_t)(b * L + row) * 8 + h) * 64 + ck * 8, &Ks[0][r0 * 64]);
            gl_lds16(Vt + (size_t)(bh * 64 + row) * L + ck * 8, &Vs[0][r0 * 64]);
        }
        __syncthreads();
    }

    int cur = 0;
    for (int r = 0; r < S; r++) {
        if (r + 1 < S) {
            const int k1 = (r + 1) * 64;
            #pragma unroll
            for (int seg = 0; seg < 2; seg++) {
                const int r0  = (seg * 4 + w) * 8;
                const int row = r0 + srow;
                const int ck  = scp ^ (row & 7);
                gl_lds16(Kb + ((size_t)(b * L + k1 + row) * 8 + h) * 64 + ck * 8, &Ks[cur ^ 1][r0 * 64]);
                gl_lds16(Vt + (size_t)(bh * 64 + row) * L + k1 + ck * 8, &Vs[cur ^ 1][r0 * 64]);
            }
        }

        const int k0 = r * 64;
        const bool actA  = (r <= i);
        const bool maskA = (r == i);
        const bool maskB = (r == S - 1);

        f32x4 stA[4], stB[4];
        const f32x4 zz = {0.f, 0.f, 0.f, 0.f};
        #pragma unroll
        for (int ntk = 0; ntk < 4; ntk++) {
            const int key = ntk * 16 + col;
            const int sw  = key & 7;
            sh8 kf0 = *(const sh8*)&Ks[cur][key * 64 + ((quad ^ sw) << 3)];
            sh8 kf1 = *(const sh8*)&Ks[cur][key * 64 + (((quad + 4) ^ sw) << 3)];
            f32x4 aB = __builtin_amdgcn_mfma_f32_16x16x32_bf16(kf0, qfB[0], zz, 0, 0, 0);
            stB[ntk] = __builtin_amdgcn_mfma_f32_16x16x32_bf16(kf1, qfB[1], aB, 0, 0, 0);
            if (actA) {
                f32x4 aA = __builtin_amdgcn_mfma_f32_16x16x32_bf16(kf0, qfA[0], zz, 0, 0, 0);
                stA[ntk] = __builtin_amdgcn_mfma_f32_16x16x32_bf16(kf1, qfA[1], aA, 0, 0, 0);
            }
        }

        {
            if (maskB) {
                #pragma unroll
                for (int ntk = 0; ntk < 4; ntk++)
                    #pragma unroll
                    for (int reg = 0; reg < 4; reg++)
                        if (k0 + ntk * 16 + quad * 4 + reg > qrowB) stB[ntk][reg] = -1e30f;
            }
            #pragma unroll
            for (int ntk = 0; ntk < 4; ntk++) {
                #pragma unroll
                for (int reg = 0; reg < 4; reg++)
                    stB[ntk][reg] = exp2f(stB[ntk][reg]);
                lB += (stB[ntk][0] + stB[ntk][1]) + (stB[ntk][2] + stB[ntk][3]);
                *(uint2*)&PsB[w][col][ntk * 16 + quad * 4] =
                    make_uint2(pk_bf16(stB[ntk][0], stB[ntk][1]), pk_bf16(stB[ntk][2], stB[ntk][3]));
            }
        }
        if (actA) {
            if (maskA) {
                #pragma unroll
                for (int ntk = 0; ntk < 4; ntk++)
                    #pragma unroll
                    for (int reg = 0; reg < 4; reg++)
                        if (k0 + ntk * 16 + quad * 4 + reg > qrowA) stA[ntk][reg] = -1e30f;
            }
            #pragma unroll
            for (int ntk = 0; ntk < 4; ntk++) {
                #pragma unroll
                for (int reg = 0; reg < 4; reg++)
                    stA[ntk][reg] = exp2f(stA[ntk][reg]);
                lA += (stA[ntk][0] + stA[ntk][1]) + (stA[ntk][2] + stA[ntk][3]);
                *(uint2*)&PsA[w][col][ntk * 16 + quad * 4] =
                    make_uint2(pk_bf16(stA[ntk][0], stA[ntk][1]), pk_bf16(stA[ntk][2], stA[ntk][3]));
            }
        }

        #pragma unroll
        for (int kchunk = 0; kchunk < 2; kchunk++) {
            sh8 pfB = *(const sh8*)&PsB[w][col][kchunk * 32 + quad * 8];
            sh8 pfA;
            if (actA) pfA = *(const sh8*)&PsA[w][col][kchunk * 32 + quad * 8];
            #pragma unroll
            for (int nt = 0; nt < 4; nt++) {
                const int e  = nt * 16 + col;
                sh8 vf = *(const sh8*)&Vs[cur][e * 64 + (((kchunk * 4 + quad) ^ (e & 7)) << 3)];
                OB[nt] = __builtin_amdgcn_mfma_f32_16x16x32_bf16(pfB, vf, OB[nt], 0, 0, 0);
                if (actA) OA[nt] = __builtin_amdgcn_mfma_f32_16x16x32_bf16(pfA, vf, OA[nt], 0, 0, 0);
            }
        }
        __syncthreads();
        cur ^= 1;
    }

    lA += __shfl_xor(lA, 16); lA += __shfl_xor(lA, 32);
    lB += __shfl_xor(lB, 16); lB += __shfl_xor(lB, 32);
    {
        const float li = 1.f / lA;
        float lr[4];
        #pragma unroll
        for (int reg = 0; reg < 4; reg++) lr[reg] = __shfl(li, quad * 4 + reg);
        #pragma unroll
        for (int reg = 0; reg < 4; reg++) {
            const int qr = qtA * 64 + w * 16 + quad * 4 + reg;
            #pragma unroll
            for (int nt = 0; nt < 4; nt++)
                O[((size_t)(b * L + qr) * 8 + h) * 64 + nt * 16 + col] =
                    __float2bfloat16(OA[nt][reg] * lr[reg]);
        }
    }
    {
        const float li = 1.f / lB;
        float lr[4];
        #pragma unroll
        for (int reg = 0; reg < 4; reg++) lr[reg] = __shfl(li, quad * 4 + reg);
        #pragma unroll
        for (int reg = 0; reg < 4; reg++) {
            const int qr = qtB * 64 + w * 16 + quad * 4 + reg;
            #pragma unroll
            for (int nt = 0; nt < 4; nt++)
                O[((size_t)(b * L + qr) * 8 + h) * 64 + nt * 16 + col] =
                    __float2bfloat16(OB[nt][reg] * lr[reg]);
        }
    }
}

// ---------------------------------------------------------------------------
// LayerNorm over last dim (512), bf16 in / bf16 out (R12 diet).
// x = f1 [+ f2] [+ rb(fp32)]. In-place safe (reads precede writes/thread).
// ---------------------------------------------------------------------------
__global__ __launch_bounds__(256) void layernorm_k(const unsigned short* __restrict__ f1,
                                                   const unsigned short* __restrict__ f2,
                                                   const float* __restrict__ rb,
                                                   const float* __restrict__ g,
                                                   const float* __restrict__ bb,
                                                   unsigned short* __restrict__ out16)
{
    const int row = blockIdx.x;
    const int t   = threadIdx.x;
    const size_t base = (size_t)row * 512;
    const int i0 = t * 2;

    const unsigned u1 = *(const unsigned*)(f1 + base + i0);
    float a0 = bf2f((unsigned short)(u1 & 0xffff));
    float a1 = bf2f((unsigned short)(u1 >> 16));
    if (f2) {
        const unsigned u2 = *(const unsigned*)(f2 + base + i0);
        a0 += bf2f((unsigned short)(u2 & 0xffff));
        a1 += bf2f((unsigned short)(u2 >> 16));
    }
    if (rb) { a0 += rb[base + i0]; a1 += rb[base + i0 + 1]; }

    float s = a0 + a1, ss = a0 * a0 + a1 * a1;
    #pragma unroll
    for (int off = 32; off > 0; off >>= 1) {
        s  += __shfl_xor(s, off);
        ss += __shfl_xor(ss, off);
    }
    __shared__ float red[16];
    const int lane = t & 63, wid = t >> 6;
    if (lane == 0) { red[wid] = s; red[8 + wid] = ss; }
    __syncthreads();
    if (t == 0) {
        const float S  = red[0] + red[1] + red[2] + red[3];
        const float SS = red[8] + red[9] + red[10] + red[11];
        const float mu = S * (1.f / 512.f);
        const float var = SS * (1.f / 512.f) - mu * mu;
        red[0] = mu;
        red[1] = rsqrtf(fmaxf(var, 0.f) + 1e-5f);
    }
    __syncthreads();
    const float mu = red[0], rstd = red[1];
    const float y0 = (a0 - mu) * rstd * g[i0]     + bb[i0];
    const float y1 = (a1 - mu) * rstd * g[i0 + 1] + bb[i0 + 1];
    *(unsigned*)(out16 + base + i0) = pk_bf16(y0, y1);
}

// ---------------------------------------------------------------------------
extern "C" void kernel_launch(void* const* d_in, const int* in_sizes, int n_in,
                              void* d_out, int out_size, void* d_ws, size_t ws_size,
                              hipStream_t stream)
{
    const float* q   = (const float*)d_in[0];
    const float* k   = (const float*)d_in[1];
    const float* v   = (const float*)d_in[2];
    const float* Wq  = (const float*)d_in[3];
    const float* bq  = (const float*)d_in[4];
    const float* Wk  = (const float*)d_in[5];
    const float* bk  = (const float*)d_in[6];
    const float* Wv  = (const float*)d_in[7];
    const float* bv  = (const float*)d_in[8];
    const float* Wo  = (const float*)d_in[9];
    const float* bo  = (const float*)d_in[10];
    const float* Wc1 = (const float*)d_in[11];
    const float* bc1 = (const float*)d_in[12];
    const float* Wc2 = (const float*)d_in[13];
    const float* bc2 = (const float*)d_in[14];
    const float* g1  = (const float*)d_in[15];
    const float* b1  = (const float*)d_in[16];
    const float* g2  = (const float*)d_in[17];
    const float* b2  = (const float*)d_in[18];
    const float* Wl  = (const float*)d_in[19];
    const float* bl  = (const float*)d_in[20];
    float* out = (float*)d_out;

    const int B = 4, L = 2048, H = 8;
    const int M = B * L;                        // 8192

    // Workspace map (bytes):
    //   A2b (8 MB) at 40370176 (Wo out, dead after LN1).
    //   Y2b (8 MB) at 48758784 (FFN2 out, dead after LN2).
    //   X1b (16 MB) at 73924608, live LN1 -> FFN1 -> LN2 (in-place).
    char* base = (char*)d_ws;
    unsigned short* Wall = (unsigned short*)(base + 0);          // 6.8 MB, live all
    unsigned short* Wob  = (unsigned short*)(base + 1572864);
    unsigned short* Wlb  = (unsigned short*)(base + 2097152);
    unsigned short* Wc1b = (unsigned short*)(base + 2621440);
    unsigned short* Wc2b = (unsigned short*)(base + 4718592);
    unsigned short* Qb   = (unsigned short*)(base + 6815744);    // -> dead after attn
    unsigned short* Kb   = (unsigned short*)(base + 15204352);   // -> dead after attn
    unsigned short* Vt   = (unsigned short*)(base + 23592960);   // -> dead after attn
    unsigned short* A1   = (unsigned short*)(base + 31981568);   // -> dead after Wo
    unsigned short* A2b  = (unsigned short*)(base + 40370176);   // att@Wo bf16 -> dead after LN1
    unsigned short* Y2b  = (unsigned short*)(base + 48758784);   // FFN2 out bf16 -> dead after LN2
    unsigned short* X1b  = (unsigned short*)(base + 73924608);   // x bf16, live to LN2 (in-place)
    unsigned short* X2b  = (unsigned short*)(base + 73924608);   // = X1b (in-place LN2)
    unsigned short* H1   = (unsigned short*)(base + 6815744);    // 33.5 MB over Qb..A1
    const dim3 blk(256);

    // 1: weights fp32 -> bf16
    WArg wa;
    wa.w[0] = Wq; wa.w[1] = Wk; wa.w[2] = Wv; wa.w[3] = Wo; wa.w[4] = Wl;
    wa.w[5] = Wc1; wa.w[6] = Wc2; wa.wd = Wall;
    conv_w<<<dim3(3328), blk, 0, stream>>>(wa);

    // 2: batched QKV projections (fp32 A direct, BK=32 2-phase)
    QkvArg qa;
    qa.A0 = q;  qa.A1 = k;  qa.A2 = v;
    qa.b0 = bq; qa.b1 = bk; qa.b2 = bv;
    qa.C0 = Qb; qa.C1 = Kb; qa.Vt = Vt;
    gemm_qkv<<<dim3(4, 64, 3), blk, 0, stream>>>(qa, Wall, M, 512, 512);

    // 3: flash attention v9 (R6-verified) -> bf16 A1
    attn_mfma<<<dim3(16, B * H), blk, 0, stream>>>(Qb, Kb, Vt, (__hip_bfloat16*)A1, L);

    // 4: att @ Wo^T + bo -> bf16 A2b
    gemm_mfma64<__hip_bfloat16, false><<<dim3(4, 128), blk, 0, stream>>>(A1, Wob, bo, (__hip_bfloat16*)A2b, M, 512, 512);

    // 5: x = LN(A2b + v) -> bf16 X1b
    layernorm_k<<<dim3(M), blk, 0, stream>>>(A2b, nullptr, v, g1, b1, X1b);

    // 6: h1 = relu(x @ Wc1^T + bc1) -> bf16 [M,2048]
    gemm_mfma<__hip_bfloat16, true><<<dim3(16, 64), blk, 0, stream>>>(X1b, Wc1b, bc1, (__hip_bfloat16*)H1, M, 2048, 512);

    // 7: y2 = h1 @ Wc2^T + bc2 -> bf16 Y2b
    gemm_mfma64<__hip_bfloat16, false><<<dim3(4, 128), blk, 0, stream>>>(H1, Wc2b, bc2, (__hip_bfloat16*)Y2b, M, 512, 2048);

    // 8: x2 = LN(X1b + Y2b) -> bf16, in place on X1b
    layernorm_k<<<dim3(M), blk, 0, stream>>>(X1b, Y2b, nullptr, g2, b2, X2b);

    // 9: out = x2 @ Wl^T + bl -> fp32 d_out
    gemm_mfma64<float, false><<<dim3(4, 128), blk, 0, stream>>>(X2b, Wlb, bl, out, M, 512, 512);
}